// Round 1
// baseline (3771.075 us; speedup 1.0000x reference)
//
#include <hip/hip_runtime.h>
#include <math.h>

// ---------------- problem constants ----------------
constexpr int NS = 25, NQ = 15, NB = 40;     // support imgs, query imgs, total
constexpr int B3 = 375;                      // qk * n * k = 15*25
constexpr int T49 = 49;                      // seq len (7*7)
constexpr float BN_INV = 0.9999950000374997f; // 1/sqrt(1+1e-5)

// ---------------- workspace layout (float elements) ----------------
// Encoder ping-pongs: conv -> CONV buffer, pool -> P* buffer. After the
// encoder finishes, the 16M-elt CONV buffer is dead and is reused for
// attended / gi / y0 (strictly sequential producers/consumers, verified):
//   attention writes ATT            (reads PROJ, FEATT)
//   gemm0     writes GI             (reads ATT, FEATT)
//   gru0      writes Y0             (reads GI)
//   gemm1     writes GI  (overwrite)(reads Y0)
//   gru1      writes HFIN           (reads GI)
constexpr size_t OFF_IN    = 0;
constexpr size_t SZ_IN     = (size_t)NB * 224 * 224;            // 2,007,040
constexpr size_t OFF_CONV  = OFF_IN + SZ_IN;
constexpr size_t SZ_CONV   = (size_t)NB * 32 * 112 * 112;       // 16,056,320
constexpr size_t OFF_ATT   = OFF_CONV;                          // 375*49*256 = 4,704,000
constexpr size_t OFF_GI    = OFF_ATT + (size_t)B3 * T49 * 256;  // 18375*384 = 7,056,000
constexpr size_t OFF_Y0    = OFF_GI + (size_t)B3 * T49 * 384;   // 375*49*128 = 2,352,000
// (4.70M + 7.06M + 2.35M = 14.11M <= 16.06M, fits inside CONV)        
constexpr size_t OFF_P1    = OFF_CONV + SZ_CONV;                // 40*32*56*56
constexpr size_t OFF_P2    = OFF_P1 + (size_t)NB * 32 * 56 * 56;  // 40*64*28*28
constexpr size_t OFF_P3    = OFF_P2 + (size_t)NB * 64 * 28 * 28;  // 40*128*14*14
constexpr size_t OFF_FEAT  = OFF_P3 + (size_t)NB * 128 * 14 * 14; // 40*256*7*7
constexpr size_t OFF_FEATT = OFF_FEAT + (size_t)NB * 256 * T49;   // (b,t,f) layout
constexpr size_t OFF_PROJ  = OFF_FEATT + (size_t)NB * T49 * 256;  // 40*49*64
constexpr size_t OFF_WHT0  = OFF_PROJ + (size_t)NB * T49 * 64;    // 128*384
constexpr size_t OFF_WHT1  = OFF_WHT0 + (size_t)128 * 384;
constexpr size_t OFF_HFIN  = OFF_WHT1 + (size_t)128 * 384;        // 375*128
constexpr size_t OFF_END   = OFF_HFIN + (size_t)B3 * 128;
// total ~26.4M floats = ~100.6 MB of d_ws

// ---------------- conv 3x3 + bias + BN(eval) + ReLU ----------------
// one block: 16x16 output tile for one (image b, out-channel oc).
// weights for oc staged in LDS (max IC=128 -> 1152 floats).
__global__ __launch_bounds__(256) void conv3x3_bn_relu(
    const float* __restrict__ in, const float* __restrict__ w,
    const float* __restrict__ cb, const float* __restrict__ g,
    const float* __restrict__ be, float* __restrict__ out,
    int IC, int IH, int IW, int OC, int OH, int OW, int stride) {
  __shared__ float wl[128 * 9];
  const int oc = blockIdx.z % OC, b = blockIdx.z / OC;
  const int nw = IC * 9;
  for (int l = threadIdx.y * 16 + threadIdx.x; l < nw; l += 256)
    wl[l] = w[(size_t)oc * nw + l];
  __syncthreads();
  const int ox = blockIdx.x * 16 + threadIdx.x;
  const int oy = blockIdx.y * 16 + threadIdx.y;
  if (ox >= OW || oy >= OH) return;
  const float* ib = in + (size_t)b * IC * IH * IW;
  const int iy0 = oy * stride - 1, ix0 = ox * stride - 1;
  float acc = 0.f;
  for (int ic = 0; ic < IC; ++ic) {
    const float* p = ib + (size_t)ic * IH * IW;
    const float* wp = &wl[ic * 9];
#pragma unroll
    for (int ky = 0; ky < 3; ++ky) {
      const int iy = iy0 + ky;
      if (iy < 0 || iy >= IH) continue;
#pragma unroll
      for (int kx = 0; kx < 3; ++kx) {
        const int ix = ix0 + kx;
        if (ix < 0 || ix >= IW) continue;
        acc += p[(size_t)iy * IW + ix] * wp[ky * 3 + kx];
      }
    }
  }
  const float s = g[oc] * BN_INV;
  float v = (acc + cb[oc]) * s + be[oc];
  out[(((size_t)b * OC + oc) * OH + oy) * OW + ox] = v > 0.f ? v : 0.f;
}

// ---------------- 2x2 maxpool, stride 2 ----------------
__global__ void maxpool2(const float* __restrict__ in, float* __restrict__ out,
                         int BC, int IH, int IW) {
  const int OH = IH >> 1, OW = IW >> 1;
  const size_t n = (size_t)BC * OH * OW;
  for (size_t i = (size_t)blockIdx.x * blockDim.x + threadIdx.x; i < n;
       i += (size_t)gridDim.x * blockDim.x) {
    const int x = (int)(i % OW);
    const int y = (int)((i / OW) % OH);
    const int bc = (int)(i / ((size_t)OW * OH));
    const float* p = in + ((size_t)bc * IH + 2 * y) * IW + 2 * x;
    out[i] = fmaxf(fmaxf(p[0], p[1]), fmaxf(p[IW], p[IW + 1]));
  }
}

// ---------------- feat (b,c,t) -> featT (b,t,c) ----------------
__global__ void transpose_feat(const float* __restrict__ feat,
                               float* __restrict__ featT) {
  const int n = NB * T49 * 256;
  for (int i = blockIdx.x * blockDim.x + threadIdx.x; i < n;
       i += gridDim.x * blockDim.x) {
    const int f = i & 255;
    const int t = (i >> 8) % T49;
    const int b = i / (256 * T49);
    featT[i] = feat[((size_t)b * 256 + f) * T49 + t];
  }
}

// ---------------- attention projection: proj[b,t,h] = featT[b,t,:]·aw[h,:]+ab[h]
__global__ void att_proj(const float* __restrict__ featT,
                         const float* __restrict__ aw,
                         const float* __restrict__ ab,
                         float* __restrict__ proj) {
  const int n = NB * T49 * 64;
  for (int i = blockIdx.x * blockDim.x + threadIdx.x; i < n;
       i += gridDim.x * blockDim.x) {
    const int h = i & 63;
    const int bt = i >> 6;
    const float* x = featT + (size_t)bt * 256;
    const float* wr = aw + (size_t)h * 256;
    float acc = ab[h];
    for (int c = 0; c < 256; ++c) acc += x[c] * wr[c];
    proj[i] = acc;
  }
}

// ---------------- fused attention: scores->softmax->attended, per (q,s) ----
__global__ __launch_bounds__(256) void attention_kernel(
    const float* __restrict__ proj, const float* __restrict__ featT,
    float* __restrict__ attended) {
  __shared__ float Wq[T49 * 64], Wh[T49 * 64], sc[T49 * 50];
  const int qs = blockIdx.x, q = qs / NS, s = qs % NS;
  const int tid = threadIdx.x;
  const float* pq = proj + (size_t)(NS + q) * T49 * 64;
  const float* ph = proj + (size_t)s * T49 * 64;
  for (int l = tid; l < T49 * 64; l += 256) { Wq[l] = pq[l]; Wh[l] = ph[l]; }
  __syncthreads();
  for (int e = tid; e < T49 * T49; e += 256) {
    const int t = e / T49, u = e % T49;
    const float* a = &Wq[t * 64];
    const float* b = &Wh[u * 64];
    float acc = 0.f;
#pragma unroll 8
    for (int h = 0; h < 64; ++h) acc += tanhf(a[h] * b[h]);
    sc[t * 50 + u] = acc;
  }
  __syncthreads();
  if (tid < T49) {  // softmax over u per row t
    float* row = &sc[tid * 50];
    float m = row[0];
    for (int u = 1; u < T49; ++u) m = fmaxf(m, row[u]);
    float ssum = 0.f;
    for (int u = 0; u < T49; ++u) { const float e = expf(row[u] - m); row[u] = e; ssum += e; }
    const float inv = 1.f / ssum;
    for (int u = 0; u < T49; ++u) row[u] *= inv;
  }
  __syncthreads();
  // attended[t,f] = sum_u sc[t,u] * featT[s,u,f]; thread = f
  const float* fs = featT + (size_t)s * T49 * 256;
  float* outp = attended + (size_t)qs * T49 * 256;
  for (int t = 0; t < T49; ++t) {
    float acc = 0.f;
    for (int u = 0; u < T49; ++u) acc += sc[t * 50 + u] * fs[u * 256 + tid];
    outp[t * 256 + tid] = acc;
  }
}

// ---------------- tiled fp32 GEMM: C[m,j] = bias[j] + sum_k A(m,k)*W[j,k] ----
// mode 0: K=512, A = concat(attended[m,0:256], qf[q(m),t(m),0:256]) gathered
// mode 1: K=128, A = A0[m*128+k]
__global__ __launch_bounds__(256) void gemm_tiled(
    const float* __restrict__ A0, const float* __restrict__ A1,
    const float* __restrict__ W, const float* __restrict__ bias,
    float* __restrict__ C, int K, int mode) {
  const int M = B3 * T49;  // 18375
  __shared__ float As[32][33], Bs[32][33];
  const int tid = threadIdx.x;
  const int tx = tid & 31, ty = tid >> 5;
  const int j0 = blockIdx.x * 32, m0 = blockIdx.y * 32;
  float acc[4] = {0.f, 0.f, 0.f, 0.f};
  for (int k0 = 0; k0 < K; k0 += 32) {
    for (int l = tid; l < 1024; l += 256) {
      const int mi = l >> 5, ki = l & 31;
      const int m = m0 + mi, k = k0 + ki;
      float v = 0.f;
      if (m < M) {
        if (mode == 0) {
          if (k < 256) {
            v = A0[(size_t)m * 256 + k];
          } else {
            const int b = m / T49, t = m % T49, q = b / NS;
            v = A1[((size_t)(NS + q) * T49 + t) * 256 + (k - 256)];
          }
        } else {
          v = A0[(size_t)m * 128 + k];
        }
      }
      As[mi][ki] = v;
    }
    for (int l = tid; l < 1024; l += 256) {
      const int ji = l >> 5, ki = l & 31;
      Bs[ki][ji] = W[(size_t)(j0 + ji) * K + k0 + ki];
    }
    __syncthreads();
#pragma unroll
    for (int ki = 0; ki < 32; ++ki) {
      const float bv = Bs[ki][tx];
      acc[0] += As[ty][ki] * bv;
      acc[1] += As[ty + 8][ki] * bv;
      acc[2] += As[ty + 16][ki] * bv;
      acc[3] += As[ty + 24][ki] * bv;
    }
    __syncthreads();
  }
  const float bj = bias[j0 + tx];
#pragma unroll
  for (int r = 0; r < 4; ++r) {
    const int m = m0 + ty + 8 * r;
    if (m < M) C[(size_t)m * 384 + j0 + tx] = acc[r] + bj;
  }
}

// ---------------- wh (384,128) -> whT (128,384) ----------------
__global__ void transpose_wh(const float* __restrict__ wh,
                             float* __restrict__ whT) {
  const int i = blockIdx.x * 256 + threadIdx.x;
  if (i < 384 * 128) {
    const int j = i % 384, k = i / 384;
    whT[i] = wh[(size_t)j * 128 + k];
  }
}

// ---------------- GRU layer: one block per batch row, loops all 49 steps ----
// gi precomputed (b,t,384). h kept in LDS. whT is (128,384) so lane reads
// across j coalesce.
__global__ __launch_bounds__(384) void gru_layer(
    const float* __restrict__ gi, const float* __restrict__ whT,
    const float* __restrict__ bh, float* __restrict__ y, int store_all) {
  __shared__ float hl[128], ghl[384];
  const int b = blockIdx.x, j = threadIdx.x;
  if (j < 128) hl[j] = 0.f;
  __syncthreads();
  const float bhj = bh[j];
  for (int t = 0; t < T49; ++t) {
    float a0 = 0.f, a1 = 0.f, a2 = 0.f, a3 = 0.f;
#pragma unroll 8
    for (int k = 0; k < 128; k += 4) {
      a0 += whT[(size_t)(k + 0) * 384 + j] * hl[k + 0];
      a1 += whT[(size_t)(k + 1) * 384 + j] * hl[k + 1];
      a2 += whT[(size_t)(k + 2) * 384 + j] * hl[k + 2];
      a3 += whT[(size_t)(k + 3) * 384 + j] * hl[k + 3];
    }
    ghl[j] = bhj + ((a0 + a1) + (a2 + a3));
    __syncthreads();
    if (j < 128) {
      const float* gib = gi + ((size_t)b * T49 + t) * 384;
      const float r = 1.f / (1.f + expf(-(gib[j] + ghl[j])));
      const float z = 1.f / (1.f + expf(-(gib[128 + j] + ghl[128 + j])));
      const float n = tanhf(gib[256 + j] + r * ghl[256 + j]);
      const float hn = (1.f - z) * n + z * hl[j];
      hl[j] = hn;
      if (store_all) y[((size_t)b * T49 + t) * 128 + j] = hn;
    }
    __syncthreads();
  }
  if (!store_all && j < 128) y[(size_t)b * 128 + j] = hl[j];
}

// ---------------- head: logits, (15,5,5) sum over k, log_softmax ----------
__global__ __launch_bounds__(512) void head_kernel(
    const float* __restrict__ hf, const float* __restrict__ tw,
    const float* __restrict__ tb, float* __restrict__ out) {
  __shared__ float lg[B3];
  const int tid = threadIdx.x;
  if (tid < B3) {
    const float* h = hf + (size_t)tid * 128;
    float acc = tb[0];
    for (int k = 0; k < 128; ++k) acc += h[k] * tw[k];
    lg[tid] = acc;
  }
  __syncthreads();
  if (tid < NQ) {
    float cls[5];
#pragma unroll
    for (int n = 0; n < 5; ++n) {
      float s = 0.f;
#pragma unroll
      for (int k = 0; k < 5; ++k) s += lg[tid * 25 + n * 5 + k];
      cls[n] = s;
    }
    float m = cls[0];
#pragma unroll
    for (int n = 1; n < 5; ++n) m = fmaxf(m, cls[n]);
    float se = 0.f;
#pragma unroll
    for (int n = 0; n < 5; ++n) se += expf(cls[n] - m);
    const float lse = m + logf(se);
#pragma unroll
    for (int n = 0; n < 5; ++n) out[tid * 5 + n] = cls[n] - lse;
  }
}

extern "C" void kernel_launch(void* const* d_in, const int* in_sizes, int n_in,
                              void* d_out, int out_size, void* d_ws,
                              size_t ws_size, hipStream_t stream) {
  (void)in_sizes; (void)n_in; (void)out_size; (void)ws_size;
  const float* support = (const float*)d_in[0];
  const float* query   = (const float*)d_in[1];
  const float* cw1 = (const float*)d_in[2];  const float* cb1 = (const float*)d_in[3];
  const float* cw2 = (const float*)d_in[4];  const float* cb2 = (const float*)d_in[5];
  const float* cw3 = (const float*)d_in[6];  const float* cb3 = (const float*)d_in[7];
  const float* cw4 = (const float*)d_in[8];  const float* cb4 = (const float*)d_in[9];
  const float* g1  = (const float*)d_in[10]; const float* be1 = (const float*)d_in[11];
  const float* g2  = (const float*)d_in[12]; const float* be2 = (const float*)d_in[13];
  const float* g3  = (const float*)d_in[14]; const float* be3 = (const float*)d_in[15];
  const float* g4  = (const float*)d_in[16]; const float* be4 = (const float*)d_in[17];
  const float* aw  = (const float*)d_in[18]; const float* ab  = (const float*)d_in[19];
  const float* wi0 = (const float*)d_in[20]; const float* wh0 = (const float*)d_in[21];
  const float* bi0 = (const float*)d_in[22]; const float* bh0 = (const float*)d_in[23];
  const float* wi1 = (const float*)d_in[24]; const float* wh1 = (const float*)d_in[25];
  const float* bi1 = (const float*)d_in[26]; const float* bh1 = (const float*)d_in[27];
  const float* tw  = (const float*)d_in[28]; const float* tb  = (const float*)d_in[29];

  float* ws = (float*)d_ws;
  float* out = (float*)d_out;
  float* IN    = ws + OFF_IN;
  float* CONV  = ws + OFF_CONV;
  float* P1    = ws + OFF_P1;
  float* P2    = ws + OFF_P2;
  float* P3    = ws + OFF_P3;
  float* FEAT  = ws + OFF_FEAT;
  float* FEATT = ws + OFF_FEATT;
  float* PROJ  = ws + OFF_PROJ;
  float* ATT   = ws + OFF_ATT;
  float* GI    = ws + OFF_GI;
  float* Y0    = ws + OFF_Y0;
  float* WHT0  = ws + OFF_WHT0;
  float* WHT1  = ws + OFF_WHT1;
  float* HFIN  = ws + OFF_HFIN;

  // stage inputs contiguously: (40,1,224,224), support then query
  hipMemcpyAsync(IN, support, (size_t)NS * 224 * 224 * sizeof(float),
                 hipMemcpyDeviceToDevice, stream);
  hipMemcpyAsync(IN + (size_t)NS * 224 * 224, query,
                 (size_t)NQ * 224 * 224 * sizeof(float),
                 hipMemcpyDeviceToDevice, stream);

  const dim3 blk(16, 16);
  // encoder
  conv3x3_bn_relu<<<dim3(7, 7, NB * 32), blk, 0, stream>>>(
      IN, cw1, cb1, g1, be1, CONV, 1, 224, 224, 32, 112, 112, 2);
  maxpool2<<<1024, 256, 0, stream>>>(CONV, P1, NB * 32, 112, 112);
  conv3x3_bn_relu<<<dim3(4, 4, NB * 64), blk, 0, stream>>>(
      P1, cw2, cb2, g2, be2, CONV, 32, 56, 56, 64, 56, 56, 1);
  maxpool2<<<1024, 256, 0, stream>>>(CONV, P2, NB * 64, 56, 56);
  conv3x3_bn_relu<<<dim3(2, 2, NB * 128), blk, 0, stream>>>(
      P2, cw3, cb3, g3, be3, CONV, 64, 28, 28, 128, 28, 28, 1);
  maxpool2<<<1024, 256, 0, stream>>>(CONV, P3, NB * 128, 28, 28);
  conv3x3_bn_relu<<<dim3(1, 1, NB * 256), blk, 0, stream>>>(
      P3, cw4, cb4, g4, be4, CONV, 128, 14, 14, 256, 14, 14, 1);
  maxpool2<<<512, 256, 0, stream>>>(CONV, FEAT, NB * 256, 14, 14);

  // attention
  transpose_feat<<<512, 256, 0, stream>>>(FEAT, FEATT);
  att_proj<<<512, 256, 0, stream>>>(FEATT, aw, ab, PROJ);
  attention_kernel<<<B3, 256, 0, stream>>>(PROJ, FEATT, ATT);

  // GRU stack
  transpose_wh<<<192, 256, 0, stream>>>(wh0, WHT0);
  transpose_wh<<<192, 256, 0, stream>>>(wh1, WHT1);
  gemm_tiled<<<dim3(12, 575), 256, 0, stream>>>(ATT, FEATT, wi0, bi0, GI, 512, 0);
  gru_layer<<<B3, 384, 0, stream>>>(GI, WHT0, bh0, Y0, 1);
  gemm_tiled<<<dim3(12, 575), 256, 0, stream>>>(Y0, nullptr, wi1, bi1, GI, 128, 1);
  gru_layer<<<B3, 384, 0, stream>>>(GI, WHT1, bh1, HFIN, 0);

  // head
  head_kernel<<<1, 512, 0, stream>>>(HFIN, tw, tb, out);
}

// Round 6
// 779.069 us; speedup vs baseline: 4.8405x; 4.8405x over previous
//
#include <hip/hip_runtime.h>
#include <hip/hip_bf16.h>
#include <math.h>

typedef unsigned short u16;
typedef unsigned int u32;
typedef __attribute__((ext_vector_type(8))) short bf16x8v;
typedef __attribute__((ext_vector_type(4))) float f32x4;

// ---------------- problem constants ----------------
constexpr int NS = 25, NQ = 15, NB = 40;
constexpr int B3 = 375;     // 15*25
constexpr int T49 = 49;
constexpr float BN_INV = 0.9999950000374997f;

// ---------------- workspace layout (BYTES), f32 activations ----------------
constexpr size_t A1_OFF    = 0;            // (40,56,56,32) f32 = 16,056,320
constexpr size_t X2_OFF    = 16056320;     // (40,56,56,64) f32 = 32,112,640
constexpr size_t P2_OFF    = 48168960;     // (40,28,28,64) f32 = 8,028,160
constexpr size_t X3_OFF    = 0;            // (40,28,28,128) f32 = 16,056,320
constexpr size_t P3_OFF    = 56197120;     // (40,14,14,128) f32 = 4,014,080
constexpr size_t X4_OFF    = 16056320;     // (40,14,14,256) f32 = 8,028,160
constexpr size_t FEATT_OFF = 60211200;     // (40,49,256) f32 = 2,007,040
constexpr size_t PROJ_OFF  = 24084480;     // (1960,64) f32 = 501,760
constexpr size_t ATT_OFF   = 24586240;     // (375,49,256) f32 = 18,816,000
constexpr size_t GI_OFF    = 62218240;     // (18375,384) f32 = 28,224,000
constexpr size_t Y0_OFF    = 0;            // (18375,128) f32 = 9,408,000
constexpr size_t HFIN_OFF  = 90442240;     // (375,128) f32 = 192,000
constexpr size_t WHT0_OFF  = 90634240;     // (128,384) f32
constexpr size_t WHT1_OFF  = 90830848;
constexpr size_t WBH_OFF   = 91027456;     // bf16-hi arena 649,216 u16
constexpr size_t WBL_OFF   = 92325888;     // bf16-lo arena
// u16-element offsets within each arena:
constexpr size_t W2_E = 0;        // 64*288
constexpr size_t W3_E = 18432;    // 128*576
constexpr size_t W4_E = 92160;    // 256*1152
constexpr size_t AW_E = 387072;   // 64*256
constexpr size_t WI0_E = 403456;  // 384*512
constexpr size_t WI1_E = 600064;  // 384*128

static __device__ __forceinline__ u16 f2b(float f) {
  __hip_bfloat16 h = __float2bfloat16(f);
  return *reinterpret_cast<u16*>(&h);
}
static __device__ __forceinline__ float b2f(u16 u) {
  return __uint_as_float((u32)u << 16);
}
// split v into hi+lo bf16 pair, packed into u32 words
static __device__ __forceinline__ void split8(const float* v, u32* hp, u32* lp) {
  u16 h[8], l[8];
#pragma unroll
  for (int j = 0; j < 8; ++j) {
    const u16 hb = f2b(v[j]);
    h[j] = hb;
    l[j] = f2b(v[j] - b2f(hb));
  }
#pragma unroll
  for (int j = 0; j < 4; ++j) {
    hp[j] = (u32)h[2 * j] | ((u32)h[2 * j + 1] << 16);
    lp[j] = (u32)l[2 * j] | ((u32)l[2 * j + 1] << 16);
  }
}

// ---------------- weight split converters ----------------
__global__ void cvt_split(const float* __restrict__ x, u16* __restrict__ oh,
                          u16* __restrict__ ol, int n) {
  int i = blockIdx.x * 256 + threadIdx.x;
  if (i >= n) return;
  const float v = x[i];
  const u16 h = f2b(v);
  oh[i] = h;
  ol[i] = f2b(v - b2f(h));
}
// OIHW f32 -> [oc][(ky*3+kx)*IC + ic] hi/lo bf16
__global__ void cvt_conv_w_split(const float* __restrict__ w, u16* __restrict__ oh,
                                 u16* __restrict__ ol, int OC, int IC) {
  const int n = OC * IC * 9;
  int i = blockIdx.x * 256 + threadIdx.x;
  if (i >= n) return;
  const int oc = i / (IC * 9), rem = i % (IC * 9);
  const int e = rem / IC, ic = rem % IC;
  const int ky = e / 3, kx = e % 3;
  const float v = w[((size_t)(oc * IC + ic) * 3 + ky) * 3 + kx];
  const u16 h = f2b(v);
  oh[i] = h;
  ol[i] = f2b(v - b2f(h));
}

// ---------------- fused conv1(s2)+BN+ReLU+pool2, f32 out NHWC ----------------
__global__ __launch_bounds__(256) void conv1_pool(
    const float* __restrict__ support, const float* __restrict__ query,
    const float* __restrict__ w1, const float* __restrict__ cb1,
    const float* __restrict__ g1, const float* __restrict__ be1,
    float* __restrict__ out) {
  __shared__ float wl[288], scl[32], shl[32], cbl[32];
  const int tid = threadIdx.x;
  // FIX(r5): blockDim is 256 — a plain `if (tid < 288)` left wl[256..287]
  // (weights for oc 28..31) as garbage LDS. Strided loop covers all 288.
  for (int l = tid; l < 288; l += 256) wl[l] = w1[l];
  if (tid < 32) { scl[tid] = g1[tid] * BN_INV; shl[tid] = be1[tid]; cbl[tid] = cb1[tid]; }
  __syncthreads();
  const int oc = tid & 31;
  const int p = blockIdx.x * 8 + (tid >> 5);   // 0 .. 125439 = (b,oy,ox)
  const int ox = p % 56, oy = (p / 56) % 56, b = p / 3136;
  const float* in_b = (b < NS) ? (support + (size_t)b * 50176)
                               : (query + (size_t)(b - NS) * 50176);
  const int iy0 = 4 * oy - 1, ix0 = 4 * ox - 1;
  float pat[5][5];
#pragma unroll
  for (int dy = 0; dy < 5; ++dy) {
    const int iy = iy0 + dy;
#pragma unroll
    for (int dx = 0; dx < 5; ++dx) {
      const int ix = ix0 + dx;
      pat[dy][dx] = (iy >= 0 && iy < 224 && ix >= 0 && ix < 224)
                        ? in_b[(size_t)iy * 224 + ix] : 0.f;
    }
  }
  const float* wp = &wl[oc * 9];
  float mx = 0.f;  // post-ReLU values >= 0
#pragma unroll
  for (int py = 0; py < 2; ++py)
#pragma unroll
    for (int px = 0; px < 2; ++px) {
      float acc = 0.f;
#pragma unroll
      for (int ky = 0; ky < 3; ++ky)
#pragma unroll
        for (int kx = 0; kx < 3; ++kx)
          acc += pat[2 * py + ky][2 * px + kx] * wp[ky * 3 + kx];
      float v = (acc + cbl[oc]) * scl[oc] + shl[oc];
      mx = fmaxf(mx, v);
    }
  out[(size_t)p * 32 + oc] = mx;
}

// ---------------- f32 NHWC maxpool 2x2 ----------------
__global__ void maxpool2_f32(const float* __restrict__ X, float* __restrict__ Y,
                             int Bn, int H, int W, int C) {
  const int OH = H >> 1, OW = W >> 1;
  const int cpr = C >> 2;
  const int chunks = Bn * OH * OW * cpr;
  for (int i = blockIdx.x * blockDim.x + threadIdx.x; i < chunks;
       i += gridDim.x * blockDim.x) {
    const int c4 = i % cpr, m = i / cpr;
    const int ox = m % OW, oy = (m / OW) % OH, b = m / (OW * OH);
    const size_t base = (((size_t)b * H + 2 * oy) * W + 2 * ox) * C + (c4 << 2);
    const float4 r0 = *(const float4*)&X[base];
    const float4 r1 = *(const float4*)&X[base + C];
    const float4 r2 = *(const float4*)&X[base + (size_t)W * C];
    const float4 r3 = *(const float4*)&X[base + (size_t)W * C + C];
    float4 o;
    o.x = fmaxf(fmaxf(r0.x, r1.x), fmaxf(r2.x, r3.x));
    o.y = fmaxf(fmaxf(r0.y, r1.y), fmaxf(r2.y, r3.y));
    o.z = fmaxf(fmaxf(r0.z, r1.z), fmaxf(r2.z, r3.z));
    o.w = fmaxf(fmaxf(r0.w, r1.w), fmaxf(r2.w, r3.w));
    *(float4*)&Y[(size_t)m * C + (c4 << 2)] = o;
  }
}

// ---------------- split-bf16 MFMA GEMM: C = epi(A @ W^T) --------------------
// 3-pass Dekker: acc += Ah*Wh + Ah*Wl + Al*Wh  (error ~1.6e-5 relative)
// AMODE 0: A f32 (M x K) contiguous.
// AMODE 1: K=512 concat gather: k<256 -> A(=ATT f32), else A2(=FEATT f32) qrep.
// AMODE 2: implicit im2col from A = NHWC f32 (Bn,H,W,IC); K = 9*IC; pad=1.
// EPI 0: f32 out = relu((acc+p0[n])*p1[n]*BN_INV + p2[n]).  EPI 1: f32 out = acc+p0[n].
template <int AMODE, int EPI>
__global__ __launch_bounds__(256) void sgemm(
    const float* __restrict__ A, const float* __restrict__ A2, int M, int K,
    const u16* __restrict__ Bh, const u16* __restrict__ Bl,
    const float* __restrict__ p0, const float* __restrict__ p1,
    const float* __restrict__ p2, float* __restrict__ Cout, int ldc,
    int H, int W, int IC, int icb) {
  __shared__ u16 Ash[64][72], Asl[64][72];
  __shared__ u16 Bsh[64][72], Bsl[64][72];
  const int tid = threadIdx.x;
  const int lane = tid & 63, wv = tid >> 6;
  const int wy = wv >> 1, wx = wv & 1;
  const int n0 = blockIdx.x * 64, m0 = blockIdx.y * 64;
  f32x4 acc[2][2] = {{{0, 0, 0, 0}, {0, 0, 0, 0}}, {{0, 0, 0, 0}, {0, 0, 0, 0}}};
  for (int k0 = 0; k0 < K; k0 += 64) {
    // ---- stage A (split f32 -> hi/lo bf16) ----
#pragma unroll
    for (int s = 0; s < 2; ++s) {
      const int c = s * 256 + tid;
      const int row = c >> 3, kc = (c & 7) << 3;
      const int gm = m0 + row, gk = k0 + kc;
      float4 x0 = {0, 0, 0, 0}, x1 = {0, 0, 0, 0};
      if (AMODE == 0) {
        if (gm < M && gk < K) {
          const float* p = A + (size_t)gm * K + gk;
          x0 = *(const float4*)p; x1 = *(const float4*)(p + 4);
        }
      } else if (AMODE == 1) {
        if (gm < M) {
          const float* p;
          if (gk < 256) {
            p = A + (size_t)gm * 256 + gk;
          } else {
            const int b = gm / T49, t = gm % T49, q = b / NS;
            p = A2 + (((size_t)(NS + q) * T49 + t) << 8) + (gk - 256);
          }
          x0 = *(const float4*)p; x1 = *(const float4*)(p + 4);
        }
      } else {  // implicit im2col
        if (gm < M && gk < K) {
          const int ox = gm % W, t_ = gm / W;
          const int oy = t_ % H, b = t_ / H;
          const int e = gk >> icb, ic = gk & (IC - 1);
          const int ky = e / 3, kx = e - 3 * (e / 3);
          const int iy = oy + ky - 1, ix = ox + kx - 1;
          if (iy >= 0 && iy < H && ix >= 0 && ix < W) {
            const float* p = A + (((size_t)b * H + iy) * W + ix) * IC + ic;
            x0 = *(const float4*)p; x1 = *(const float4*)(p + 4);
          }
        }
      }
      float v[8] = {x0.x, x0.y, x0.z, x0.w, x1.x, x1.y, x1.z, x1.w};
      u32 hp[4], lp[4];
      split8(v, hp, lp);
      *(uint4*)&Ash[row][kc] = *(uint4*)hp;
      *(uint4*)&Asl[row][kc] = *(uint4*)lp;
    }
    // ---- stage B (pre-split weights) ----
#pragma unroll
    for (int s = 0; s < 2; ++s) {
      const int c = s * 256 + tid;
      const int row = c >> 3, kc = (c & 7) << 3;
      const int gk = k0 + kc;
      uint4 vh = {0u, 0u, 0u, 0u}, vl = {0u, 0u, 0u, 0u};
      if (gk < K) {
        vh = *(const uint4*)&Bh[(size_t)(n0 + row) * K + gk];
        vl = *(const uint4*)&Bl[(size_t)(n0 + row) * K + gk];
      }
      *(uint4*)&Bsh[row][kc] = vh;
      *(uint4*)&Bsl[row][kc] = vl;
    }
    __syncthreads();
#pragma unroll
    for (int kk = 0; kk < 64; kk += 32) {
      const int ko = kk + ((lane >> 4) << 3);
      const int ra0 = wy * 32 + (lane & 15), ra1 = ra0 + 16;
      const int rb0 = wx * 32 + (lane & 15), rb1 = rb0 + 16;
      bf16x8v a0h = *(const bf16x8v*)&Ash[ra0][ko];
      bf16x8v a1h = *(const bf16x8v*)&Ash[ra1][ko];
      bf16x8v b0h = *(const bf16x8v*)&Bsh[rb0][ko];
      bf16x8v b1h = *(const bf16x8v*)&Bsh[rb1][ko];
      bf16x8v a0l = *(const bf16x8v*)&Asl[ra0][ko];
      bf16x8v a1l = *(const bf16x8v*)&Asl[ra1][ko];
      bf16x8v b0l = *(const bf16x8v*)&Bsl[rb0][ko];
      bf16x8v b1l = *(const bf16x8v*)&Bsl[rb1][ko];
      acc[0][0] = __builtin_amdgcn_mfma_f32_16x16x32_bf16(a0h, b0h, acc[0][0], 0, 0, 0);
      acc[0][1] = __builtin_amdgcn_mfma_f32_16x16x32_bf16(a0h, b1h, acc[0][1], 0, 0, 0);
      acc[1][0] = __builtin_amdgcn_mfma_f32_16x16x32_bf16(a1h, b0h, acc[1][0], 0, 0, 0);
      acc[1][1] = __builtin_amdgcn_mfma_f32_16x16x32_bf16(a1h, b1h, acc[1][1], 0, 0, 0);
      acc[0][0] = __builtin_amdgcn_mfma_f32_16x16x32_bf16(a0h, b0l, acc[0][0], 0, 0, 0);
      acc[0][1] = __builtin_amdgcn_mfma_f32_16x16x32_bf16(a0h, b1l, acc[0][1], 0, 0, 0);
      acc[1][0] = __builtin_amdgcn_mfma_f32_16x16x32_bf16(a1h, b0l, acc[1][0], 0, 0, 0);
      acc[1][1] = __builtin_amdgcn_mfma_f32_16x16x32_bf16(a1h, b1l, acc[1][1], 0, 0, 0);
      acc[0][0] = __builtin_amdgcn_mfma_f32_16x16x32_bf16(a0l, b0h, acc[0][0], 0, 0, 0);
      acc[0][1] = __builtin_amdgcn_mfma_f32_16x16x32_bf16(a0l, b1h, acc[0][1], 0, 0, 0);
      acc[1][0] = __builtin_amdgcn_mfma_f32_16x16x32_bf16(a1l, b0h, acc[1][0], 0, 0, 0);
      acc[1][1] = __builtin_amdgcn_mfma_f32_16x16x32_bf16(a1l, b1h, acc[1][1], 0, 0, 0);
    }
    __syncthreads();
  }
  // ---- epilogue (f32 out) ----
#pragma unroll
  for (int r = 0; r < 2; ++r) {
#pragma unroll
    for (int c = 0; c < 2; ++c) {
      const int gn = n0 + wx * 32 + c * 16 + (lane & 15);
      float sc0 = 0.f, sh0 = 0.f;
      if (EPI == 0) { sc0 = p1[gn] * BN_INV; sh0 = p2[gn]; }
#pragma unroll
      for (int i = 0; i < 4; ++i) {
        const int gm = m0 + wy * 32 + r * 16 + ((lane >> 4) << 2) + i;
        if (gm >= M) continue;
        const float a = acc[r][c][i];
        if (EPI == 0) {
          Cout[(size_t)gm * ldc + gn] = fmaxf((a + p0[gn]) * sc0 + sh0, 0.f);
        } else {
          Cout[(size_t)gm * ldc + gn] = a + p0[gn];
        }
      }
    }
  }
}

// ---------------- fused attention per (q,s), all f32 ----------------
__global__ __launch_bounds__(256) void attention_f32(
    const float* __restrict__ proj, const float* __restrict__ featT,
    float* __restrict__ attended) {
  __shared__ float Wq[T49 * 64], Wh[T49 * 64], sc[T49 * 50];
  const int qs = blockIdx.x, q = qs / NS, s = qs % NS;
  const int tid = threadIdx.x;
  const float* pq = proj + (size_t)(NS + q) * T49 * 64;
  const float* ph = proj + (size_t)s * T49 * 64;
  for (int l = tid; l < T49 * 64; l += 256) { Wq[l] = pq[l]; Wh[l] = ph[l]; }
  __syncthreads();
  for (int e = tid; e < T49 * T49; e += 256) {
    const int t = e / T49, u = e % T49;
    const float* a = &Wq[t * 64];
    const float* b = &Wh[u * 64];
    float acc = 0.f;
#pragma unroll 8
    for (int h = 0; h < 64; ++h) acc += tanhf(a[h] * b[h]);
    sc[t * 50 + u] = acc;
  }
  __syncthreads();
  if (tid < T49) {
    float* row = &sc[tid * 50];
    float m = row[0];
    for (int u = 1; u < T49; ++u) m = fmaxf(m, row[u]);
    float ssum = 0.f;
    for (int u = 0; u < T49; ++u) { const float e = expf(row[u] - m); row[u] = e; ssum += e; }
    const float inv = 1.f / ssum;
    for (int u = 0; u < T49; ++u) row[u] *= inv;
  }
  __syncthreads();
  const float* fs = featT + (size_t)s * T49 * 256;
  float* outp = attended + (size_t)qs * T49 * 256;
  for (int t0 = 0; t0 < T49; t0 += 7) {
    float acc[7] = {0.f, 0.f, 0.f, 0.f, 0.f, 0.f, 0.f};
    for (int u = 0; u < T49; ++u) {
      const float v = fs[u * 256 + tid];
#pragma unroll
      for (int i = 0; i < 7; ++i) acc[i] += sc[(t0 + i) * 50 + u] * v;
    }
#pragma unroll
    for (int i = 0; i < 7; ++i) outp[(t0 + i) * 256 + tid] = acc[i];
  }
}

// ---------------- wh (384,128) -> whT (128,384) ----------------
__global__ void transpose_wh(const float* __restrict__ wh,
                             float* __restrict__ whT) {
  const int i = blockIdx.x * 256 + threadIdx.x;
  if (i < 384 * 128) {
    const int j = i % 384, k = i / 384;
    whT[i] = wh[(size_t)j * 128 + k];
  }
}

// ---------------- fp32 GRU layer: one block per sequence, 49 steps ----------
__global__ __launch_bounds__(384) void gru_layer(
    const float* __restrict__ gi, const float* __restrict__ whT,
    const float* __restrict__ bh, float* __restrict__ y, int store_all) {
  __shared__ float hl[128], ghl[384];
  const int b = blockIdx.x, j = threadIdx.x;
  if (j < 128) hl[j] = 0.f;
  __syncthreads();
  const float bhj = bh[j];
  for (int t = 0; t < T49; ++t) {
    float a0 = 0.f, a1 = 0.f, a2 = 0.f, a3 = 0.f;
#pragma unroll 8
    for (int k = 0; k < 128; k += 4) {
      a0 += whT[(size_t)(k + 0) * 384 + j] * hl[k + 0];
      a1 += whT[(size_t)(k + 1) * 384 + j] * hl[k + 1];
      a2 += whT[(size_t)(k + 2) * 384 + j] * hl[k + 2];
      a3 += whT[(size_t)(k + 3) * 384 + j] * hl[k + 3];
    }
    ghl[j] = bhj + ((a0 + a1) + (a2 + a3));
    __syncthreads();
    if (j < 128) {
      const float* gib = gi + ((size_t)b * T49 + t) * 384;
      const float r = 1.f / (1.f + expf(-(gib[j] + ghl[j])));
      const float z = 1.f / (1.f + expf(-(gib[128 + j] + ghl[128 + j])));
      const float n = tanhf(gib[256 + j] + r * ghl[256 + j]);
      const float hn = (1.f - z) * n + z * hl[j];
      hl[j] = hn;
      if (store_all) y[((size_t)b * T49 + t) * 128 + j] = hn;
    }
    __syncthreads();
  }
  if (!store_all && j < 128) y[(size_t)b * 128 + j] = hl[j];
}

// ---------------- head ----------------
__global__ __launch_bounds__(512) void head_kernel(
    const float* __restrict__ hf, const float* __restrict__ tw,
    const float* __restrict__ tb, float* __restrict__ out) {
  __shared__ float lg[B3];
  const int tid = threadIdx.x;
  if (tid < B3) {
    const float* h = hf + (size_t)tid * 128;
    float acc = tb[0];
    for (int k = 0; k < 128; ++k) acc += h[k] * tw[k];
    lg[tid] = acc;
  }
  __syncthreads();
  if (tid < NQ) {
    float cls[5];
#pragma unroll
    for (int n = 0; n < 5; ++n) {
      float s = 0.f;
#pragma unroll
      for (int k = 0; k < 5; ++k) s += lg[tid * 25 + n * 5 + k];
      cls[n] = s;
    }
    float m = cls[0];
#pragma unroll
    for (int n = 1; n < 5; ++n) m = fmaxf(m, cls[n]);
    float se = 0.f;
#pragma unroll
    for (int n = 0; n < 5; ++n) se += expf(cls[n] - m);
    const float lse = m + logf(se);
#pragma unroll
    for (int n = 0; n < 5; ++n) out[tid * 5 + n] = cls[n] - lse;
  }
}

extern "C" void kernel_launch(void* const* d_in, const int* in_sizes, int n_in,
                              void* d_out, int out_size, void* d_ws,
                              size_t ws_size, hipStream_t stream) {
  (void)in_sizes; (void)n_in; (void)out_size; (void)ws_size;
  const float* support = (const float*)d_in[0];
  const float* query   = (const float*)d_in[1];
  const float* cw1 = (const float*)d_in[2];  const float* cb1 = (const float*)d_in[3];
  const float* cw2 = (const float*)d_in[4];  const float* cb2 = (const float*)d_in[5];
  const float* cw3 = (const float*)d_in[6];  const float* cb3 = (const float*)d_in[7];
  const float* cw4 = (const float*)d_in[8];  const float* cb4 = (const float*)d_in[9];
  const float* g1  = (const float*)d_in[10]; const float* be1 = (const float*)d_in[11];
  const float* g2  = (const float*)d_in[12]; const float* be2 = (const float*)d_in[13];
  const float* g3  = (const float*)d_in[14]; const float* be3 = (const float*)d_in[15];
  const float* g4  = (const float*)d_in[16]; const float* be4 = (const float*)d_in[17];
  const float* aw  = (const float*)d_in[18]; const float* ab  = (const float*)d_in[19];
  const float* wi0 = (const float*)d_in[20]; const float* wh0 = (const float*)d_in[21];
  const float* bi0 = (const float*)d_in[22]; const float* bh0 = (const float*)d_in[23];
  const float* wi1 = (const float*)d_in[24]; const float* wh1 = (const float*)d_in[25];
  const float* bi1 = (const float*)d_in[26]; const float* bh1 = (const float*)d_in[27];
  const float* tw  = (const float*)d_in[28]; const float* tb  = (const float*)d_in[29];

  char* ws = (char*)d_ws;
  float* out = (float*)d_out;
  float* A1    = (float*)(ws + A1_OFF);
  float* X2    = (float*)(ws + X2_OFF);
  float* P2    = (float*)(ws + P2_OFF);
  float* X3    = (float*)(ws + X3_OFF);
  float* P3    = (float*)(ws + P3_OFF);
  float* X4    = (float*)(ws + X4_OFF);
  float* FEATT = (float*)(ws + FEATT_OFF);
  float* PROJ  = (float*)(ws + PROJ_OFF);
  float* ATT   = (float*)(ws + ATT_OFF);
  float* GI    = (float*)(ws + GI_OFF);
  float* Y0    = (float*)(ws + Y0_OFF);
  float* HFIN  = (float*)(ws + HFIN_OFF);
  float* WHT0  = (float*)(ws + WHT0_OFF);
  float* WHT1  = (float*)(ws + WHT1_OFF);
  u16* WBH = (u16*)(ws + WBH_OFF);
  u16* WBL = (u16*)(ws + WBL_OFF);

  // weight conversions (split hi/lo)
  cvt_conv_w_split<<<(64 * 288 + 255) / 256, 256, 0, stream>>>(cw2, WBH + W2_E, WBL + W2_E, 64, 32);
  cvt_conv_w_split<<<(128 * 576 + 255) / 256, 256, 0, stream>>>(cw3, WBH + W3_E, WBL + W3_E, 128, 64);
  cvt_conv_w_split<<<(256 * 1152 + 255) / 256, 256, 0, stream>>>(cw4, WBH + W4_E, WBL + W4_E, 256, 128);
  cvt_split<<<(64 * 256 + 255) / 256, 256, 0, stream>>>(aw, WBH + AW_E, WBL + AW_E, 64 * 256);
  cvt_split<<<(384 * 512 + 255) / 256, 256, 0, stream>>>(wi0, WBH + WI0_E, WBL + WI0_E, 384 * 512);
  cvt_split<<<(384 * 128 + 255) / 256, 256, 0, stream>>>(wi1, WBH + WI1_E, WBL + WI1_E, 384 * 128);
  transpose_wh<<<192, 256, 0, stream>>>(wh0, WHT0);
  transpose_wh<<<192, 256, 0, stream>>>(wh1, WHT1);

  // ---- encoder ----
  conv1_pool<<<15680, 256, 0, stream>>>(support, query, cw1, cb1, g1, be1, A1);
  // conv2: A1(40,56,56,32) -> X2(40,56,56,64) -> P2(40,28,28,64)
  sgemm<2, 0><<<dim3(1, 1960), 256, 0, stream>>>(
      A1, nullptr, 125440, 288, WBH + W2_E, WBL + W2_E, cb2, g2, be2, X2, 64,
      56, 56, 32, 5);
  maxpool2_f32<<<1960, 256, 0, stream>>>(X2, P2, NB, 56, 56, 64);
  // conv3: P2 -> X3(40,28,28,128) -> P3(40,14,14,128)
  sgemm<2, 0><<<dim3(2, 490), 256, 0, stream>>>(
      P2, nullptr, 31360, 576, WBH + W3_E, WBL + W3_E, cb3, g3, be3, X3, 128,
      28, 28, 64, 6);
  maxpool2_f32<<<980, 256, 0, stream>>>(X3, P3, NB, 28, 28, 128);
  // conv4: P3 -> X4(40,14,14,256) -> FEATT(40,7,7,256)
  sgemm<2, 0><<<dim3(4, 123), 256, 0, stream>>>(
      P3, nullptr, 7840, 1152, WBH + W4_E, WBL + W4_E, cb4, g4, be4, X4, 256,
      14, 14, 128, 7);
  maxpool2_f32<<<490, 256, 0, stream>>>(X4, FEATT, NB, 14, 14, 256);

  // ---- attention ----
  sgemm<0, 1><<<dim3(1, 31), 256, 0, stream>>>(
      FEATT, nullptr, NB * T49, 256, WBH + AW_E, WBL + AW_E, ab, nullptr,
      nullptr, PROJ, 64, 0, 0, 0, 0);
  attention_f32<<<B3, 256, 0, stream>>>(PROJ, FEATT, ATT);

  // ---- GRU stack ----
  sgemm<1, 1><<<dim3(6, 288), 256, 0, stream>>>(
      ATT, FEATT, B3 * T49, 512, WBH + WI0_E, WBL + WI0_E, bi0, nullptr,
      nullptr, GI, 384, 0, 0, 0, 0);
  gru_layer<<<B3, 384, 0, stream>>>(GI, WHT0, bh0, Y0, 1);
  sgemm<0, 1><<<dim3(6, 288), 256, 0, stream>>>(
      Y0, nullptr, B3 * T49, 128, WBH + WI1_E, WBL + WI1_E, bi1, nullptr,
      nullptr, GI, 384, 0, 0, 0, 0);
  gru_layer<<<B3, 384, 0, stream>>>(GI, WHT1, bh1, HFIN, 0);

  // ---- head ----
  head_kernel<<<1, 512, 0, stream>>>(HFIN, tw, tb, out);
}

// Round 7
// 651.150 us; speedup vs baseline: 5.7914x; 1.1965x over previous
//
#include <hip/hip_runtime.h>
#include <hip/hip_bf16.h>
#include <math.h>

typedef unsigned short u16;
typedef unsigned int u32;
typedef __attribute__((ext_vector_type(8))) short bf16x8v;
typedef __attribute__((ext_vector_type(4))) float f32x4;

// ---------------- problem constants ----------------
constexpr int NS = 25, NQ = 15, NB = 40;
constexpr int B3 = 375;     // 15*25
constexpr int T49 = 49;
constexpr float BN_INV = 0.9999950000374997f;

// ---------------- workspace layout (BYTES), f32 activations ----------------
constexpr size_t A1_OFF    = 0;            // (40,56,56,32) f32 = 16,056,320
constexpr size_t X2_OFF    = 16056320;     // (40,56,56,64) f32 = 32,112,640
constexpr size_t P2_OFF    = 48168960;     // (40,28,28,64) f32 = 8,028,160
constexpr size_t X3_OFF    = 0;            // (40,28,28,128) f32 = 16,056,320
constexpr size_t P3_OFF    = 56197120;     // (40,14,14,128) f32 = 4,014,080
constexpr size_t X4_OFF    = 16056320;     // (40,14,14,256) f32 = 8,028,160
constexpr size_t FEATT_OFF = 60211200;     // (40,49,256) f32 = 2,007,040
constexpr size_t PROJ_OFF  = 24084480;     // (1960,64) f32 = 501,760
constexpr size_t ATT_OFF   = 24586240;     // (375,49,256) f32 = 18,816,000
constexpr size_t GI_OFF    = 62218240;     // (18375,384) f32 = 28,224,000
constexpr size_t Y0_OFF    = 0;            // (18375,128) f32 = 9,408,000
constexpr size_t HFIN_OFF  = 90442240;     // (375,128) f32 = 192,000
constexpr size_t WBH_OFF   = 91027456;     // bf16-hi arena 649,216 u16
constexpr size_t WBL_OFF   = 92325888;     // bf16-lo arena
// u16-element offsets within each arena:
constexpr size_t W2_E = 0;        // 64*288
constexpr size_t W3_E = 18432;    // 128*576
constexpr size_t W4_E = 92160;    // 256*1152
constexpr size_t AW_E = 387072;   // 64*256
constexpr size_t WI0_E = 403456;  // 384*512
constexpr size_t WI1_E = 600064;  // 384*128

static __device__ __forceinline__ u16 f2b(float f) {
  __hip_bfloat16 h = __float2bfloat16(f);
  return *reinterpret_cast<u16*>(&h);
}
static __device__ __forceinline__ float b2f(u16 u) {
  return __uint_as_float((u32)u << 16);
}
// split v into hi+lo bf16 pair, packed into u32 words
static __device__ __forceinline__ void split8(const float* v, u32* hp, u32* lp) {
  u16 h[8], l[8];
#pragma unroll
  for (int j = 0; j < 8; ++j) {
    const u16 hb = f2b(v[j]);
    h[j] = hb;
    l[j] = f2b(v[j] - b2f(hb));
  }
#pragma unroll
  for (int j = 0; j < 4; ++j) {
    hp[j] = (u32)h[2 * j] | ((u32)h[2 * j + 1] << 16);
    lp[j] = (u32)l[2 * j] | ((u32)l[2 * j + 1] << 16);
  }
}

// ---------------- weight split converters ----------------
__global__ void cvt_split(const float* __restrict__ x, u16* __restrict__ oh,
                          u16* __restrict__ ol, int n) {
  int i = blockIdx.x * 256 + threadIdx.x;
  if (i >= n) return;
  const float v = x[i];
  const u16 h = f2b(v);
  oh[i] = h;
  ol[i] = f2b(v - b2f(h));
}
// OIHW f32 -> [oc][(ky*3+kx)*IC + ic] hi/lo bf16
__global__ void cvt_conv_w_split(const float* __restrict__ w, u16* __restrict__ oh,
                                 u16* __restrict__ ol, int OC, int IC) {
  const int n = OC * IC * 9;
  int i = blockIdx.x * 256 + threadIdx.x;
  if (i >= n) return;
  const int oc = i / (IC * 9), rem = i % (IC * 9);
  const int e = rem / IC, ic = rem % IC;
  const int ky = e / 3, kx = e % 3;
  const float v = w[((size_t)(oc * IC + ic) * 3 + ky) * 3 + kx];
  const u16 h = f2b(v);
  oh[i] = h;
  ol[i] = f2b(v - b2f(h));
}

// ---------------- fused conv1(s2)+BN+ReLU+pool2, f32 out NHWC ----------------
__global__ __launch_bounds__(256) void conv1_pool(
    const float* __restrict__ support, const float* __restrict__ query,
    const float* __restrict__ w1, const float* __restrict__ cb1,
    const float* __restrict__ g1, const float* __restrict__ be1,
    float* __restrict__ out) {
  __shared__ float wl[288], scl[32], shl[32], cbl[32];
  const int tid = threadIdx.x;
  for (int l = tid; l < 288; l += 256) wl[l] = w1[l];  // FIX(r5): strided, 288>256
  if (tid < 32) { scl[tid] = g1[tid] * BN_INV; shl[tid] = be1[tid]; cbl[tid] = cb1[tid]; }
  __syncthreads();
  const int oc = tid & 31;
  const int p = blockIdx.x * 8 + (tid >> 5);   // 0 .. 125439 = (b,oy,ox)
  const int ox = p % 56, oy = (p / 56) % 56, b = p / 3136;
  const float* in_b = (b < NS) ? (support + (size_t)b * 50176)
                               : (query + (size_t)(b - NS) * 50176);
  const int iy0 = 4 * oy - 1, ix0 = 4 * ox - 1;
  float pat[5][5];
#pragma unroll
  for (int dy = 0; dy < 5; ++dy) {
    const int iy = iy0 + dy;
#pragma unroll
    for (int dx = 0; dx < 5; ++dx) {
      const int ix = ix0 + dx;
      pat[dy][dx] = (iy >= 0 && iy < 224 && ix >= 0 && ix < 224)
                        ? in_b[(size_t)iy * 224 + ix] : 0.f;
    }
  }
  const float* wp = &wl[oc * 9];
  float mx = 0.f;  // post-ReLU values >= 0
#pragma unroll
  for (int py = 0; py < 2; ++py)
#pragma unroll
    for (int px = 0; px < 2; ++px) {
      float acc = 0.f;
#pragma unroll
      for (int ky = 0; ky < 3; ++ky)
#pragma unroll
        for (int kx = 0; kx < 3; ++kx)
          acc += pat[2 * py + ky][2 * px + kx] * wp[ky * 3 + kx];
      float v = (acc + cbl[oc]) * scl[oc] + shl[oc];
      mx = fmaxf(mx, v);
    }
  out[(size_t)p * 32 + oc] = mx;
}

// ---------------- f32 NHWC maxpool 2x2 ----------------
__global__ void maxpool2_f32(const float* __restrict__ X, float* __restrict__ Y,
                             int Bn, int H, int W, int C) {
  const int OH = H >> 1, OW = W >> 1;
  const int cpr = C >> 2;
  const int chunks = Bn * OH * OW * cpr;
  for (int i = blockIdx.x * blockDim.x + threadIdx.x; i < chunks;
       i += gridDim.x * blockDim.x) {
    const int c4 = i % cpr, m = i / cpr;
    const int ox = m % OW, oy = (m / OW) % OH, b = m / (OW * OH);
    const size_t base = (((size_t)b * H + 2 * oy) * W + 2 * ox) * C + (c4 << 2);
    const float4 r0 = *(const float4*)&X[base];
    const float4 r1 = *(const float4*)&X[base + C];
    const float4 r2 = *(const float4*)&X[base + (size_t)W * C];
    const float4 r3 = *(const float4*)&X[base + (size_t)W * C + C];
    float4 o;
    o.x = fmaxf(fmaxf(r0.x, r1.x), fmaxf(r2.x, r3.x));
    o.y = fmaxf(fmaxf(r0.y, r1.y), fmaxf(r2.y, r3.y));
    o.z = fmaxf(fmaxf(r0.z, r1.z), fmaxf(r2.z, r3.z));
    o.w = fmaxf(fmaxf(r0.w, r1.w), fmaxf(r2.w, r3.w));
    *(float4*)&Y[(size_t)m * C + (c4 << 2)] = o;
  }
}

// ---------------- split-bf16 MFMA GEMM: C = epi(A @ W^T) --------------------
// 3-pass Dekker: acc += Ah*Wh + Ah*Wl + Al*Wh  (error ~1.6e-5 relative)
// AMODE 0: A f32 (M x K) contiguous.
// AMODE 1: K=512 concat gather: k<256 -> A(=ATT f32), else A2(=FEATT f32) qrep.
// AMODE 2: implicit im2col from A = NHWC f32 (Bn,H,W,IC); K = 9*IC; pad=1.
// EPI 0: f32 out = relu((acc+p0[n])*p1[n]*BN_INV + p2[n]).  EPI 1: f32 out = acc+p0[n].
template <int AMODE, int EPI>
__global__ __launch_bounds__(256) void sgemm(
    const float* __restrict__ A, const float* __restrict__ A2, int M, int K,
    const u16* __restrict__ Bh, const u16* __restrict__ Bl,
    const float* __restrict__ p0, const float* __restrict__ p1,
    const float* __restrict__ p2, float* __restrict__ Cout, int ldc,
    int H, int W, int IC, int icb) {
  __shared__ u16 Ash[64][72], Asl[64][72];
  __shared__ u16 Bsh[64][72], Bsl[64][72];
  const int tid = threadIdx.x;
  const int lane = tid & 63, wv = tid >> 6;
  const int wy = wv >> 1, wx = wv & 1;
  const int n0 = blockIdx.x * 64, m0 = blockIdx.y * 64;
  f32x4 acc[2][2] = {{{0, 0, 0, 0}, {0, 0, 0, 0}}, {{0, 0, 0, 0}, {0, 0, 0, 0}}};
  for (int k0 = 0; k0 < K; k0 += 64) {
    // ---- stage A (split f32 -> hi/lo bf16) ----
#pragma unroll
    for (int s = 0; s < 2; ++s) {
      const int c = s * 256 + tid;
      const int row = c >> 3, kc = (c & 7) << 3;
      const int gm = m0 + row, gk = k0 + kc;
      float4 x0 = {0, 0, 0, 0}, x1 = {0, 0, 0, 0};
      if (AMODE == 0) {
        if (gm < M && gk < K) {
          const float* p = A + (size_t)gm * K + gk;
          x0 = *(const float4*)p; x1 = *(const float4*)(p + 4);
        }
      } else if (AMODE == 1) {
        if (gm < M) {
          const float* p;
          if (gk < 256) {
            p = A + (size_t)gm * 256 + gk;
          } else {
            const int b = gm / T49, t = gm % T49, q = b / NS;
            p = A2 + (((size_t)(NS + q) * T49 + t) << 8) + (gk - 256);
          }
          x0 = *(const float4*)p; x1 = *(const float4*)(p + 4);
        }
      } else {  // implicit im2col
        if (gm < M && gk < K) {
          const int ox = gm % W, t_ = gm / W;
          const int oy = t_ % H, b = t_ / H;
          const int e = gk >> icb, ic = gk & (IC - 1);
          const int ky = e / 3, kx = e - 3 * (e / 3);
          const int iy = oy + ky - 1, ix = ox + kx - 1;
          if (iy >= 0 && iy < H && ix >= 0 && ix < W) {
            const float* p = A + (((size_t)b * H + iy) * W + ix) * IC + ic;
            x0 = *(const float4*)p; x1 = *(const float4*)(p + 4);
          }
        }
      }
      float v[8] = {x0.x, x0.y, x0.z, x0.w, x1.x, x1.y, x1.z, x1.w};
      u32 hp[4], lp[4];
      split8(v, hp, lp);
      *(uint4*)&Ash[row][kc] = *(uint4*)hp;
      *(uint4*)&Asl[row][kc] = *(uint4*)lp;
    }
    // ---- stage B (pre-split weights) ----
#pragma unroll
    for (int s = 0; s < 2; ++s) {
      const int c = s * 256 + tid;
      const int row = c >> 3, kc = (c & 7) << 3;
      const int gk = k0 + kc;
      uint4 vh = {0u, 0u, 0u, 0u}, vl = {0u, 0u, 0u, 0u};
      if (gk < K) {
        vh = *(const uint4*)&Bh[(size_t)(n0 + row) * K + gk];
        vl = *(const uint4*)&Bl[(size_t)(n0 + row) * K + gk];
      }
      *(uint4*)&Bsh[row][kc] = vh;
      *(uint4*)&Bsl[row][kc] = vl;
    }
    __syncthreads();
#pragma unroll
    for (int kk = 0; kk < 64; kk += 32) {
      const int ko = kk + ((lane >> 4) << 3);
      const int ra0 = wy * 32 + (lane & 15), ra1 = ra0 + 16;
      const int rb0 = wx * 32 + (lane & 15), rb1 = rb0 + 16;
      bf16x8v a0h = *(const bf16x8v*)&Ash[ra0][ko];
      bf16x8v a1h = *(const bf16x8v*)&Ash[ra1][ko];
      bf16x8v b0h = *(const bf16x8v*)&Bsh[rb0][ko];
      bf16x8v b1h = *(const bf16x8v*)&Bsh[rb1][ko];
      bf16x8v a0l = *(const bf16x8v*)&Asl[ra0][ko];
      bf16x8v a1l = *(const bf16x8v*)&Asl[ra1][ko];
      bf16x8v b0l = *(const bf16x8v*)&Bsl[rb0][ko];
      bf16x8v b1l = *(const bf16x8v*)&Bsl[rb1][ko];
      acc[0][0] = __builtin_amdgcn_mfma_f32_16x16x32_bf16(a0h, b0h, acc[0][0], 0, 0, 0);
      acc[0][1] = __builtin_amdgcn_mfma_f32_16x16x32_bf16(a0h, b1h, acc[0][1], 0, 0, 0);
      acc[1][0] = __builtin_amdgcn_mfma_f32_16x16x32_bf16(a1h, b0h, acc[1][0], 0, 0, 0);
      acc[1][1] = __builtin_amdgcn_mfma_f32_16x16x32_bf16(a1h, b1h, acc[1][1], 0, 0, 0);
      acc[0][0] = __builtin_amdgcn_mfma_f32_16x16x32_bf16(a0h, b0l, acc[0][0], 0, 0, 0);
      acc[0][1] = __builtin_amdgcn_mfma_f32_16x16x32_bf16(a0h, b1l, acc[0][1], 0, 0, 0);
      acc[1][0] = __builtin_amdgcn_mfma_f32_16x16x32_bf16(a1h, b0l, acc[1][0], 0, 0, 0);
      acc[1][1] = __builtin_amdgcn_mfma_f32_16x16x32_bf16(a1h, b1l, acc[1][1], 0, 0, 0);
      acc[0][0] = __builtin_amdgcn_mfma_f32_16x16x32_bf16(a0l, b0h, acc[0][0], 0, 0, 0);
      acc[0][1] = __builtin_amdgcn_mfma_f32_16x16x32_bf16(a0l, b1h, acc[0][1], 0, 0, 0);
      acc[1][0] = __builtin_amdgcn_mfma_f32_16x16x32_bf16(a1l, b0h, acc[1][0], 0, 0, 0);
      acc[1][1] = __builtin_amdgcn_mfma_f32_16x16x32_bf16(a1l, b1h, acc[1][1], 0, 0, 0);
    }
    __syncthreads();
  }
  // ---- epilogue (f32 out) ----
#pragma unroll
  for (int r = 0; r < 2; ++r) {
#pragma unroll
    for (int c = 0; c < 2; ++c) {
      const int gn = n0 + wx * 32 + c * 16 + (lane & 15);
      float sc0 = 0.f, sh0 = 0.f;
      if (EPI == 0) { sc0 = p1[gn] * BN_INV; sh0 = p2[gn]; }
#pragma unroll
      for (int i = 0; i < 4; ++i) {
        const int gm = m0 + wy * 32 + r * 16 + ((lane >> 4) << 2) + i;
        if (gm >= M) continue;
        const float a = acc[r][c][i];
        if (EPI == 0) {
          Cout[(size_t)gm * ldc + gn] = fmaxf((a + p0[gn]) * sc0 + sh0, 0.f);
        } else {
          Cout[(size_t)gm * ldc + gn] = a + p0[gn];
        }
      }
    }
  }
}

// ---------------- fused attention per (q,s), all f32 ----------------
__global__ __launch_bounds__(256) void attention_f32(
    const float* __restrict__ proj, const float* __restrict__ featT,
    float* __restrict__ attended) {
  __shared__ float Wq[T49 * 64], Wh[T49 * 64], sc[T49 * 50];
  const int qs = blockIdx.x, q = qs / NS, s = qs % NS;
  const int tid = threadIdx.x;
  const float* pq = proj + (size_t)(NS + q) * T49 * 64;
  const float* ph = proj + (size_t)s * T49 * 64;
  for (int l = tid; l < T49 * 64; l += 256) { Wq[l] = pq[l]; Wh[l] = ph[l]; }
  __syncthreads();
  for (int e = tid; e < T49 * T49; e += 256) {
    const int t = e / T49, u = e % T49;
    const float* a = &Wq[t * 64];
    const float* b = &Wh[u * 64];
    float acc = 0.f;
#pragma unroll 8
    for (int h = 0; h < 64; ++h) acc += tanhf(a[h] * b[h]);
    sc[t * 50 + u] = acc;
  }
  __syncthreads();
  if (tid < T49) {
    float* row = &sc[tid * 50];
    float m = row[0];
    for (int u = 1; u < T49; ++u) m = fmaxf(m, row[u]);
    float ssum = 0.f;
    for (int u = 0; u < T49; ++u) { const float e = expf(row[u] - m); row[u] = e; ssum += e; }
    const float inv = 1.f / ssum;
    for (int u = 0; u < T49; ++u) row[u] *= inv;
  }
  __syncthreads();
  const float* fs = featT + (size_t)s * T49 * 256;
  float* outp = attended + (size_t)qs * T49 * 256;
  for (int t0 = 0; t0 < T49; t0 += 7) {
    float acc[7] = {0.f, 0.f, 0.f, 0.f, 0.f, 0.f, 0.f};
    for (int u = 0; u < T49; ++u) {
      const float v = fs[u * 256 + tid];
#pragma unroll
      for (int i = 0; i < 7; ++i) acc[i] += sc[(t0 + i) * 50 + u] * v;
    }
#pragma unroll
    for (int i = 0; i < 7; ++i) outp[(t0 + i) * 256 + tid] = acc[i];
  }
}

// ---------------- batched split-bf16 MFMA GRU ----------------
// 24 blocks x 512 threads (8 waves), 16 sequences/block (M=16 MFMA tile).
// Wh (384x128) split hi/lo bf16 held in REGISTERS per wave (3 n-frags x 4 kk):
// zero Wh memory traffic in the 49-step loop (was 3.6 GB L2/layer). h carried
// f32 in LDS; hi/lo split feeds the same 3-pass Dekker MFMA as sgemm.
__global__ __launch_bounds__(512) void gru_mfma(
    const float* __restrict__ gi,   // (375,49,384), includes bi
    const float* __restrict__ wh,   // (384,128) f32
    const float* __restrict__ bh,   // (384)
    float* __restrict__ y,          // (375,49,128) if store_all else (375,128)
    int store_all) {
  __shared__ u16 hah[16][136], hal[16][136];
  __shared__ float ghs[16][384];
  __shared__ float hfl[16][128];
  const int tid = threadIdx.x;
  const int lane = tid & 63, wv = tid >> 6;   // 8 waves
  const int r0 = blockIdx.x * 16;
  // ---- one-time: load + split Wh fragments into registers ----
  bf16x8v Bhr[3][4], Blr[3][4];
#pragma unroll
  for (int f = 0; f < 3; ++f) {
    const int n = (wv * 3 + f) * 16 + (lane & 15);
#pragma unroll
    for (int kk = 0; kk < 4; ++kk) {
      const int k = kk * 32 + ((lane >> 4) << 3);
      const float* p = wh + (size_t)n * 128 + k;
      float v[8];
      *(float4*)&v[0] = *(const float4*)p;
      *(float4*)&v[4] = *(const float4*)(p + 4);
      u32 hp[4], lp[4];
      split8(v, hp, lp);
      Bhr[f][kk] = *(bf16x8v*)hp;
      Blr[f][kk] = *(bf16x8v*)lp;
    }
  }
  // ---- preload bh for this thread's 4 gate slots ----
  float bhr[4], bhz[4], bhn[4];
#pragma unroll
  for (int u = 0; u < 4; ++u) {
    const int j = ((u << 9) + tid) & 127;
    bhr[u] = bh[j]; bhz[u] = bh[128 + j]; bhn[u] = bh[256 + j];
  }
  // ---- init state ----
  for (int i = tid; i < 16 * 136; i += 512) { hah[i / 136][i % 136] = 0; hal[i / 136][i % 136] = 0; }
  for (int i = tid; i < 16 * 128; i += 512) hfl[i >> 7][i & 127] = 0.f;
  __syncthreads();
  const int ar = lane & 15, ko = (lane >> 4) << 3;
  for (int t = 0; t < T49; ++t) {
    // prefetch gi for this step (consumed after MFMA phase)
    float xr[4], xz[4], xn[4];
#pragma unroll
    for (int u = 0; u < 4; ++u) {
      const int idx = (u << 9) + tid;
      const int row = idx >> 7, j = idx & 127;
      int sq = r0 + row; if (sq >= B3) sq = B3 - 1;
      const float* gib = gi + ((size_t)sq * T49 + t) * 384;
      xr[u] = gib[j]; xz[u] = gib[128 + j]; xn[u] = gib[256 + j];
    }
    // A-frags (h hi/lo) from LDS
    bf16x8v Ah[4], Al[4];
#pragma unroll
    for (int kk = 0; kk < 4; ++kk) {
      Ah[kk] = *(const bf16x8v*)&hah[ar][kk * 32 + ko];
      Al[kk] = *(const bf16x8v*)&hal[ar][kk * 32 + ko];
    }
    // gh = h @ Wh^T (3-pass Dekker)
#pragma unroll
    for (int f = 0; f < 3; ++f) {
      f32x4 acc = {0, 0, 0, 0};
#pragma unroll
      for (int kk = 0; kk < 4; ++kk)
        acc = __builtin_amdgcn_mfma_f32_16x16x32_bf16(Ah[kk], Bhr[f][kk], acc, 0, 0, 0);
#pragma unroll
      for (int kk = 0; kk < 4; ++kk)
        acc = __builtin_amdgcn_mfma_f32_16x16x32_bf16(Ah[kk], Blr[f][kk], acc, 0, 0, 0);
#pragma unroll
      for (int kk = 0; kk < 4; ++kk)
        acc = __builtin_amdgcn_mfma_f32_16x16x32_bf16(Al[kk], Bhr[f][kk], acc, 0, 0, 0);
      const int nc = (wv * 3 + f) * 16 + (lane & 15);
      const int rb = (lane >> 4) << 2;
#pragma unroll
      for (int i = 0; i < 4; ++i) ghs[rb + i][nc] = acc[i];
    }
    __syncthreads();
    // fused gate math
#pragma unroll
    for (int u = 0; u < 4; ++u) {
      const int idx = (u << 9) + tid;
      const int row = idx >> 7, j = idx & 127;
      const int seq = r0 + row;
      const float r_ = 1.f / (1.f + expf(-(xr[u] + ghs[row][j] + bhr[u])));
      const float z_ = 1.f / (1.f + expf(-(xz[u] + ghs[row][128 + j] + bhz[u])));
      const float n_ = tanhf(xn[u] + r_ * (ghs[row][256 + j] + bhn[u]));
      const float hp = hfl[row][j];
      const float hn = (1.f - z_) * n_ + z_ * hp;
      hfl[row][j] = hn;
      const u16 hb = f2b(hn);
      hah[row][j] = hb;
      hal[row][j] = f2b(hn - b2f(hb));
      if (seq < B3) {
        if (store_all) y[((size_t)seq * T49 + t) * 128 + j] = hn;
        else if (t == T49 - 1) y[(size_t)seq * 128 + j] = hn;
      }
    }
    __syncthreads();
  }
}

// ---------------- head ----------------
__global__ __launch_bounds__(512) void head_kernel(
    const float* __restrict__ hf, const float* __restrict__ tw,
    const float* __restrict__ tb, float* __restrict__ out) {
  __shared__ float lg[B3];
  const int tid = threadIdx.x;
  if (tid < B3) {
    const float* h = hf + (size_t)tid * 128;
    float acc = tb[0];
    for (int k = 0; k < 128; ++k) acc += h[k] * tw[k];
    lg[tid] = acc;
  }
  __syncthreads();
  if (tid < NQ) {
    float cls[5];
#pragma unroll
    for (int n = 0; n < 5; ++n) {
      float s = 0.f;
#pragma unroll
      for (int k = 0; k < 5; ++k) s += lg[tid * 25 + n * 5 + k];
      cls[n] = s;
    }
    float m = cls[0];
#pragma unroll
    for (int n = 1; n < 5; ++n) m = fmaxf(m, cls[n]);
    float se = 0.f;
#pragma unroll
    for (int n = 0; n < 5; ++n) se += expf(cls[n] - m);
    const float lse = m + logf(se);
#pragma unroll
    for (int n = 0; n < 5; ++n) out[tid * 5 + n] = cls[n] - lse;
  }
}

extern "C" void kernel_launch(void* const* d_in, const int* in_sizes, int n_in,
                              void* d_out, int out_size, void* d_ws,
                              size_t ws_size, hipStream_t stream) {
  (void)in_sizes; (void)n_in; (void)out_size; (void)ws_size;
  const float* support = (const float*)d_in[0];
  const float* query   = (const float*)d_in[1];
  const float* cw1 = (const float*)d_in[2];  const float* cb1 = (const float*)d_in[3];
  const float* cw2 = (const float*)d_in[4];  const float* cb2 = (const float*)d_in[5];
  const float* cw3 = (const float*)d_in[6];  const float* cb3 = (const float*)d_in[7];
  const float* cw4 = (const float*)d_in[8];  const float* cb4 = (const float*)d_in[9];
  const float* g1  = (const float*)d_in[10]; const float* be1 = (const float*)d_in[11];
  const float* g2  = (const float*)d_in[12]; const float* be2 = (const float*)d_in[13];
  const float* g3  = (const float*)d_in[14]; const float* be3 = (const float*)d_in[15];
  const float* g4  = (const float*)d_in[16]; const float* be4 = (const float*)d_in[17];
  const float* aw  = (const float*)d_in[18]; const float* ab  = (const float*)d_in[19];
  const float* wi0 = (const float*)d_in[20]; const float* wh0 = (const float*)d_in[21];
  const float* bi0 = (const float*)d_in[22]; const float* bh0 = (const float*)d_in[23];
  const float* wi1 = (const float*)d_in[24]; const float* wh1 = (const float*)d_in[25];
  const float* bi1 = (const float*)d_in[26]; const float* bh1 = (const float*)d_in[27];
  const float* tw  = (const float*)d_in[28]; const float* tb  = (const float*)d_in[29];

  char* ws = (char*)d_ws;
  float* out = (float*)d_out;
  float* A1    = (float*)(ws + A1_OFF);
  float* X2    = (float*)(ws + X2_OFF);
  float* P2    = (float*)(ws + P2_OFF);
  float* X3    = (float*)(ws + X3_OFF);
  float* P3    = (float*)(ws + P3_OFF);
  float* X4    = (float*)(ws + X4_OFF);
  float* FEATT = (float*)(ws + FEATT_OFF);
  float* PROJ  = (float*)(ws + PROJ_OFF);
  float* ATT   = (float*)(ws + ATT_OFF);
  float* GI    = (float*)(ws + GI_OFF);
  float* Y0    = (float*)(ws + Y0_OFF);
  float* HFIN  = (float*)(ws + HFIN_OFF);
  u16* WBH = (u16*)(ws + WBH_OFF);
  u16* WBL = (u16*)(ws + WBL_OFF);

  // weight conversions (split hi/lo)
  cvt_conv_w_split<<<(64 * 288 + 255) / 256, 256, 0, stream>>>(cw2, WBH + W2_E, WBL + W2_E, 64, 32);
  cvt_conv_w_split<<<(128 * 576 + 255) / 256, 256, 0, stream>>>(cw3, WBH + W3_E, WBL + W3_E, 128, 64);
  cvt_conv_w_split<<<(256 * 1152 + 255) / 256, 256, 0, stream>>>(cw4, WBH + W4_E, WBL + W4_E, 256, 128);
  cvt_split<<<(64 * 256 + 255) / 256, 256, 0, stream>>>(aw, WBH + AW_E, WBL + AW_E, 64 * 256);
  cvt_split<<<(384 * 512 + 255) / 256, 256, 0, stream>>>(wi0, WBH + WI0_E, WBL + WI0_E, 384 * 512);
  cvt_split<<<(384 * 128 + 255) / 256, 256, 0, stream>>>(wi1, WBH + WI1_E, WBL + WI1_E, 384 * 128);

  // ---- encoder ----
  conv1_pool<<<15680, 256, 0, stream>>>(support, query, cw1, cb1, g1, be1, A1);
  // conv2: A1(40,56,56,32) -> X2(40,56,56,64) -> P2(40,28,28,64)
  sgemm<2, 0><<<dim3(1, 1960), 256, 0, stream>>>(
      A1, nullptr, 125440, 288, WBH + W2_E, WBL + W2_E, cb2, g2, be2, X2, 64,
      56, 56, 32, 5);
  maxpool2_f32<<<1960, 256, 0, stream>>>(X2, P2, NB, 56, 56, 64);
  // conv3: P2 -> X3(40,28,28,128) -> P3(40,14,14,128)
  sgemm<2, 0><<<dim3(2, 490), 256, 0, stream>>>(
      P2, nullptr, 31360, 576, WBH + W3_E, WBL + W3_E, cb3, g3, be3, X3, 128,
      28, 28, 64, 6);
  maxpool2_f32<<<980, 256, 0, stream>>>(X3, P3, NB, 28, 28, 128);
  // conv4: P3 -> X4(40,14,14,256) -> FEATT(40,7,7,256)
  sgemm<2, 0><<<dim3(4, 123), 256, 0, stream>>>(
      P3, nullptr, 7840, 1152, WBH + W4_E, WBL + W4_E, cb4, g4, be4, X4, 256,
      14, 14, 128, 7);
  maxpool2_f32<<<490, 256, 0, stream>>>(X4, FEATT, NB, 14, 14, 256);

  // ---- attention ----
  sgemm<0, 1><<<dim3(1, 31), 256, 0, stream>>>(
      FEATT, nullptr, NB * T49, 256, WBH + AW_E, WBL + AW_E, ab, nullptr,
      nullptr, PROJ, 64, 0, 0, 0, 0);
  attention_f32<<<B3, 256, 0, stream>>>(PROJ, FEATT, ATT);

  // ---- GRU stack ----
  sgemm<1, 1><<<dim3(6, 288), 256, 0, stream>>>(
      ATT, FEATT, B3 * T49, 512, WBH + WI0_E, WBL + WI0_E, bi0, nullptr,
      nullptr, GI, 384, 0, 0, 0, 0);
  gru_mfma<<<24, 512, 0, stream>>>(GI, wh0, bh0, Y0, 1);
  sgemm<0, 1><<<dim3(6, 288), 256, 0, stream>>>(
      Y0, nullptr, B3 * T49, 128, WBH + WI1_E, WBL + WI1_E, bi1, nullptr,
      nullptr, GI, 384, 0, 0, 0, 0);
  gru_mfma<<<24, 512, 0, stream>>>(GI, wh1, bh1, HFIN, 0);

  // ---- head ----
  head_kernel<<<1, 512, 0, stream>>>(HFIN, tw, tb, out);
}

// Round 8
// 573.511 us; speedup vs baseline: 6.5754x; 1.1354x over previous
//
#include <hip/hip_runtime.h>
#include <hip/hip_bf16.h>
#include <math.h>

typedef unsigned short u16;
typedef unsigned int u32;
typedef __attribute__((ext_vector_type(8))) short bf16x8v;
typedef __attribute__((ext_vector_type(4))) float f32x4;

// ---------------- problem constants ----------------
constexpr int NS = 25, NQ = 15, NB = 40;
constexpr int B3 = 375;     // 15*25
constexpr int T49 = 49;
constexpr float BN_INV = 0.9999950000374997f;

// ---------------- workspace layout (BYTES), f32 activations ----------------
constexpr size_t A1_OFF    = 0;            // (40,56,56,32) f32 = 16,056,320
constexpr size_t X2_OFF    = 16056320;     // (40,56,56,64) f32 = 32,112,640
constexpr size_t P2_OFF    = 48168960;     // (40,28,28,64) f32 = 8,028,160
constexpr size_t X3_OFF    = 0;            // (40,28,28,128) f32 = 16,056,320
constexpr size_t P3_OFF    = 56197120;     // (40,14,14,128) f32 = 4,014,080
constexpr size_t X4_OFF    = 16056320;     // (40,14,14,256) f32 = 8,028,160
constexpr size_t FEATT_OFF = 60211200;     // (40,49,256) f32 = 2,007,040
constexpr size_t PROJ_OFF  = 24084480;     // (1960,64) f32 = 501,760
constexpr size_t ATT_OFF   = 24586240;     // (375,49,256) f32 = 18,816,000
constexpr size_t GI_OFF    = 62218240;     // (18375,384) f32 = 28,224,000
constexpr size_t Y0_OFF    = 0;            // (18375,128) f32 = 9,408,000
constexpr size_t HFIN_OFF  = 90442240;     // (375,128) f32 = 192,000
constexpr size_t WBH_OFF   = 91027456;     // bf16-hi arena 649,216 u16
constexpr size_t WBL_OFF   = 92325888;     // bf16-lo arena
// u16-element offsets within each arena:
constexpr size_t W2_E = 0;        // 64*288
constexpr size_t W3_E = 18432;    // 128*576
constexpr size_t W4_E = 92160;    // 256*1152
constexpr size_t AW_E = 387072;   // 64*256
constexpr size_t WI0_E = 403456;  // 384*512
constexpr size_t WI1_E = 600064;  // 384*128

static __device__ __forceinline__ u16 f2b(float f) {
  __hip_bfloat16 h = __float2bfloat16(f);
  return *reinterpret_cast<u16*>(&h);
}
static __device__ __forceinline__ float b2f(u16 u) {
  return __uint_as_float((u32)u << 16);
}
// split v into hi+lo bf16 pair, packed into u32 words
static __device__ __forceinline__ void split8(const float* v, u32* hp, u32* lp) {
  u16 h[8], l[8];
#pragma unroll
  for (int j = 0; j < 8; ++j) {
    const u16 hb = f2b(v[j]);
    h[j] = hb;
    l[j] = f2b(v[j] - b2f(hb));
  }
#pragma unroll
  for (int j = 0; j < 4; ++j) {
    hp[j] = (u32)h[2 * j] | ((u32)h[2 * j + 1] << 16);
    lp[j] = (u32)l[2 * j] | ((u32)l[2 * j + 1] << 16);
  }
}

// ---------------- weight split converters ----------------
__global__ void cvt_split(const float* __restrict__ x, u16* __restrict__ oh,
                          u16* __restrict__ ol, int n) {
  int i = blockIdx.x * 256 + threadIdx.x;
  if (i >= n) return;
  const float v = x[i];
  const u16 h = f2b(v);
  oh[i] = h;
  ol[i] = f2b(v - b2f(h));
}
// OIHW f32 -> [oc][(ky*3+kx)*IC + ic] hi/lo bf16
__global__ void cvt_conv_w_split(const float* __restrict__ w, u16* __restrict__ oh,
                                 u16* __restrict__ ol, int OC, int IC) {
  const int n = OC * IC * 9;
  int i = blockIdx.x * 256 + threadIdx.x;
  if (i >= n) return;
  const int oc = i / (IC * 9), rem = i % (IC * 9);
  const int e = rem / IC, ic = rem % IC;
  const int ky = e / 3, kx = e % 3;
  const float v = w[((size_t)(oc * IC + ic) * 3 + ky) * 3 + kx];
  const u16 h = f2b(v);
  oh[i] = h;
  ol[i] = f2b(v - b2f(h));
}

// ---------------- fused conv1(s2)+BN+ReLU+pool2, f32 out NHWC ----------------
__global__ __launch_bounds__(256) void conv1_pool(
    const float* __restrict__ support, const float* __restrict__ query,
    const float* __restrict__ w1, const float* __restrict__ cb1,
    const float* __restrict__ g1, const float* __restrict__ be1,
    float* __restrict__ out) {
  __shared__ float wl[288], scl[32], shl[32], cbl[32];
  const int tid = threadIdx.x;
  for (int l = tid; l < 288; l += 256) wl[l] = w1[l];  // FIX(r5): strided, 288>256
  if (tid < 32) { scl[tid] = g1[tid] * BN_INV; shl[tid] = be1[tid]; cbl[tid] = cb1[tid]; }
  __syncthreads();
  const int oc = tid & 31;
  const int p = blockIdx.x * 8 + (tid >> 5);   // 0 .. 125439 = (b,oy,ox)
  const int ox = p % 56, oy = (p / 56) % 56, b = p / 3136;
  const float* in_b = (b < NS) ? (support + (size_t)b * 50176)
                               : (query + (size_t)(b - NS) * 50176);
  const int iy0 = 4 * oy - 1, ix0 = 4 * ox - 1;
  float pat[5][5];
#pragma unroll
  for (int dy = 0; dy < 5; ++dy) {
    const int iy = iy0 + dy;
#pragma unroll
    for (int dx = 0; dx < 5; ++dx) {
      const int ix = ix0 + dx;
      pat[dy][dx] = (iy >= 0 && iy < 224 && ix >= 0 && ix < 224)
                        ? in_b[(size_t)iy * 224 + ix] : 0.f;
    }
  }
  const float* wp = &wl[oc * 9];
  float mx = 0.f;  // post-ReLU values >= 0
#pragma unroll
  for (int py = 0; py < 2; ++py)
#pragma unroll
    for (int px = 0; px < 2; ++px) {
      float acc = 0.f;
#pragma unroll
      for (int ky = 0; ky < 3; ++ky)
#pragma unroll
        for (int kx = 0; kx < 3; ++kx)
          acc += pat[2 * py + ky][2 * px + kx] * wp[ky * 3 + kx];
      float v = (acc + cbl[oc]) * scl[oc] + shl[oc];
      mx = fmaxf(mx, v);
    }
  out[(size_t)p * 32 + oc] = mx;
}

// ---------------- f32 NHWC maxpool 2x2 ----------------
__global__ void maxpool2_f32(const float* __restrict__ X, float* __restrict__ Y,
                             int Bn, int H, int W, int C) {
  const int OH = H >> 1, OW = W >> 1;
  const int cpr = C >> 2;
  const int chunks = Bn * OH * OW * cpr;
  for (int i = blockIdx.x * blockDim.x + threadIdx.x; i < chunks;
       i += gridDim.x * blockDim.x) {
    const int c4 = i % cpr, m = i / cpr;
    const int ox = m % OW, oy = (m / OW) % OH, b = m / (OW * OH);
    const size_t base = (((size_t)b * H + 2 * oy) * W + 2 * ox) * C + (c4 << 2);
    const float4 r0 = *(const float4*)&X[base];
    const float4 r1 = *(const float4*)&X[base + C];
    const float4 r2 = *(const float4*)&X[base + (size_t)W * C];
    const float4 r3 = *(const float4*)&X[base + (size_t)W * C + C];
    float4 o;
    o.x = fmaxf(fmaxf(r0.x, r1.x), fmaxf(r2.x, r3.x));
    o.y = fmaxf(fmaxf(r0.y, r1.y), fmaxf(r2.y, r3.y));
    o.z = fmaxf(fmaxf(r0.z, r1.z), fmaxf(r2.z, r3.z));
    o.w = fmaxf(fmaxf(r0.w, r1.w), fmaxf(r2.w, r3.w));
    *(float4*)&Y[(size_t)m * C + (c4 << 2)] = o;
  }
}

// ---------------- split-bf16 MFMA GEMM: C = epi(A @ W^T) --------------------
// 3-pass Dekker: acc += Ah*Wh + Ah*Wl + Al*Wh  (error ~1.6e-5 relative)
// AMODE 0: A f32 (M x K) contiguous.
// AMODE 1: K=512 concat gather: k<256 -> A(=ATT f32), else A2(=FEATT f32) qrep.
// AMODE 2: implicit im2col from A = NHWC f32 (Bn,H,W,IC); K = 9*IC; pad=1.
// EPI 0: f32 out = relu((acc+p0[n])*p1[n]*BN_INV + p2[n]).  EPI 1: f32 out = acc+p0[n].
template <int AMODE, int EPI>
__global__ __launch_bounds__(256) void sgemm(
    const float* __restrict__ A, const float* __restrict__ A2, int M, int K,
    const u16* __restrict__ Bh, const u16* __restrict__ Bl,
    const float* __restrict__ p0, const float* __restrict__ p1,
    const float* __restrict__ p2, float* __restrict__ Cout, int ldc,
    int H, int W, int IC, int icb) {
  __shared__ u16 Ash[64][72], Asl[64][72];
  __shared__ u16 Bsh[64][72], Bsl[64][72];
  const int tid = threadIdx.x;
  const int lane = tid & 63, wv = tid >> 6;
  const int wy = wv >> 1, wx = wv & 1;
  const int n0 = blockIdx.x * 64, m0 = blockIdx.y * 64;
  f32x4 acc[2][2] = {{{0, 0, 0, 0}, {0, 0, 0, 0}}, {{0, 0, 0, 0}, {0, 0, 0, 0}}};
  for (int k0 = 0; k0 < K; k0 += 64) {
    // ---- stage A (split f32 -> hi/lo bf16) ----
#pragma unroll
    for (int s = 0; s < 2; ++s) {
      const int c = s * 256 + tid;
      const int row = c >> 3, kc = (c & 7) << 3;
      const int gm = m0 + row, gk = k0 + kc;
      float4 x0 = {0, 0, 0, 0}, x1 = {0, 0, 0, 0};
      if (AMODE == 0) {
        if (gm < M && gk < K) {
          const float* p = A + (size_t)gm * K + gk;
          x0 = *(const float4*)p; x1 = *(const float4*)(p + 4);
        }
      } else if (AMODE == 1) {
        if (gm < M) {
          const float* p;
          if (gk < 256) {
            p = A + (size_t)gm * 256 + gk;
          } else {
            const int b = gm / T49, t = gm % T49, q = b / NS;
            p = A2 + (((size_t)(NS + q) * T49 + t) << 8) + (gk - 256);
          }
          x0 = *(const float4*)p; x1 = *(const float4*)(p + 4);
        }
      } else {  // implicit im2col
        if (gm < M && gk < K) {
          const int ox = gm % W, t_ = gm / W;
          const int oy = t_ % H, b = t_ / H;
          const int e = gk >> icb, ic = gk & (IC - 1);
          const int ky = e / 3, kx = e - 3 * (e / 3);
          const int iy = oy + ky - 1, ix = ox + kx - 1;
          if (iy >= 0 && iy < H && ix >= 0 && ix < W) {
            const float* p = A + (((size_t)b * H + iy) * W + ix) * IC + ic;
            x0 = *(const float4*)p; x1 = *(const float4*)(p + 4);
          }
        }
      }
      float v[8] = {x0.x, x0.y, x0.z, x0.w, x1.x, x1.y, x1.z, x1.w};
      u32 hp[4], lp[4];
      split8(v, hp, lp);
      *(uint4*)&Ash[row][kc] = *(uint4*)hp;
      *(uint4*)&Asl[row][kc] = *(uint4*)lp;
    }
    // ---- stage B (pre-split weights) ----
#pragma unroll
    for (int s = 0; s < 2; ++s) {
      const int c = s * 256 + tid;
      const int row = c >> 3, kc = (c & 7) << 3;
      const int gk = k0 + kc;
      uint4 vh = {0u, 0u, 0u, 0u}, vl = {0u, 0u, 0u, 0u};
      if (gk < K) {
        vh = *(const uint4*)&Bh[(size_t)(n0 + row) * K + gk];
        vl = *(const uint4*)&Bl[(size_t)(n0 + row) * K + gk];
      }
      *(uint4*)&Bsh[row][kc] = vh;
      *(uint4*)&Bsl[row][kc] = vl;
    }
    __syncthreads();
#pragma unroll
    for (int kk = 0; kk < 64; kk += 32) {
      const int ko = kk + ((lane >> 4) << 3);
      const int ra0 = wy * 32 + (lane & 15), ra1 = ra0 + 16;
      const int rb0 = wx * 32 + (lane & 15), rb1 = rb0 + 16;
      bf16x8v a0h = *(const bf16x8v*)&Ash[ra0][ko];
      bf16x8v a1h = *(const bf16x8v*)&Ash[ra1][ko];
      bf16x8v b0h = *(const bf16x8v*)&Bsh[rb0][ko];
      bf16x8v b1h = *(const bf16x8v*)&Bsh[rb1][ko];
      bf16x8v a0l = *(const bf16x8v*)&Asl[ra0][ko];
      bf16x8v a1l = *(const bf16x8v*)&Asl[ra1][ko];
      bf16x8v b0l = *(const bf16x8v*)&Bsl[rb0][ko];
      bf16x8v b1l = *(const bf16x8v*)&Bsl[rb1][ko];
      acc[0][0] = __builtin_amdgcn_mfma_f32_16x16x32_bf16(a0h, b0h, acc[0][0], 0, 0, 0);
      acc[0][1] = __builtin_amdgcn_mfma_f32_16x16x32_bf16(a0h, b1h, acc[0][1], 0, 0, 0);
      acc[1][0] = __builtin_amdgcn_mfma_f32_16x16x32_bf16(a1h, b0h, acc[1][0], 0, 0, 0);
      acc[1][1] = __builtin_amdgcn_mfma_f32_16x16x32_bf16(a1h, b1h, acc[1][1], 0, 0, 0);
      acc[0][0] = __builtin_amdgcn_mfma_f32_16x16x32_bf16(a0h, b0l, acc[0][0], 0, 0, 0);
      acc[0][1] = __builtin_amdgcn_mfma_f32_16x16x32_bf16(a0h, b1l, acc[0][1], 0, 0, 0);
      acc[1][0] = __builtin_amdgcn_mfma_f32_16x16x32_bf16(a1h, b0l, acc[1][0], 0, 0, 0);
      acc[1][1] = __builtin_amdgcn_mfma_f32_16x16x32_bf16(a1h, b1l, acc[1][1], 0, 0, 0);
      acc[0][0] = __builtin_amdgcn_mfma_f32_16x16x32_bf16(a0l, b0h, acc[0][0], 0, 0, 0);
      acc[0][1] = __builtin_amdgcn_mfma_f32_16x16x32_bf16(a0l, b1h, acc[0][1], 0, 0, 0);
      acc[1][0] = __builtin_amdgcn_mfma_f32_16x16x32_bf16(a1l, b0h, acc[1][0], 0, 0, 0);
      acc[1][1] = __builtin_amdgcn_mfma_f32_16x16x32_bf16(a1l, b1h, acc[1][1], 0, 0, 0);
    }
    __syncthreads();
  }
  // ---- epilogue (f32 out) ----
#pragma unroll
  for (int r = 0; r < 2; ++r) {
#pragma unroll
    for (int c = 0; c < 2; ++c) {
      const int gn = n0 + wx * 32 + c * 16 + (lane & 15);
      float sc0 = 0.f, sh0 = 0.f;
      if (EPI == 0) { sc0 = p1[gn] * BN_INV; sh0 = p2[gn]; }
#pragma unroll
      for (int i = 0; i < 4; ++i) {
        const int gm = m0 + wy * 32 + r * 16 + ((lane >> 4) << 2) + i;
        if (gm >= M) continue;
        const float a = acc[r][c][i];
        if (EPI == 0) {
          Cout[(size_t)gm * ldc + gn] = fmaxf((a + p0[gn]) * sc0 + sh0, 0.f);
        } else {
          Cout[(size_t)gm * ldc + gn] = a + p0[gn];
        }
      }
    }
  }
}

// ---------------- fused attention per (q,s), all f32 ----------------
// r7: transposed LDS (kills the 49-way bank conflict: 5.7e7 SQ_LDS_BANK_CONFLICT),
// fast tanh via exp2+rcp (vs ocml tanhf), 512 threads for occupancy.
__global__ __launch_bounds__(512) void attention_f32(
    const float* __restrict__ proj, const float* __restrict__ featT,
    float* __restrict__ attended) {
  __shared__ float WqT[64][51], WhT[64][51];   // [h][t], pad 51 (odd) -> conflict-free
  __shared__ float sc[T49 * 50];
  const int qs = blockIdx.x, q = qs / NS, s = qs % NS;
  const int tid = threadIdx.x;
  const float* pq = proj + (size_t)(NS + q) * T49 * 64;
  const float* ph = proj + (size_t)s * T49 * 64;
  for (int l = tid; l < T49 * 64; l += 512) {
    const int t = l >> 6, h = l & 63;
    WqT[h][t] = pq[l];
    WhT[h][t] = ph[l];
  }
  __syncthreads();
  // scores: sc[t][u] = sum_h tanh(Wq[t,h]*Wh[u,h]); tanh(x)=1-2/(exp2(x*2log2e)+1)
  constexpr float C2LOG2E = 2.8853900817779268f;
  for (int e = tid; e < T49 * T49; e += 512) {
    const int t = e / T49, u = e - t * T49;
    float acc = 0.f;
#pragma unroll
    for (int h = 0; h < 64; ++h) {
      const float p = WqT[h][t] * WhT[h][u];
      const float ex = __builtin_amdgcn_exp2f(p * C2LOG2E);
      acc += 1.f - 2.f * __builtin_amdgcn_rcpf(ex + 1.f);
    }
    sc[t * 50 + u] = acc;
  }
  __syncthreads();
  if (tid < T49) {  // softmax over u per row t
    float* row = &sc[tid * 50];
    float m = row[0];
    for (int u = 1; u < T49; ++u) m = fmaxf(m, row[u]);
    float ssum = 0.f;
    for (int u = 0; u < T49; ++u) { const float e = expf(row[u] - m); row[u] = e; ssum += e; }
    const float inv = 1.f / ssum;
    for (int u = 0; u < T49; ++u) row[u] *= inv;
  }
  __syncthreads();
  // attended[t,f] = sum_u sc[t,u]*featT[s,u,f]; 512 thr: f=tid&255, t-half=tid>>8
  const float* fs = featT + (size_t)s * T49 * 256;
  float* outp = attended + (size_t)qs * T49 * 256;
  const int f = tid & 255, hf = tid >> 8;
  const int tb = hf * 25, te = hf ? T49 : 25;
  for (int t0 = tb; t0 < te; t0 += 7) {
    const int cnt = (te - t0) < 7 ? (te - t0) : 7;
    float acc[7] = {0.f, 0.f, 0.f, 0.f, 0.f, 0.f, 0.f};
    for (int u = 0; u < T49; ++u) {
      const float v = fs[u * 256 + f];
#pragma unroll
      for (int i = 0; i < 7; ++i)
        if (i < cnt) acc[i] += sc[(t0 + i) * 50 + u] * v;
    }
#pragma unroll
    for (int i = 0; i < 7; ++i)
      if (i < cnt) outp[(t0 + i) * 256 + f] = acc[i];
  }
}

// ---------------- batched split-bf16 MFMA GRU ----------------
// 24 blocks x 512 threads (8 waves), 16 sequences/block (M=16 MFMA tile).
// Wh (384x128) split hi/lo bf16 held in REGISTERS per wave: zero Wh memory
// traffic in the 49-step loop. h carried f32 in LDS; 3-pass Dekker MFMA.
__global__ __launch_bounds__(512) void gru_mfma(
    const float* __restrict__ gi,   // (375,49,384), includes bi
    const float* __restrict__ wh,   // (384,128) f32
    const float* __restrict__ bh,   // (384)
    float* __restrict__ y,          // (375,49,128) if store_all else (375,128)
    int store_all) {
  __shared__ u16 hah[16][136], hal[16][136];
  __shared__ float ghs[16][384];
  __shared__ float hfl[16][128];
  const int tid = threadIdx.x;
  const int lane = tid & 63, wv = tid >> 6;   // 8 waves
  const int r0 = blockIdx.x * 16;
  bf16x8v Bhr[3][4], Blr[3][4];
#pragma unroll
  for (int f = 0; f < 3; ++f) {
    const int n = (wv * 3 + f) * 16 + (lane & 15);
#pragma unroll
    for (int kk = 0; kk < 4; ++kk) {
      const int k = kk * 32 + ((lane >> 4) << 3);
      const float* p = wh + (size_t)n * 128 + k;
      float v[8];
      *(float4*)&v[0] = *(const float4*)p;
      *(float4*)&v[4] = *(const float4*)(p + 4);
      u32 hp[4], lp[4];
      split8(v, hp, lp);
      Bhr[f][kk] = *(bf16x8v*)hp;
      Blr[f][kk] = *(bf16x8v*)lp;
    }
  }
  float bhr[4], bhz[4], bhn[4];
#pragma unroll
  for (int u = 0; u < 4; ++u) {
    const int j = ((u << 9) + tid) & 127;
    bhr[u] = bh[j]; bhz[u] = bh[128 + j]; bhn[u] = bh[256 + j];
  }
  for (int i = tid; i < 16 * 136; i += 512) { hah[i / 136][i % 136] = 0; hal[i / 136][i % 136] = 0; }
  for (int i = tid; i < 16 * 128; i += 512) hfl[i >> 7][i & 127] = 0.f;
  __syncthreads();
  const int ar = lane & 15, ko = (lane >> 4) << 3;
  for (int t = 0; t < T49; ++t) {
    float xr[4], xz[4], xn[4];
#pragma unroll
    for (int u = 0; u < 4; ++u) {
      const int idx = (u << 9) + tid;
      const int row = idx >> 7, j = idx & 127;
      int sq = r0 + row; if (sq >= B3) sq = B3 - 1;
      const float* gib = gi + ((size_t)sq * T49 + t) * 384;
      xr[u] = gib[j]; xz[u] = gib[128 + j]; xn[u] = gib[256 + j];
    }
    bf16x8v Ah[4], Al[4];
#pragma unroll
    for (int kk = 0; kk < 4; ++kk) {
      Ah[kk] = *(const bf16x8v*)&hah[ar][kk * 32 + ko];
      Al[kk] = *(const bf16x8v*)&hal[ar][kk * 32 + ko];
    }
#pragma unroll
    for (int f = 0; f < 3; ++f) {
      f32x4 acc = {0, 0, 0, 0};
#pragma unroll
      for (int kk = 0; kk < 4; ++kk)
        acc = __builtin_amdgcn_mfma_f32_16x16x32_bf16(Ah[kk], Bhr[f][kk], acc, 0, 0, 0);
#pragma unroll
      for (int kk = 0; kk < 4; ++kk)
        acc = __builtin_amdgcn_mfma_f32_16x16x32_bf16(Ah[kk], Blr[f][kk], acc, 0, 0, 0);
#pragma unroll
      for (int kk = 0; kk < 4; ++kk)
        acc = __builtin_amdgcn_mfma_f32_16x16x32_bf16(Al[kk], Bhr[f][kk], acc, 0, 0, 0);
      const int nc = (wv * 3 + f) * 16 + (lane & 15);
      const int rb = (lane >> 4) << 2;
#pragma unroll
      for (int i = 0; i < 4; ++i) ghs[rb + i][nc] = acc[i];
    }
    __syncthreads();
#pragma unroll
    for (int u = 0; u < 4; ++u) {
      const int idx = (u << 9) + tid;
      const int row = idx >> 7, j = idx & 127;
      const int seq = r0 + row;
      const float r_ = 1.f / (1.f + expf(-(xr[u] + ghs[row][j] + bhr[u])));
      const float z_ = 1.f / (1.f + expf(-(xz[u] + ghs[row][128 + j] + bhz[u])));
      const float n_ = tanhf(xn[u] + r_ * (ghs[row][256 + j] + bhn[u]));
      const float hp = hfl[row][j];
      const float hn = (1.f - z_) * n_ + z_ * hp;
      hfl[row][j] = hn;
      const u16 hb = f2b(hn);
      hah[row][j] = hb;
      hal[row][j] = f2b(hn - b2f(hb));
      if (seq < B3) {
        if (store_all) y[((size_t)seq * T49 + t) * 128 + j] = hn;
        else if (t == T49 - 1) y[(size_t)seq * 128 + j] = hn;
      }
    }
    __syncthreads();
  }
}

// ---------------- head ----------------
__global__ __launch_bounds__(512) void head_kernel(
    const float* __restrict__ hf, const float* __restrict__ tw,
    const float* __restrict__ tb, float* __restrict__ out) {
  __shared__ float lg[B3];
  const int tid = threadIdx.x;
  if (tid < B3) {
    const float* h = hf + (size_t)tid * 128;
    float acc = tb[0];
    for (int k = 0; k < 128; ++k) acc += h[k] * tw[k];
    lg[tid] = acc;
  }
  __syncthreads();
  if (tid < NQ) {
    float cls[5];
#pragma unroll
    for (int n = 0; n < 5; ++n) {
      float s = 0.f;
#pragma unroll
      for (int k = 0; k < 5; ++k) s += lg[tid * 25 + n * 5 + k];
      cls[n] = s;
    }
    float m = cls[0];
#pragma unroll
    for (int n = 1; n < 5; ++n) m = fmaxf(m, cls[n]);
    float se = 0.f;
#pragma unroll
    for (int n = 0; n < 5; ++n) se += expf(cls[n] - m);
    const float lse = m + logf(se);
#pragma unroll
    for (int n = 0; n < 5; ++n) out[tid * 5 + n] = cls[n] - lse;
  }
}

extern "C" void kernel_launch(void* const* d_in, const int* in_sizes, int n_in,
                              void* d_out, int out_size, void* d_ws,
                              size_t ws_size, hipStream_t stream) {
  (void)in_sizes; (void)n_in; (void)out_size; (void)ws_size;
  const float* support = (const float*)d_in[0];
  const float* query   = (const float*)d_in[1];
  const float* cw1 = (const float*)d_in[2];  const float* cb1 = (const float*)d_in[3];
  const float* cw2 = (const float*)d_in[4];  const float* cb2 = (const float*)d_in[5];
  const float* cw3 = (const float*)d_in[6];  const float* cb3 = (const float*)d_in[7];
  const float* cw4 = (const float*)d_in[8];  const float* cb4 = (const float*)d_in[9];
  const float* g1  = (const float*)d_in[10]; const float* be1 = (const float*)d_in[11];
  const float* g2  = (const float*)d_in[12]; const float* be2 = (const float*)d_in[13];
  const float* g3  = (const float*)d_in[14]; const float* be3 = (const float*)d_in[15];
  const float* g4  = (const float*)d_in[16]; const float* be4 = (const float*)d_in[17];
  const float* aw  = (const float*)d_in[18]; const float* ab  = (const float*)d_in[19];
  const float* wi0 = (const float*)d_in[20]; const float* wh0 = (const float*)d_in[21];
  const float* bi0 = (const float*)d_in[22]; const float* bh0 = (const float*)d_in[23];
  const float* wi1 = (const float*)d_in[24]; const float* wh1 = (const float*)d_in[25];
  const float* bi1 = (const float*)d_in[26]; const float* bh1 = (const float*)d_in[27];
  const float* tw  = (const float*)d_in[28]; const float* tb  = (const float*)d_in[29];

  char* ws = (char*)d_ws;
  float* out = (float*)d_out;
  float* A1    = (float*)(ws + A1_OFF);
  float* X2    = (float*)(ws + X2_OFF);
  float* P2    = (float*)(ws + P2_OFF);
  float* X3    = (float*)(ws + X3_OFF);
  float* P3    = (float*)(ws + P3_OFF);
  float* X4    = (float*)(ws + X4_OFF);
  float* FEATT = (float*)(ws + FEATT_OFF);
  float* PROJ  = (float*)(ws + PROJ_OFF);
  float* ATT   = (float*)(ws + ATT_OFF);
  float* GI    = (float*)(ws + GI_OFF);
  float* Y0    = (float*)(ws + Y0_OFF);
  float* HFIN  = (float*)(ws + HFIN_OFF);
  u16* WBH = (u16*)(ws + WBH_OFF);
  u16* WBL = (u16*)(ws + WBL_OFF);

  // weight conversions (split hi/lo)
  cvt_conv_w_split<<<(64 * 288 + 255) / 256, 256, 0, stream>>>(cw2, WBH + W2_E, WBL + W2_E, 64, 32);
  cvt_conv_w_split<<<(128 * 576 + 255) / 256, 256, 0, stream>>>(cw3, WBH + W3_E, WBL + W3_E, 128, 64);
  cvt_conv_w_split<<<(256 * 1152 + 255) / 256, 256, 0, stream>>>(cw4, WBH + W4_E, WBL + W4_E, 256, 128);
  cvt_split<<<(64 * 256 + 255) / 256, 256, 0, stream>>>(aw, WBH + AW_E, WBL + AW_E, 64 * 256);
  cvt_split<<<(384 * 512 + 255) / 256, 256, 0, stream>>>(wi0, WBH + WI0_E, WBL + WI0_E, 384 * 512);
  cvt_split<<<(384 * 128 + 255) / 256, 256, 0, stream>>>(wi1, WBH + WI1_E, WBL + WI1_E, 384 * 128);

  // ---- encoder ----
  conv1_pool<<<15680, 256, 0, stream>>>(support, query, cw1, cb1, g1, be1, A1);
  // conv2: A1(40,56,56,32) -> X2(40,56,56,64) -> P2(40,28,28,64)
  sgemm<2, 0><<<dim3(1, 1960), 256, 0, stream>>>(
      A1, nullptr, 125440, 288, WBH + W2_E, WBL + W2_E, cb2, g2, be2, X2, 64,
      56, 56, 32, 5);
  maxpool2_f32<<<1960, 256, 0, stream>>>(X2, P2, NB, 56, 56, 64);
  // conv3: P2 -> X3(40,28,28,128) -> P3(40,14,14,128)
  sgemm<2, 0><<<dim3(2, 490), 256, 0, stream>>>(
      P2, nullptr, 31360, 576, WBH + W3_E, WBL + W3_E, cb3, g3, be3, X3, 128,
      28, 28, 64, 6);
  maxpool2_f32<<<980, 256, 0, stream>>>(X3, P3, NB, 28, 28, 128);
  // conv4: P3 -> X4(40,14,14,256) -> FEATT(40,7,7,256)
  sgemm<2, 0><<<dim3(4, 123), 256, 0, stream>>>(
      P3, nullptr, 7840, 1152, WBH + W4_E, WBL + W4_E, cb4, g4, be4, X4, 256,
      14, 14, 128, 7);
  maxpool2_f32<<<490, 256, 0, stream>>>(X4, FEATT, NB, 14, 14, 256);

  // ---- attention ----
  sgemm<0, 1><<<dim3(1, 31), 256, 0, stream>>>(
      FEATT, nullptr, NB * T49, 256, WBH + AW_E, WBL + AW_E, ab, nullptr,
      nullptr, PROJ, 64, 0, 0, 0, 0);
  attention_f32<<<B3, 512, 0, stream>>>(PROJ, FEATT, ATT);

  // ---- GRU stack ----
  sgemm<1, 1><<<dim3(6, 288), 256, 0, stream>>>(
      ATT, FEATT, B3 * T49, 512, WBH + WI0_E, WBL + WI0_E, bi0, nullptr,
      nullptr, GI, 384, 0, 0, 0, 0);
  gru_mfma<<<24, 512, 0, stream>>>(GI, wh0, bh0, Y0, 1);
  sgemm<0, 1><<<dim3(6, 288), 256, 0, stream>>>(
      Y0, nullptr, B3 * T49, 128, WBH + WI1_E, WBL + WI1_E, bi1, nullptr,
      nullptr, GI, 384, 0, 0, 0, 0);
  gru_mfma<<<24, 512, 0, stream>>>(GI, wh1, bh1, HFIN, 0);

  // ---- head ----
  head_kernel<<<1, 512, 0, stream>>>(HFIN, tw, tb, out);
}

// Round 9
// 461.114 us; speedup vs baseline: 8.1782x; 1.2438x over previous
//
#include <hip/hip_runtime.h>
#include <hip/hip_bf16.h>
#include <math.h>

typedef unsigned short u16;
typedef unsigned int u32;
typedef __attribute__((ext_vector_type(8))) short bf16x8v;
typedef __attribute__((ext_vector_type(4))) float f32x4;

// ---------------- problem constants ----------------
constexpr int NS = 25, NQ = 15, NB = 40;
constexpr int B3 = 375;     // 15*25
constexpr int T49 = 49;
constexpr float BN_INV = 0.9999950000374997f;

// ---------------- workspace layout (BYTES), f32 activations ----------------
constexpr size_t A1_OFF    = 0;            // (40,56,56,32) f32 = 16,056,320
constexpr size_t X2_OFF    = 16056320;     // (40,56,56,64) f32 = 32,112,640
constexpr size_t P2_OFF    = 48168960;     // (40,28,28,64) f32 = 8,028,160
constexpr size_t X3_OFF    = 0;            // (40,28,28,128) f32 = 16,056,320
constexpr size_t P3_OFF    = 56197120;     // (40,14,14,128) f32 = 4,014,080
constexpr size_t X4_OFF    = 16056320;     // (40,14,14,256) f32 = 8,028,160
constexpr size_t FEATT_OFF = 60211200;     // (40,49,256) f32 = 2,007,040
constexpr size_t PROJ_OFF  = 24084480;     // (1960,64) f32 = 501,760
constexpr size_t ATT_OFF   = 24586240;     // (375,49,256) f32 = 18,816,000
constexpr size_t GI_OFF    = 62218240;     // (18375,384) f32 = 28,224,000
constexpr size_t Y0_OFF    = 0;            // (18375,128) f32 = 9,408,000
constexpr size_t HFIN_OFF  = 90442240;     // (375,128) f32 = 192,000
constexpr size_t WBH_OFF   = 91027456;     // bf16-hi arena 649,216 u16
constexpr size_t WBL_OFF   = 92325888;     // bf16-lo arena
// u16-element offsets within each arena:
constexpr size_t W2_E = 0;        // 64*288
constexpr size_t W3_E = 18432;    // 128*576
constexpr size_t W4_E = 92160;    // 256*1152
constexpr size_t AW_E = 387072;   // 64*256
constexpr size_t WI0_E = 403456;  // 384*512
constexpr size_t WI1_E = 600064;  // 384*128

static __device__ __forceinline__ u16 f2b(float f) {
  __hip_bfloat16 h = __float2bfloat16(f);
  return *reinterpret_cast<u16*>(&h);
}
static __device__ __forceinline__ float b2f(u16 u) {
  return __uint_as_float((u32)u << 16);
}
// split v into hi+lo bf16 pair, packed into u32 words
static __device__ __forceinline__ void split8(const float* v, u32* hp, u32* lp) {
  u16 h[8], l[8];
#pragma unroll
  for (int j = 0; j < 8; ++j) {
    const u16 hb = f2b(v[j]);
    h[j] = hb;
    l[j] = f2b(v[j] - b2f(hb));
  }
#pragma unroll
  for (int j = 0; j < 4; ++j) {
    hp[j] = (u32)h[2 * j] | ((u32)h[2 * j + 1] << 16);
    lp[j] = (u32)l[2 * j] | ((u32)l[2 * j + 1] << 16);
  }
}
// fast sigmoid / tanh (exp2+rcp intrinsics; err ~1e-6, validated in attention)
constexpr float LOG2E = 1.4426950408889634f;
static __device__ __forceinline__ float fsigmoid(float x) {
  return __builtin_amdgcn_rcpf(1.f + __builtin_amdgcn_exp2f(-x * LOG2E));
}
static __device__ __forceinline__ float ftanh(float x) {
  return 1.f - 2.f * __builtin_amdgcn_rcpf(__builtin_amdgcn_exp2f(x * (2.f * LOG2E)) + 1.f);
}

// ---------------- weight split converters ----------------
__global__ void cvt_split(const float* __restrict__ x, u16* __restrict__ oh,
                          u16* __restrict__ ol, int n) {
  int i = blockIdx.x * 256 + threadIdx.x;
  if (i >= n) return;
  const float v = x[i];
  const u16 h = f2b(v);
  oh[i] = h;
  ol[i] = f2b(v - b2f(h));
}
// OIHW f32 -> [oc][(ky*3+kx)*IC + ic] hi/lo bf16
__global__ void cvt_conv_w_split(const float* __restrict__ w, u16* __restrict__ oh,
                                 u16* __restrict__ ol, int OC, int IC) {
  const int n = OC * IC * 9;
  int i = blockIdx.x * 256 + threadIdx.x;
  if (i >= n) return;
  const int oc = i / (IC * 9), rem = i % (IC * 9);
  const int e = rem / IC, ic = rem % IC;
  const int ky = e / 3, kx = e % 3;
  const float v = w[((size_t)(oc * IC + ic) * 3 + ky) * 3 + kx];
  const u16 h = f2b(v);
  oh[i] = h;
  ol[i] = f2b(v - b2f(h));
}

// ---------------- fused conv1(s2)+BN+ReLU+pool2, f32 out NHWC ----------------
__global__ __launch_bounds__(256) void conv1_pool(
    const float* __restrict__ support, const float* __restrict__ query,
    const float* __restrict__ w1, const float* __restrict__ cb1,
    const float* __restrict__ g1, const float* __restrict__ be1,
    float* __restrict__ out) {
  __shared__ float wl[288], scl[32], shl[32], cbl[32];
  const int tid = threadIdx.x;
  for (int l = tid; l < 288; l += 256) wl[l] = w1[l];  // FIX(r5): strided, 288>256
  if (tid < 32) { scl[tid] = g1[tid] * BN_INV; shl[tid] = be1[tid]; cbl[tid] = cb1[tid]; }
  __syncthreads();
  const int oc = tid & 31;
  const int p = blockIdx.x * 8 + (tid >> 5);   // 0 .. 125439 = (b,oy,ox)
  const int ox = p % 56, oy = (p / 56) % 56, b = p / 3136;
  const float* in_b = (b < NS) ? (support + (size_t)b * 50176)
                               : (query + (size_t)(b - NS) * 50176);
  const int iy0 = 4 * oy - 1, ix0 = 4 * ox - 1;
  float pat[5][5];
#pragma unroll
  for (int dy = 0; dy < 5; ++dy) {
    const int iy = iy0 + dy;
#pragma unroll
    for (int dx = 0; dx < 5; ++dx) {
      const int ix = ix0 + dx;
      pat[dy][dx] = (iy >= 0 && iy < 224 && ix >= 0 && ix < 224)
                        ? in_b[(size_t)iy * 224 + ix] : 0.f;
    }
  }
  const float* wp = &wl[oc * 9];
  float mx = 0.f;  // post-ReLU values >= 0
#pragma unroll
  for (int py = 0; py < 2; ++py)
#pragma unroll
    for (int px = 0; px < 2; ++px) {
      float acc = 0.f;
#pragma unroll
      for (int ky = 0; ky < 3; ++ky)
#pragma unroll
        for (int kx = 0; kx < 3; ++kx)
          acc += pat[2 * py + ky][2 * px + kx] * wp[ky * 3 + kx];
      float v = (acc + cbl[oc]) * scl[oc] + shl[oc];
      mx = fmaxf(mx, v);
    }
  out[(size_t)p * 32 + oc] = mx;
}

// ---------------- f32 NHWC maxpool 2x2 ----------------
__global__ void maxpool2_f32(const float* __restrict__ X, float* __restrict__ Y,
                             int Bn, int H, int W, int C) {
  const int OH = H >> 1, OW = W >> 1;
  const int cpr = C >> 2;
  const int chunks = Bn * OH * OW * cpr;
  for (int i = blockIdx.x * blockDim.x + threadIdx.x; i < chunks;
       i += gridDim.x * blockDim.x) {
    const int c4 = i % cpr, m = i / cpr;
    const int ox = m % OW, oy = (m / OW) % OH, b = m / (OW * OH);
    const size_t base = (((size_t)b * H + 2 * oy) * W + 2 * ox) * C + (c4 << 2);
    const float4 r0 = *(const float4*)&X[base];
    const float4 r1 = *(const float4*)&X[base + C];
    const float4 r2 = *(const float4*)&X[base + (size_t)W * C];
    const float4 r3 = *(const float4*)&X[base + (size_t)W * C + C];
    float4 o;
    o.x = fmaxf(fmaxf(r0.x, r1.x), fmaxf(r2.x, r3.x));
    o.y = fmaxf(fmaxf(r0.y, r1.y), fmaxf(r2.y, r3.y));
    o.z = fmaxf(fmaxf(r0.z, r1.z), fmaxf(r2.z, r3.z));
    o.w = fmaxf(fmaxf(r0.w, r1.w), fmaxf(r2.w, r3.w));
    *(float4*)&Y[(size_t)m * C + (c4 << 2)] = o;
  }
}

// ---------------- split-bf16 MFMA GEMM: C = epi(A @ W^T) --------------------
// 3-pass Dekker: acc += Ah*Wh + Ah*Wl + Al*Wh  (error ~1.6e-5 relative)
// AMODE 0: A f32 (M x K) contiguous.
// AMODE 1: K=512 concat gather: k<256 -> A(=ATT f32), else A2(=FEATT f32) qrep.
// AMODE 2: implicit im2col from A = NHWC f32 (Bn,H,W,IC); K = 9*IC; pad=1.
// EPI 0: f32 out = relu((acc+p0[n])*p1[n]*BN_INV + p2[n]).  EPI 1: f32 out = acc+p0[n].
template <int AMODE, int EPI>
__global__ __launch_bounds__(256) void sgemm(
    const float* __restrict__ A, const float* __restrict__ A2, int M, int K,
    const u16* __restrict__ Bh, const u16* __restrict__ Bl,
    const float* __restrict__ p0, const float* __restrict__ p1,
    const float* __restrict__ p2, float* __restrict__ Cout, int ldc,
    int H, int W, int IC, int icb) {
  __shared__ u16 Ash[64][72], Asl[64][72];
  __shared__ u16 Bsh[64][72], Bsl[64][72];
  const int tid = threadIdx.x;
  const int lane = tid & 63, wv = tid >> 6;
  const int wy = wv >> 1, wx = wv & 1;
  const int n0 = blockIdx.x * 64, m0 = blockIdx.y * 64;
  f32x4 acc[2][2] = {{{0, 0, 0, 0}, {0, 0, 0, 0}}, {{0, 0, 0, 0}, {0, 0, 0, 0}}};
  for (int k0 = 0; k0 < K; k0 += 64) {
    // ---- stage A (split f32 -> hi/lo bf16) ----
#pragma unroll
    for (int s = 0; s < 2; ++s) {
      const int c = s * 256 + tid;
      const int row = c >> 3, kc = (c & 7) << 3;
      const int gm = m0 + row, gk = k0 + kc;
      float4 x0 = {0, 0, 0, 0}, x1 = {0, 0, 0, 0};
      if (AMODE == 0) {
        if (gm < M && gk < K) {
          const float* p = A + (size_t)gm * K + gk;
          x0 = *(const float4*)p; x1 = *(const float4*)(p + 4);
        }
      } else if (AMODE == 1) {
        if (gm < M) {
          const float* p;
          if (gk < 256) {
            p = A + (size_t)gm * 256 + gk;
          } else {
            const int b = gm / T49, t = gm % T49, q = b / NS;
            p = A2 + (((size_t)(NS + q) * T49 + t) << 8) + (gk - 256);
          }
          x0 = *(const float4*)p; x1 = *(const float4*)(p + 4);
        }
      } else {  // implicit im2col
        if (gm < M && gk < K) {
          const int ox = gm % W, t_ = gm / W;
          const int oy = t_ % H, b = t_ / H;
          const int e = gk >> icb, ic = gk & (IC - 1);
          const int ky = e / 3, kx = e - 3 * (e / 3);
          const int iy = oy + ky - 1, ix = ox + kx - 1;
          if (iy >= 0 && iy < H && ix >= 0 && ix < W) {
            const float* p = A + (((size_t)b * H + iy) * W + ix) * IC + ic;
            x0 = *(const float4*)p; x1 = *(const float4*)(p + 4);
          }
        }
      }
      float v[8] = {x0.x, x0.y, x0.z, x0.w, x1.x, x1.y, x1.z, x1.w};
      u32 hp[4], lp[4];
      split8(v, hp, lp);
      *(uint4*)&Ash[row][kc] = *(uint4*)hp;
      *(uint4*)&Asl[row][kc] = *(uint4*)lp;
    }
    // ---- stage B (pre-split weights) ----
#pragma unroll
    for (int s = 0; s < 2; ++s) {
      const int c = s * 256 + tid;
      const int row = c >> 3, kc = (c & 7) << 3;
      const int gk = k0 + kc;
      uint4 vh = {0u, 0u, 0u, 0u}, vl = {0u, 0u, 0u, 0u};
      if (gk < K) {
        vh = *(const uint4*)&Bh[(size_t)(n0 + row) * K + gk];
        vl = *(const uint4*)&Bl[(size_t)(n0 + row) * K + gk];
      }
      *(uint4*)&Bsh[row][kc] = vh;
      *(uint4*)&Bsl[row][kc] = vl;
    }
    __syncthreads();
#pragma unroll
    for (int kk = 0; kk < 64; kk += 32) {
      const int ko = kk + ((lane >> 4) << 3);
      const int ra0 = wy * 32 + (lane & 15), ra1 = ra0 + 16;
      const int rb0 = wx * 32 + (lane & 15), rb1 = rb0 + 16;
      bf16x8v a0h = *(const bf16x8v*)&Ash[ra0][ko];
      bf16x8v a1h = *(const bf16x8v*)&Ash[ra1][ko];
      bf16x8v b0h = *(const bf16x8v*)&Bsh[rb0][ko];
      bf16x8v b1h = *(const bf16x8v*)&Bsh[rb1][ko];
      bf16x8v a0l = *(const bf16x8v*)&Asl[ra0][ko];
      bf16x8v a1l = *(const bf16x8v*)&Asl[ra1][ko];
      bf16x8v b0l = *(const bf16x8v*)&Bsl[rb0][ko];
      bf16x8v b1l = *(const bf16x8v*)&Bsl[rb1][ko];
      acc[0][0] = __builtin_amdgcn_mfma_f32_16x16x32_bf16(a0h, b0h, acc[0][0], 0, 0, 0);
      acc[0][1] = __builtin_amdgcn_mfma_f32_16x16x32_bf16(a0h, b1h, acc[0][1], 0, 0, 0);
      acc[1][0] = __builtin_amdgcn_mfma_f32_16x16x32_bf16(a1h, b0h, acc[1][0], 0, 0, 0);
      acc[1][1] = __builtin_amdgcn_mfma_f32_16x16x32_bf16(a1h, b1h, acc[1][1], 0, 0, 0);
      acc[0][0] = __builtin_amdgcn_mfma_f32_16x16x32_bf16(a0h, b0l, acc[0][0], 0, 0, 0);
      acc[0][1] = __builtin_amdgcn_mfma_f32_16x16x32_bf16(a0h, b1l, acc[0][1], 0, 0, 0);
      acc[1][0] = __builtin_amdgcn_mfma_f32_16x16x32_bf16(a1h, b0l, acc[1][0], 0, 0, 0);
      acc[1][1] = __builtin_amdgcn_mfma_f32_16x16x32_bf16(a1h, b1l, acc[1][1], 0, 0, 0);
      acc[0][0] = __builtin_amdgcn_mfma_f32_16x16x32_bf16(a0l, b0h, acc[0][0], 0, 0, 0);
      acc[0][1] = __builtin_amdgcn_mfma_f32_16x16x32_bf16(a0l, b1h, acc[0][1], 0, 0, 0);
      acc[1][0] = __builtin_amdgcn_mfma_f32_16x16x32_bf16(a1l, b0h, acc[1][0], 0, 0, 0);
      acc[1][1] = __builtin_amdgcn_mfma_f32_16x16x32_bf16(a1l, b1h, acc[1][1], 0, 0, 0);
    }
    __syncthreads();
  }
  // ---- epilogue (f32 out) ----
#pragma unroll
  for (int r = 0; r < 2; ++r) {
#pragma unroll
    for (int c = 0; c < 2; ++c) {
      const int gn = n0 + wx * 32 + c * 16 + (lane & 15);
      float sc0 = 0.f, sh0 = 0.f;
      if (EPI == 0) { sc0 = p1[gn] * BN_INV; sh0 = p2[gn]; }
#pragma unroll
      for (int i = 0; i < 4; ++i) {
        const int gm = m0 + wy * 32 + r * 16 + ((lane >> 4) << 2) + i;
        if (gm >= M) continue;
        const float a = acc[r][c][i];
        if (EPI == 0) {
          Cout[(size_t)gm * ldc + gn] = fmaxf((a + p0[gn]) * sc0 + sh0, 0.f);
        } else {
          Cout[(size_t)gm * ldc + gn] = a + p0[gn];
        }
      }
    }
  }
}

// ---------------- fused attention per (q,s), all f32 ----------------
__global__ __launch_bounds__(512) void attention_f32(
    const float* __restrict__ proj, const float* __restrict__ featT,
    float* __restrict__ attended) {
  __shared__ float WqT[64][51], WhT[64][51];   // [h][t], pad 51 (odd) -> conflict-free
  __shared__ float sc[T49 * 50];
  const int qs = blockIdx.x, q = qs / NS, s = qs % NS;
  const int tid = threadIdx.x;
  const float* pq = proj + (size_t)(NS + q) * T49 * 64;
  const float* ph = proj + (size_t)s * T49 * 64;
  for (int l = tid; l < T49 * 64; l += 512) {
    const int t = l >> 6, h = l & 63;
    WqT[h][t] = pq[l];
    WhT[h][t] = ph[l];
  }
  __syncthreads();
  constexpr float C2LOG2E = 2.8853900817779268f;
  for (int e = tid; e < T49 * T49; e += 512) {
    const int t = e / T49, u = e - t * T49;
    float acc = 0.f;
#pragma unroll
    for (int h = 0; h < 64; ++h) {
      const float p = WqT[h][t] * WhT[h][u];
      const float ex = __builtin_amdgcn_exp2f(p * C2LOG2E);
      acc += 1.f - 2.f * __builtin_amdgcn_rcpf(ex + 1.f);
    }
    sc[t * 50 + u] = acc;
  }
  __syncthreads();
  if (tid < T49) {  // softmax over u per row t
    float* row = &sc[tid * 50];
    float m = row[0];
    for (int u = 1; u < T49; ++u) m = fmaxf(m, row[u]);
    float ssum = 0.f;
    for (int u = 0; u < T49; ++u) { const float e = expf(row[u] - m); row[u] = e; ssum += e; }
    const float inv = 1.f / ssum;
    for (int u = 0; u < T49; ++u) row[u] *= inv;
  }
  __syncthreads();
  const float* fs = featT + (size_t)s * T49 * 256;
  float* outp = attended + (size_t)qs * T49 * 256;
  const int f = tid & 255, hf = tid >> 8;
  const int tb = hf * 25, te = hf ? T49 : 25;
  for (int t0 = tb; t0 < te; t0 += 7) {
    const int cnt = (te - t0) < 7 ? (te - t0) : 7;
    float acc[7] = {0.f, 0.f, 0.f, 0.f, 0.f, 0.f, 0.f};
    for (int u = 0; u < T49; ++u) {
      const float v = fs[u * 256 + f];
#pragma unroll
      for (int i = 0; i < 7; ++i)
        if (i < cnt) acc[i] += sc[(t0 + i) * 50 + u] * v;
    }
#pragma unroll
    for (int i = 0; i < 7; ++i)
      if (i < cnt) outp[(t0 + i) * 256 + f] = acc[i];
  }
}

// ---------------- batched split-bf16 MFMA GRU ----------------
// r8: SPB 16->8 (47 blocks), gi prefetched one step ahead (double-buffered
// regs), fast exp2-based gates. Wh stays register-resident hi/lo bf16.
constexpr int SPB = 8;
__global__ __launch_bounds__(512) void gru_mfma(
    const float* __restrict__ gi,   // (375,49,384), includes bi
    const float* __restrict__ wh,   // (384,128) f32
    const float* __restrict__ bh,   // (384)
    float* __restrict__ y,          // (375,49,128) if store_all else (375,128)
    int store_all) {
  __shared__ u16 hah[16][136], hal[16][136];
  __shared__ float ghs[SPB][384];
  __shared__ float hfl[SPB][128];
  const int tid = threadIdx.x;
  const int lane = tid & 63, wv = tid >> 6;   // 8 waves
  const int r0 = blockIdx.x * SPB;
  // ---- one-time: load + split Wh fragments into registers ----
  bf16x8v Bhr[3][4], Blr[3][4];
#pragma unroll
  for (int f = 0; f < 3; ++f) {
    const int n = (wv * 3 + f) * 16 + (lane & 15);
#pragma unroll
    for (int kk = 0; kk < 4; ++kk) {
      const int k = kk * 32 + ((lane >> 4) << 3);
      const float* p = wh + (size_t)n * 128 + k;
      float v[8];
      *(float4*)&v[0] = *(const float4*)p;
      *(float4*)&v[4] = *(const float4*)(p + 4);
      u32 hp[4], lp[4];
      split8(v, hp, lp);
      Bhr[f][kk] = *(bf16x8v*)hp;
      Blr[f][kk] = *(bf16x8v*)lp;
    }
  }
  // thread's 2 gate slots: idx = u*512+tid -> row=idx>>7 (0..7), j=idx&127
  const int row0 = tid >> 7, j0 = tid & 127;
  const int row1 = (512 + tid) >> 7, j1 = tid & 127;
  int sq0 = r0 + row0; if (sq0 >= B3) sq0 = B3 - 1;
  int sq1 = r0 + row1; if (sq1 >= B3) sq1 = B3 - 1;
  const float bhr0 = bh[j0], bhz0 = bh[128 + j0], bhn0 = bh[256 + j0];
  const float bhr1 = bh[j1], bhz1 = bh[128 + j1], bhn1 = bh[256 + j1];
  const float* gib0 = gi + (size_t)sq0 * T49 * 384;
  const float* gib1 = gi + (size_t)sq1 * T49 * 384;
  // ---- init state ----
  for (int i = tid; i < 16 * 136; i += 512) { hah[i / 136][i % 136] = 0; hal[i / 136][i % 136] = 0; }
  for (int i = tid; i < SPB * 128; i += 512) hfl[i >> 7][i & 127] = 0.f;
  __syncthreads();
  const int ar = lane & 15, ko = (lane >> 4) << 3;
  // prologue: load gi for t=0
  float xr0c = gib0[j0], xz0c = gib0[128 + j0], xn0c = gib0[256 + j0];
  float xr1c = gib1[j1], xz1c = gib1[128 + j1], xn1c = gib1[256 + j1];
  for (int t = 0; t < T49; ++t) {
    // issue prefetch for t+1 (clamped) — lands during MFMA + gate phases
    const int tn = (t + 1 < T49) ? t + 1 : t;
    const float* g0n = gib0 + (size_t)tn * 384;
    const float* g1n = gib1 + (size_t)tn * 384;
    const float xr0n = g0n[j0], xz0n = g0n[128 + j0], xn0n = g0n[256 + j0];
    const float xr1n = g1n[j1], xz1n = g1n[128 + j1], xn1n = g1n[256 + j1];
    // A-frags (h hi/lo) from LDS
    bf16x8v Ah[4], Al[4];
#pragma unroll
    for (int kk = 0; kk < 4; ++kk) {
      Ah[kk] = *(const bf16x8v*)&hah[ar][kk * 32 + ko];
      Al[kk] = *(const bf16x8v*)&hal[ar][kk * 32 + ko];
    }
    // gh = h @ Wh^T (3-pass Dekker)
#pragma unroll
    for (int f = 0; f < 3; ++f) {
      f32x4 acc = {0, 0, 0, 0};
#pragma unroll
      for (int kk = 0; kk < 4; ++kk)
        acc = __builtin_amdgcn_mfma_f32_16x16x32_bf16(Ah[kk], Bhr[f][kk], acc, 0, 0, 0);
#pragma unroll
      for (int kk = 0; kk < 4; ++kk)
        acc = __builtin_amdgcn_mfma_f32_16x16x32_bf16(Ah[kk], Blr[f][kk], acc, 0, 0, 0);
#pragma unroll
      for (int kk = 0; kk < 4; ++kk)
        acc = __builtin_amdgcn_mfma_f32_16x16x32_bf16(Al[kk], Bhr[f][kk], acc, 0, 0, 0);
      const int nc = (wv * 3 + f) * 16 + (lane & 15);
      const int rb = (lane >> 4) << 2;
      if (rb < SPB) {
#pragma unroll
        for (int i = 0; i < 4; ++i) ghs[rb + i][nc] = acc[i];
      }
    }
    __syncthreads();
    // fused gate math (fast sigmoid/tanh), 2 slots/thread
    {
      const float r_ = fsigmoid(xr0c + ghs[row0][j0] + bhr0);
      const float z_ = fsigmoid(xz0c + ghs[row0][128 + j0] + bhz0);
      const float n_ = ftanh(xn0c + r_ * (ghs[row0][256 + j0] + bhn0));
      const float hn = (1.f - z_) * n_ + z_ * hfl[row0][j0];
      hfl[row0][j0] = hn;
      const u16 hb = f2b(hn);
      hah[row0][j0] = hb;
      hal[row0][j0] = f2b(hn - b2f(hb));
      if (r0 + row0 < B3) {
        if (store_all) y[((size_t)(r0 + row0) * T49 + t) * 128 + j0] = hn;
        else if (t == T49 - 1) y[(size_t)(r0 + row0) * 128 + j0] = hn;
      }
    }
    {
      const float r_ = fsigmoid(xr1c + ghs[row1][j1] + bhr1);
      const float z_ = fsigmoid(xz1c + ghs[row1][128 + j1] + bhz1);
      const float n_ = ftanh(xn1c + r_ * (ghs[row1][256 + j1] + bhn1));
      const float hn = (1.f - z_) * n_ + z_ * hfl[row1][j1];
      hfl[row1][j1] = hn;
      const u16 hb = f2b(hn);
      hah[row1][j1] = hb;
      hal[row1][j1] = f2b(hn - b2f(hb));
      if (r0 + row1 < B3) {
        if (store_all) y[((size_t)(r0 + row1) * T49 + t) * 128 + j1] = hn;
        else if (t == T49 - 1) y[(size_t)(r0 + row1) * 128 + j1] = hn;
      }
    }
    __syncthreads();
    // rotate prefetched regs into current
    xr0c = xr0n; xz0c = xz0n; xn0c = xn0n;
    xr1c = xr1n; xz1c = xz1n; xn1c = xn1n;
  }
}

// ---------------- head ----------------
__global__ __launch_bounds__(512) void head_kernel(
    const float* __restrict__ hf, const float* __restrict__ tw,
    const float* __restrict__ tb, float* __restrict__ out) {
  __shared__ float lg[B3];
  const int tid = threadIdx.x;
  if (tid < B3) {
    const float* h = hf + (size_t)tid * 128;
    float acc = tb[0];
    for (int k = 0; k < 128; ++k) acc += h[k] * tw[k];
    lg[tid] = acc;
  }
  __syncthreads();
  if (tid < NQ) {
    float cls[5];
#pragma unroll
    for (int n = 0; n < 5; ++n) {
      float s = 0.f;
#pragma unroll
      for (int k = 0; k < 5; ++k) s += lg[tid * 25 + n * 5 + k];
      cls[n] = s;
    }
    float m = cls[0];
#pragma unroll
    for (int n = 1; n < 5; ++n) m = fmaxf(m, cls[n]);
    float se = 0.f;
#pragma unroll
    for (int n = 0; n < 5; ++n) se += expf(cls[n] - m);
    const float lse = m + logf(se);
#pragma unroll
    for (int n = 0; n < 5; ++n) out[tid * 5 + n] = cls[n] - lse;
  }
}

extern "C" void kernel_launch(void* const* d_in, const int* in_sizes, int n_in,
                              void* d_out, int out_size, void* d_ws,
                              size_t ws_size, hipStream_t stream) {
  (void)in_sizes; (void)n_in; (void)out_size; (void)ws_size;
  const float* support = (const float*)d_in[0];
  const float* query   = (const float*)d_in[1];
  const float* cw1 = (const float*)d_in[2];  const float* cb1 = (const float*)d_in[3];
  const float* cw2 = (const float*)d_in[4];  const float* cb2 = (const float*)d_in[5];
  const float* cw3 = (const float*)d_in[6];  const float* cb3 = (const float*)d_in[7];
  const float* cw4 = (const float*)d_in[8];  const float* cb4 = (const float*)d_in[9];
  const float* g1  = (const float*)d_in[10]; const float* be1 = (const float*)d_in[11];
  const float* g2  = (const float*)d_in[12]; const float* be2 = (const float*)d_in[13];
  const float* g3  = (const float*)d_in[14]; const float* be3 = (const float*)d_in[15];
  const float* g4  = (const float*)d_in[16]; const float* be4 = (const float*)d_in[17];
  const float* aw  = (const float*)d_in[18]; const float* ab  = (const float*)d_in[19];
  const float* wi0 = (const float*)d_in[20]; const float* wh0 = (const float*)d_in[21];
  const float* bi0 = (const float*)d_in[22]; const float* bh0 = (const float*)d_in[23];
  const float* wi1 = (const float*)d_in[24]; const float* wh1 = (const float*)d_in[25];
  const float* bi1 = (const float*)d_in[26]; const float* bh1 = (const float*)d_in[27];
  const float* tw  = (const float*)d_in[28]; const float* tb  = (const float*)d_in[29];

  char* ws = (char*)d_ws;
  float* out = (float*)d_out;
  float* A1    = (float*)(ws + A1_OFF);
  float* X2    = (float*)(ws + X2_OFF);
  float* P2    = (float*)(ws + P2_OFF);
  float* X3    = (float*)(ws + X3_OFF);
  float* P3    = (float*)(ws + P3_OFF);
  float* X4    = (float*)(ws + X4_OFF);
  float* FEATT = (float*)(ws + FEATT_OFF);
  float* PROJ  = (float*)(ws + PROJ_OFF);
  float* ATT   = (float*)(ws + ATT_OFF);
  float* GI    = (float*)(ws + GI_OFF);
  float* Y0    = (float*)(ws + Y0_OFF);
  float* HFIN  = (float*)(ws + HFIN_OFF);
  u16* WBH = (u16*)(ws + WBH_OFF);
  u16* WBL = (u16*)(ws + WBL_OFF);

  // weight conversions (split hi/lo)
  cvt_conv_w_split<<<(64 * 288 + 255) / 256, 256, 0, stream>>>(cw2, WBH + W2_E, WBL + W2_E, 64, 32);
  cvt_conv_w_split<<<(128 * 576 + 255) / 256, 256, 0, stream>>>(cw3, WBH + W3_E, WBL + W3_E, 128, 64);
  cvt_conv_w_split<<<(256 * 1152 + 255) / 256, 256, 0, stream>>>(cw4, WBH + W4_E, WBL + W4_E, 256, 128);
  cvt_split<<<(64 * 256 + 255) / 256, 256, 0, stream>>>(aw, WBH + AW_E, WBL + AW_E, 64 * 256);
  cvt_split<<<(384 * 512 + 255) / 256, 256, 0, stream>>>(wi0, WBH + WI0_E, WBL + WI0_E, 384 * 512);
  cvt_split<<<(384 * 128 + 255) / 256, 256, 0, stream>>>(wi1, WBH + WI1_E, WBL + WI1_E, 384 * 128);

  // ---- encoder ----
  conv1_pool<<<15680, 256, 0, stream>>>(support, query, cw1, cb1, g1, be1, A1);
  // conv2: A1(40,56,56,32) -> X2(40,56,56,64) -> P2(40,28,28,64)
  sgemm<2, 0><<<dim3(1, 1960), 256, 0, stream>>>(
      A1, nullptr, 125440, 288, WBH + W2_E, WBL + W2_E, cb2, g2, be2, X2, 64,
      56, 56, 32, 5);
  maxpool2_f32<<<1960, 256, 0, stream>>>(X2, P2, NB, 56, 56, 64);
  // conv3: P2 -> X3(40,28,28,128) -> P3(40,14,14,128)
  sgemm<2, 0><<<dim3(2, 490), 256, 0, stream>>>(
      P2, nullptr, 31360, 576, WBH + W3_E, WBL + W3_E, cb3, g3, be3, X3, 128,
      28, 28, 64, 6);
  maxpool2_f32<<<980, 256, 0, stream>>>(X3, P3, NB, 28, 28, 128);
  // conv4: P3 -> X4(40,14,14,256) -> FEATT(40,7,7,256)
  sgemm<2, 0><<<dim3(4, 123), 256, 0, stream>>>(
      P3, nullptr, 7840, 1152, WBH + W4_E, WBL + W4_E, cb4, g4, be4, X4, 256,
      14, 14, 128, 7);
  maxpool2_f32<<<490, 256, 0, stream>>>(X4, FEATT, NB, 14, 14, 256);

  // ---- attention ----
  sgemm<0, 1><<<dim3(1, 31), 256, 0, stream>>>(
      FEATT, nullptr, NB * T49, 256, WBH + AW_E, WBL + AW_E, ab, nullptr,
      nullptr, PROJ, 64, 0, 0, 0, 0);
  attention_f32<<<B3, 512, 0, stream>>>(PROJ, FEATT, ATT);

  // ---- GRU stack ----
  sgemm<1, 1><<<dim3(6, 288), 256, 0, stream>>>(
      ATT, FEATT, B3 * T49, 512, WBH + WI0_E, WBL + WI0_E, bi0, nullptr,
      nullptr, GI, 384, 0, 0, 0, 0);
  gru_mfma<<<47, 512, 0, stream>>>(GI, wh0, bh0, Y0, 1);
  sgemm<0, 1><<<dim3(6, 288), 256, 0, stream>>>(
      Y0, nullptr, B3 * T49, 128, WBH + WI1_E, WBL + WI1_E, bi1, nullptr,
      nullptr, GI, 384, 0, 0, 0, 0);
  gru_mfma<<<47, 512, 0, stream>>>(GI, wh1, bh1, HFIN, 0);

  // ---- head ----
  head_kernel<<<1, 512, 0, stream>>>(HFIN, tw, tb, out);
}

// Round 10
// 441.664 us; speedup vs baseline: 8.5383x; 1.0440x over previous
//
#include <hip/hip_runtime.h>
#include <hip/hip_bf16.h>
#include <math.h>

typedef unsigned short u16;
typedef unsigned int u32;
typedef __attribute__((ext_vector_type(8))) short bf16x8v;
typedef __attribute__((ext_vector_type(4))) float f32x4;

// ---------------- problem constants ----------------
constexpr int NS = 25, NQ = 15, NB = 40;
constexpr int B3 = 375;     // 15*25
constexpr int T49 = 49;
constexpr float BN_INV = 0.9999950000374997f;

// ---------------- workspace layout (BYTES), f32 activations ----------------
constexpr size_t A1_OFF    = 0;            // (40,56,56,32) f32 = 16,056,320
constexpr size_t X2_OFF    = 16056320;     // (40,56,56,64) f32 = 32,112,640
constexpr size_t P2_OFF    = 48168960;     // (40,28,28,64) f32 = 8,028,160
constexpr size_t X3_OFF    = 0;            // (40,28,28,128) f32 = 16,056,320
constexpr size_t P3_OFF    = 56197120;     // (40,14,14,128) f32 = 4,014,080
constexpr size_t X4_OFF    = 16056320;     // (40,14,14,256) f32 = 8,028,160
constexpr size_t FEATT_OFF = 60211200;     // (40,49,256) f32 = 2,007,040
constexpr size_t PROJ_OFF  = 24084480;     // (1960,64) f32 = 501,760
constexpr size_t ATT_OFF   = 24586240;     // (375,49,256) f32 = 18,816,000
constexpr size_t GI_OFF    = 62218240;     // (18375,384) f32 = 28,224,000
constexpr size_t Y0_OFF    = 0;            // (18375,128) f32 = 9,408,000
constexpr size_t HFIN_OFF  = 90442240;     // (375,128) f32 = 192,000
constexpr size_t WBH_OFF   = 91027456;     // bf16-hi arena 649,216 u16
constexpr size_t WBL_OFF   = 92325888;     // bf16-lo arena
// u16-element offsets within each arena:
constexpr size_t W2_E = 0;        // 64*288
constexpr size_t W3_E = 18432;    // 128*576
constexpr size_t W4_E = 92160;    // 256*1152
constexpr size_t AW_E = 387072;   // 64*256
constexpr size_t WI0_E = 403456;  // 384*512
constexpr size_t WI1_E = 600064;  // 384*128

static __device__ __forceinline__ u16 f2b(float f) {
  __hip_bfloat16 h = __float2bfloat16(f);
  return *reinterpret_cast<u16*>(&h);
}
static __device__ __forceinline__ float b2f(u16 u) {
  return __uint_as_float((u32)u << 16);
}
// split v into hi+lo bf16 pair, packed into u32 words
static __device__ __forceinline__ void split8(const float* v, u32* hp, u32* lp) {
  u16 h[8], l[8];
#pragma unroll
  for (int j = 0; j < 8; ++j) {
    const u16 hb = f2b(v[j]);
    h[j] = hb;
    l[j] = f2b(v[j] - b2f(hb));
  }
#pragma unroll
  for (int j = 0; j < 4; ++j) {
    hp[j] = (u32)h[2 * j] | ((u32)h[2 * j + 1] << 16);
    lp[j] = (u32)l[2 * j] | ((u32)l[2 * j + 1] << 16);
  }
}
// fast sigmoid / tanh (exp2+rcp intrinsics; err ~1e-6, validated at absmax 0.0)
constexpr float LOG2E = 1.4426950408889634f;
static __device__ __forceinline__ float fsigmoid(float x) {
  return __builtin_amdgcn_rcpf(1.f + __builtin_amdgcn_exp2f(-x * LOG2E));
}
static __device__ __forceinline__ float ftanh(float x) {
  return 1.f - 2.f * __builtin_amdgcn_rcpf(__builtin_amdgcn_exp2f(x * (2.f * LOG2E)) + 1.f);
}

// ---------------- weight split converters ----------------
__global__ void cvt_split(const float* __restrict__ x, u16* __restrict__ oh,
                          u16* __restrict__ ol, int n) {
  int i = blockIdx.x * 256 + threadIdx.x;
  if (i >= n) return;
  const float v = x[i];
  const u16 h = f2b(v);
  oh[i] = h;
  ol[i] = f2b(v - b2f(h));
}
// OIHW f32 -> [oc][(ky*3+kx)*IC + ic] hi/lo bf16
__global__ void cvt_conv_w_split(const float* __restrict__ w, u16* __restrict__ oh,
                                 u16* __restrict__ ol, int OC, int IC) {
  const int n = OC * IC * 9;
  int i = blockIdx.x * 256 + threadIdx.x;
  if (i >= n) return;
  const int oc = i / (IC * 9), rem = i % (IC * 9);
  const int e = rem / IC, ic = rem % IC;
  const int ky = e / 3, kx = e % 3;
  const float v = w[((size_t)(oc * IC + ic) * 3 + ky) * 3 + kx];
  const u16 h = f2b(v);
  oh[i] = h;
  ol[i] = f2b(v - b2f(h));
}

// ---------------- fused conv1(s2)+BN+ReLU+pool2, f32 out NHWC ----------------
__global__ __launch_bounds__(256) void conv1_pool(
    const float* __restrict__ support, const float* __restrict__ query,
    const float* __restrict__ w1, const float* __restrict__ cb1,
    const float* __restrict__ g1, const float* __restrict__ be1,
    float* __restrict__ out) {
  __shared__ float wl[288], scl[32], shl[32], cbl[32];
  const int tid = threadIdx.x;
  for (int l = tid; l < 288; l += 256) wl[l] = w1[l];  // FIX(r5): strided, 288>256
  if (tid < 32) { scl[tid] = g1[tid] * BN_INV; shl[tid] = be1[tid]; cbl[tid] = cb1[tid]; }
  __syncthreads();
  const int oc = tid & 31;
  const int p = blockIdx.x * 8 + (tid >> 5);   // 0 .. 125439 = (b,oy,ox)
  const int ox = p % 56, oy = (p / 56) % 56, b = p / 3136;
  const float* in_b = (b < NS) ? (support + (size_t)b * 50176)
                               : (query + (size_t)(b - NS) * 50176);
  const int iy0 = 4 * oy - 1, ix0 = 4 * ox - 1;
  float pat[5][5];
#pragma unroll
  for (int dy = 0; dy < 5; ++dy) {
    const int iy = iy0 + dy;
#pragma unroll
    for (int dx = 0; dx < 5; ++dx) {
      const int ix = ix0 + dx;
      pat[dy][dx] = (iy >= 0 && iy < 224 && ix >= 0 && ix < 224)
                        ? in_b[(size_t)iy * 224 + ix] : 0.f;
    }
  }
  const float* wp = &wl[oc * 9];
  float mx = 0.f;  // post-ReLU values >= 0
#pragma unroll
  for (int py = 0; py < 2; ++py)
#pragma unroll
    for (int px = 0; px < 2; ++px) {
      float acc = 0.f;
#pragma unroll
      for (int ky = 0; ky < 3; ++ky)
#pragma unroll
        for (int kx = 0; kx < 3; ++kx)
          acc += pat[2 * py + ky][2 * px + kx] * wp[ky * 3 + kx];
      float v = (acc + cbl[oc]) * scl[oc] + shl[oc];
      mx = fmaxf(mx, v);
    }
  out[(size_t)p * 32 + oc] = mx;
}

// ---------------- f32 NHWC maxpool 2x2 ----------------
__global__ void maxpool2_f32(const float* __restrict__ X, float* __restrict__ Y,
                             int Bn, int H, int W, int C) {
  const int OH = H >> 1, OW = W >> 1;
  const int cpr = C >> 2;
  const int chunks = Bn * OH * OW * cpr;
  for (int i = blockIdx.x * blockDim.x + threadIdx.x; i < chunks;
       i += gridDim.x * blockDim.x) {
    const int c4 = i % cpr, m = i / cpr;
    const int ox = m % OW, oy = (m / OW) % OH, b = m / (OW * OH);
    const size_t base = (((size_t)b * H + 2 * oy) * W + 2 * ox) * C + (c4 << 2);
    const float4 r0 = *(const float4*)&X[base];
    const float4 r1 = *(const float4*)&X[base + C];
    const float4 r2 = *(const float4*)&X[base + (size_t)W * C];
    const float4 r3 = *(const float4*)&X[base + (size_t)W * C + C];
    float4 o;
    o.x = fmaxf(fmaxf(r0.x, r1.x), fmaxf(r2.x, r3.x));
    o.y = fmaxf(fmaxf(r0.y, r1.y), fmaxf(r2.y, r3.y));
    o.z = fmaxf(fmaxf(r0.z, r1.z), fmaxf(r2.z, r3.z));
    o.w = fmaxf(fmaxf(r0.w, r1.w), fmaxf(r2.w, r3.w));
    *(float4*)&Y[(size_t)m * C + (c4 << 2)] = o;
  }
}

// ---------------- split-bf16 MFMA GEMM: C = epi(A @ W^T) --------------------
// 3-pass Dekker: acc += Ah*Wh + Ah*Wl + Al*Wh  (error ~1.6e-5 relative)
// AMODE 0: A f32 (M x K) contiguous.
// AMODE 1: K=512 concat gather: k<256 -> A(=ATT f32), else A2(=FEATT f32) qrep.
// AMODE 2: implicit im2col from A = NHWC f32 (Bn,H,W,IC); K = 9*IC; pad=1.
// EPI 0: f32 out = relu((acc+p0[n])*p1[n]*BN_INV + p2[n]).  EPI 1: f32 out = acc+p0[n].
template <int AMODE, int EPI>
__global__ __launch_bounds__(256) void sgemm(
    const float* __restrict__ A, const float* __restrict__ A2, int M, int K,
    const u16* __restrict__ Bh, const u16* __restrict__ Bl,
    const float* __restrict__ p0, const float* __restrict__ p1,
    const float* __restrict__ p2, float* __restrict__ Cout, int ldc,
    int H, int W, int IC, int icb) {
  __shared__ u16 Ash[64][72], Asl[64][72];
  __shared__ u16 Bsh[64][72], Bsl[64][72];
  const int tid = threadIdx.x;
  const int lane = tid & 63, wv = tid >> 6;
  const int wy = wv >> 1, wx = wv & 1;
  const int n0 = blockIdx.x * 64, m0 = blockIdx.y * 64;
  f32x4 acc[2][2] = {{{0, 0, 0, 0}, {0, 0, 0, 0}}, {{0, 0, 0, 0}, {0, 0, 0, 0}}};
  for (int k0 = 0; k0 < K; k0 += 64) {
    // ---- stage A (split f32 -> hi/lo bf16) ----
#pragma unroll
    for (int s = 0; s < 2; ++s) {
      const int c = s * 256 + tid;
      const int row = c >> 3, kc = (c & 7) << 3;
      const int gm = m0 + row, gk = k0 + kc;
      float4 x0 = {0, 0, 0, 0}, x1 = {0, 0, 0, 0};
      if (AMODE == 0) {
        if (gm < M && gk < K) {
          const float* p = A + (size_t)gm * K + gk;
          x0 = *(const float4*)p; x1 = *(const float4*)(p + 4);
        }
      } else if (AMODE == 1) {
        if (gm < M) {
          const float* p;
          if (gk < 256) {
            p = A + (size_t)gm * 256 + gk;
          } else {
            const int b = gm / T49, t = gm % T49, q = b / NS;
            p = A2 + (((size_t)(NS + q) * T49 + t) << 8) + (gk - 256);
          }
          x0 = *(const float4*)p; x1 = *(const float4*)(p + 4);
        }
      } else {  // implicit im2col
        if (gm < M && gk < K) {
          const int ox = gm % W, t_ = gm / W;
          const int oy = t_ % H, b = t_ / H;
          const int e = gk >> icb, ic = gk & (IC - 1);
          const int ky = e / 3, kx = e - 3 * (e / 3);
          const int iy = oy + ky - 1, ix = ox + kx - 1;
          if (iy >= 0 && iy < H && ix >= 0 && ix < W) {
            const float* p = A + (((size_t)b * H + iy) * W + ix) * IC + ic;
            x0 = *(const float4*)p; x1 = *(const float4*)(p + 4);
          }
        }
      }
      float v[8] = {x0.x, x0.y, x0.z, x0.w, x1.x, x1.y, x1.z, x1.w};
      u32 hp[4], lp[4];
      split8(v, hp, lp);
      *(uint4*)&Ash[row][kc] = *(uint4*)hp;
      *(uint4*)&Asl[row][kc] = *(uint4*)lp;
    }
    // ---- stage B (pre-split weights) ----
#pragma unroll
    for (int s = 0; s < 2; ++s) {
      const int c = s * 256 + tid;
      const int row = c >> 3, kc = (c & 7) << 3;
      const int gk = k0 + kc;
      uint4 vh = {0u, 0u, 0u, 0u}, vl = {0u, 0u, 0u, 0u};
      if (gk < K) {
        vh = *(const uint4*)&Bh[(size_t)(n0 + row) * K + gk];
        vl = *(const uint4*)&Bl[(size_t)(n0 + row) * K + gk];
      }
      *(uint4*)&Bsh[row][kc] = vh;
      *(uint4*)&Bsl[row][kc] = vl;
    }
    __syncthreads();
#pragma unroll
    for (int kk = 0; kk < 64; kk += 32) {
      const int ko = kk + ((lane >> 4) << 3);
      const int ra0 = wy * 32 + (lane & 15), ra1 = ra0 + 16;
      const int rb0 = wx * 32 + (lane & 15), rb1 = rb0 + 16;
      bf16x8v a0h = *(const bf16x8v*)&Ash[ra0][ko];
      bf16x8v a1h = *(const bf16x8v*)&Ash[ra1][ko];
      bf16x8v b0h = *(const bf16x8v*)&Bsh[rb0][ko];
      bf16x8v b1h = *(const bf16x8v*)&Bsh[rb1][ko];
      bf16x8v a0l = *(const bf16x8v*)&Asl[ra0][ko];
      bf16x8v a1l = *(const bf16x8v*)&Asl[ra1][ko];
      bf16x8v b0l = *(const bf16x8v*)&Bsl[rb0][ko];
      bf16x8v b1l = *(const bf16x8v*)&Bsl[rb1][ko];
      acc[0][0] = __builtin_amdgcn_mfma_f32_16x16x32_bf16(a0h, b0h, acc[0][0], 0, 0, 0);
      acc[0][1] = __builtin_amdgcn_mfma_f32_16x16x32_bf16(a0h, b1h, acc[0][1], 0, 0, 0);
      acc[1][0] = __builtin_amdgcn_mfma_f32_16x16x32_bf16(a1h, b0h, acc[1][0], 0, 0, 0);
      acc[1][1] = __builtin_amdgcn_mfma_f32_16x16x32_bf16(a1h, b1h, acc[1][1], 0, 0, 0);
      acc[0][0] = __builtin_amdgcn_mfma_f32_16x16x32_bf16(a0h, b0l, acc[0][0], 0, 0, 0);
      acc[0][1] = __builtin_amdgcn_mfma_f32_16x16x32_bf16(a0h, b1l, acc[0][1], 0, 0, 0);
      acc[1][0] = __builtin_amdgcn_mfma_f32_16x16x32_bf16(a1h, b0l, acc[1][0], 0, 0, 0);
      acc[1][1] = __builtin_amdgcn_mfma_f32_16x16x32_bf16(a1h, b1l, acc[1][1], 0, 0, 0);
      acc[0][0] = __builtin_amdgcn_mfma_f32_16x16x32_bf16(a0l, b0h, acc[0][0], 0, 0, 0);
      acc[0][1] = __builtin_amdgcn_mfma_f32_16x16x32_bf16(a0l, b1h, acc[0][1], 0, 0, 0);
      acc[1][0] = __builtin_amdgcn_mfma_f32_16x16x32_bf16(a1l, b0h, acc[1][0], 0, 0, 0);
      acc[1][1] = __builtin_amdgcn_mfma_f32_16x16x32_bf16(a1l, b1h, acc[1][1], 0, 0, 0);
    }
    __syncthreads();
  }
  // ---- epilogue (f32 out) ----
#pragma unroll
  for (int r = 0; r < 2; ++r) {
#pragma unroll
    for (int c = 0; c < 2; ++c) {
      const int gn = n0 + wx * 32 + c * 16 + (lane & 15);
      float sc0 = 0.f, sh0 = 0.f;
      if (EPI == 0) { sc0 = p1[gn] * BN_INV; sh0 = p2[gn]; }
#pragma unroll
      for (int i = 0; i < 4; ++i) {
        const int gm = m0 + wy * 32 + r * 16 + ((lane >> 4) << 2) + i;
        if (gm >= M) continue;
        const float a = acc[r][c][i];
        if (EPI == 0) {
          Cout[(size_t)gm * ldc + gn] = fmaxf((a + p0[gn]) * sc0 + sh0, 0.f);
        } else {
          Cout[(size_t)gm * ldc + gn] = a + p0[gn];
        }
      }
    }
  }
}

// ---------------- fused attention, block = (q,s,t-group of 7) ---------------
// r9: grid 375->2625 blocks (smooth CU balance, was 1.46 blk/CU with 2x
// rounding imbalance at 29% occupancy), 4-acc ILP in the tanh h-loop,
// fast exp2 softmax. LDS ~17KB -> 4 blocks/CU co-resident.
__global__ __launch_bounds__(512) void attention_f32(
    const float* __restrict__ proj, const float* __restrict__ featT,
    float* __restrict__ attended) {
  __shared__ float WqT[64][8];    // [h][tloc], 7 rows used
  __shared__ float WhT[64][51];   // [h][u], odd pad -> conflict-free
  __shared__ float sc[7][64];
  const int bid = blockIdx.x;
  const int qs = bid / 7, tg = bid - 7 * qs;
  const int q = qs / NS, s = qs - NS * q;
  const int tid = threadIdx.x;
  const float* pq = proj + ((size_t)(NS + q) * T49 + tg * 7) * 64;
  const float* ph = proj + (size_t)s * T49 * 64;
  for (int l = tid; l < 7 * 64; l += 512) WqT[l & 63][l >> 6] = pq[l];
  for (int l = tid; l < T49 * 64; l += 512) WhT[l & 63][l >> 6] = ph[l];
  __syncthreads();
  constexpr float C2LOG2E = 2.8853900817779268f;
  if (tid < 343) {
    const int tl = tid / 49, u = tid - 49 * tl;
    float a0 = 0.f, a1 = 0.f, a2 = 0.f, a3 = 0.f;
#pragma unroll
    for (int h = 0; h < 64; h += 4) {
      const float p0 = WqT[h + 0][tl] * WhT[h + 0][u];
      const float p1 = WqT[h + 1][tl] * WhT[h + 1][u];
      const float p2 = WqT[h + 2][tl] * WhT[h + 2][u];
      const float p3 = WqT[h + 3][tl] * WhT[h + 3][u];
      a0 += 1.f - 2.f * __builtin_amdgcn_rcpf(__builtin_amdgcn_exp2f(p0 * C2LOG2E) + 1.f);
      a1 += 1.f - 2.f * __builtin_amdgcn_rcpf(__builtin_amdgcn_exp2f(p1 * C2LOG2E) + 1.f);
      a2 += 1.f - 2.f * __builtin_amdgcn_rcpf(__builtin_amdgcn_exp2f(p2 * C2LOG2E) + 1.f);
      a3 += 1.f - 2.f * __builtin_amdgcn_rcpf(__builtin_amdgcn_exp2f(p3 * C2LOG2E) + 1.f);
    }
    sc[tl][u] = (a0 + a1) + (a2 + a3);
  }
  __syncthreads();
  if (tid < 7) {  // softmax over u per local row
    float* row = sc[tid];
    float m = row[0];
    for (int u = 1; u < T49; ++u) m = fmaxf(m, row[u]);
    float ssum = 0.f;
    for (int u = 0; u < T49; ++u) {
      const float e = __builtin_amdgcn_exp2f((row[u] - m) * LOG2E);
      row[u] = e; ssum += e;
    }
    const float inv = 1.f / ssum;
    for (int u = 0; u < T49; ++u) row[u] *= inv;
  }
  __syncthreads();
  // PV: 512 thr = 2 groups x 256 f; group 0 -> t 0..3, group 1 -> t 4..6
  const float* fs = featT + (size_t)s * T49 * 256;
  float* outp = attended + (size_t)qs * T49 * 256;
  const int f = tid & 255, g = tid >> 8;
  const int tb = g ? 4 : 0, nt = g ? 3 : 4;
  float acc[4] = {0.f, 0.f, 0.f, 0.f};
  for (int u = 0; u < T49; ++u) {
    const float v = fs[u * 256 + f];
#pragma unroll
    for (int i = 0; i < 4; ++i)
      if (i < nt) acc[i] += sc[tb + i][u] * v;
  }
#pragma unroll
  for (int i = 0; i < 4; ++i)
    if (i < nt) outp[(size_t)(tg * 7 + tb + i) * 256 + f] = acc[i];
}

// ---------------- batched split-bf16 MFMA GRU ----------------
// r8: SPB=8 (47 blocks), gi prefetched one step ahead, fast exp2 gates.
// Wh register-resident hi/lo bf16 (3-pass Dekker MFMA).
constexpr int SPB = 8;
__global__ __launch_bounds__(512) void gru_mfma(
    const float* __restrict__ gi,   // (375,49,384), includes bi
    const float* __restrict__ wh,   // (384,128) f32
    const float* __restrict__ bh,   // (384)
    float* __restrict__ y,          // (375,49,128) if store_all else (375,128)
    int store_all) {
  __shared__ u16 hah[16][136], hal[16][136];
  __shared__ float ghs[SPB][384];
  __shared__ float hfl[SPB][128];
  const int tid = threadIdx.x;
  const int lane = tid & 63, wv = tid >> 6;   // 8 waves
  const int r0 = blockIdx.x * SPB;
  bf16x8v Bhr[3][4], Blr[3][4];
#pragma unroll
  for (int f = 0; f < 3; ++f) {
    const int n = (wv * 3 + f) * 16 + (lane & 15);
#pragma unroll
    for (int kk = 0; kk < 4; ++kk) {
      const int k = kk * 32 + ((lane >> 4) << 3);
      const float* p = wh + (size_t)n * 128 + k;
      float v[8];
      *(float4*)&v[0] = *(const float4*)p;
      *(float4*)&v[4] = *(const float4*)(p + 4);
      u32 hp[4], lp[4];
      split8(v, hp, lp);
      Bhr[f][kk] = *(bf16x8v*)hp;
      Blr[f][kk] = *(bf16x8v*)lp;
    }
  }
  const int row0 = tid >> 7, j0 = tid & 127;
  const int row1 = (512 + tid) >> 7, j1 = tid & 127;
  int sq0 = r0 + row0; if (sq0 >= B3) sq0 = B3 - 1;
  int sq1 = r0 + row1; if (sq1 >= B3) sq1 = B3 - 1;
  const float bhr0 = bh[j0], bhz0 = bh[128 + j0], bhn0 = bh[256 + j0];
  const float bhr1 = bh[j1], bhz1 = bh[128 + j1], bhn1 = bh[256 + j1];
  const float* gib0 = gi + (size_t)sq0 * T49 * 384;
  const float* gib1 = gi + (size_t)sq1 * T49 * 384;
  for (int i = tid; i < 16 * 136; i += 512) { hah[i / 136][i % 136] = 0; hal[i / 136][i % 136] = 0; }
  for (int i = tid; i < SPB * 128; i += 512) hfl[i >> 7][i & 127] = 0.f;
  __syncthreads();
  const int ar = lane & 15, ko = (lane >> 4) << 3;
  float xr0c = gib0[j0], xz0c = gib0[128 + j0], xn0c = gib0[256 + j0];
  float xr1c = gib1[j1], xz1c = gib1[128 + j1], xn1c = gib1[256 + j1];
  for (int t = 0; t < T49; ++t) {
    const int tn = (t + 1 < T49) ? t + 1 : t;
    const float* g0n = gib0 + (size_t)tn * 384;
    const float* g1n = gib1 + (size_t)tn * 384;
    const float xr0n = g0n[j0], xz0n = g0n[128 + j0], xn0n = g0n[256 + j0];
    const float xr1n = g1n[j1], xz1n = g1n[128 + j1], xn1n = g1n[256 + j1];
    bf16x8v Ah[4], Al[4];
#pragma unroll
    for (int kk = 0; kk < 4; ++kk) {
      Ah[kk] = *(const bf16x8v*)&hah[ar][kk * 32 + ko];
      Al[kk] = *(const bf16x8v*)&hal[ar][kk * 32 + ko];
    }
#pragma unroll
    for (int f = 0; f < 3; ++f) {
      f32x4 acc = {0, 0, 0, 0};
#pragma unroll
      for (int kk = 0; kk < 4; ++kk)
        acc = __builtin_amdgcn_mfma_f32_16x16x32_bf16(Ah[kk], Bhr[f][kk], acc, 0, 0, 0);
#pragma unroll
      for (int kk = 0; kk < 4; ++kk)
        acc = __builtin_amdgcn_mfma_f32_16x16x32_bf16(Ah[kk], Blr[f][kk], acc, 0, 0, 0);
#pragma unroll
      for (int kk = 0; kk < 4; ++kk)
        acc = __builtin_amdgcn_mfma_f32_16x16x32_bf16(Al[kk], Bhr[f][kk], acc, 0, 0, 0);
      const int nc = (wv * 3 + f) * 16 + (lane & 15);
      const int rb = (lane >> 4) << 2;
      if (rb < SPB) {
#pragma unroll
        for (int i = 0; i < 4; ++i) ghs[rb + i][nc] = acc[i];
      }
    }
    __syncthreads();
    {
      const float r_ = fsigmoid(xr0c + ghs[row0][j0] + bhr0);
      const float z_ = fsigmoid(xz0c + ghs[row0][128 + j0] + bhz0);
      const float n_ = ftanh(xn0c + r_ * (ghs[row0][256 + j0] + bhn0));
      const float hn = (1.f - z_) * n_ + z_ * hfl[row0][j0];
      hfl[row0][j0] = hn;
      const u16 hb = f2b(hn);
      hah[row0][j0] = hb;
      hal[row0][j0] = f2b(hn - b2f(hb));
      if (r0 + row0 < B3) {
        if (store_all) y[((size_t)(r0 + row0) * T49 + t) * 128 + j0] = hn;
        else if (t == T49 - 1) y[(size_t)(r0 + row0) * 128 + j0] = hn;
      }
    }
    {
      const float r_ = fsigmoid(xr1c + ghs[row1][j1] + bhr1);
      const float z_ = fsigmoid(xz1c + ghs[row1][128 + j1] + bhz1);
      const float n_ = ftanh(xn1c + r_ * (ghs[row1][256 + j1] + bhn1));
      const float hn = (1.f - z_) * n_ + z_ * hfl[row1][j1];
      hfl[row1][j1] = hn;
      const u16 hb = f2b(hn);
      hah[row1][j1] = hb;
      hal[row1][j1] = f2b(hn - b2f(hb));
      if (r0 + row1 < B3) {
        if (store_all) y[((size_t)(r0 + row1) * T49 + t) * 128 + j1] = hn;
        else if (t == T49 - 1) y[(size_t)(r0 + row1) * 128 + j1] = hn;
      }
    }
    __syncthreads();
    xr0c = xr0n; xz0c = xz0n; xn0c = xn0n;
    xr1c = xr1n; xz1c = xz1n; xn1c = xn1n;
  }
}

// ---------------- head ----------------
__global__ __launch_bounds__(512) void head_kernel(
    const float* __restrict__ hf, const float* __restrict__ tw,
    const float* __restrict__ tb, float* __restrict__ out) {
  __shared__ float lg[B3];
  const int tid = threadIdx.x;
  if (tid < B3) {
    const float* h = hf + (size_t)tid * 128;
    float acc = tb[0];
    for (int k = 0; k < 128; ++k) acc += h[k] * tw[k];
    lg[tid] = acc;
  }
  __syncthreads();
  if (tid < NQ) {
    float cls[5];
#pragma unroll
    for (int n = 0; n < 5; ++n) {
      float s = 0.f;
#pragma unroll
      for (int k = 0; k < 5; ++k) s += lg[tid * 25 + n * 5 + k];
      cls[n] = s;
    }
    float m = cls[0];
#pragma unroll
    for (int n = 1; n < 5; ++n) m = fmaxf(m, cls[n]);
    float se = 0.f;
#pragma unroll
    for (int n = 0; n < 5; ++n) se += expf(cls[n] - m);
    const float lse = m + logf(se);
#pragma unroll
    for (int n = 0; n < 5; ++n) out[tid * 5 + n] = cls[n] - lse;
  }
}

extern "C" void kernel_launch(void* const* d_in, const int* in_sizes, int n_in,
                              void* d_out, int out_size, void* d_ws,
                              size_t ws_size, hipStream_t stream) {
  (void)in_sizes; (void)n_in; (void)out_size; (void)ws_size;
  const float* support = (const float*)d_in[0];
  const float* query   = (const float*)d_in[1];
  const float* cw1 = (const float*)d_in[2];  const float* cb1 = (const float*)d_in[3];
  const float* cw2 = (const float*)d_in[4];  const float* cb2 = (const float*)d_in[5];
  const float* cw3 = (const float*)d_in[6];  const float* cb3 = (const float*)d_in[7];
  const float* cw4 = (const float*)d_in[8];  const float* cb4 = (const float*)d_in[9];
  const float* g1  = (const float*)d_in[10]; const float* be1 = (const float*)d_in[11];
  const float* g2  = (const float*)d_in[12]; const float* be2 = (const float*)d_in[13];
  const float* g3  = (const float*)d_in[14]; const float* be3 = (const float*)d_in[15];
  const float* g4  = (const float*)d_in[16]; const float* be4 = (const float*)d_in[17];
  const float* aw  = (const float*)d_in[18]; const float* ab  = (const float*)d_in[19];
  const float* wi0 = (const float*)d_in[20]; const float* wh0 = (const float*)d_in[21];
  const float* bi0 = (const float*)d_in[22]; const float* bh0 = (const float*)d_in[23];
  const float* wi1 = (const float*)d_in[24]; const float* wh1 = (const float*)d_in[25];
  const float* bi1 = (const float*)d_in[26]; const float* bh1 = (const float*)d_in[27];
  const float* tw  = (const float*)d_in[28]; const float* tb  = (const float*)d_in[29];

  char* ws = (char*)d_ws;
  float* out = (float*)d_out;
  float* A1    = (float*)(ws + A1_OFF);
  float* X2    = (float*)(ws + X2_OFF);
  float* P2    = (float*)(ws + P2_OFF);
  float* X3    = (float*)(ws + X3_OFF);
  float* P3    = (float*)(ws + P3_OFF);
  float* X4    = (float*)(ws + X4_OFF);
  float* FEATT = (float*)(ws + FEATT_OFF);
  float* PROJ  = (float*)(ws + PROJ_OFF);
  float* ATT   = (float*)(ws + ATT_OFF);
  float* GI    = (float*)(ws + GI_OFF);
  float* Y0    = (float*)(ws + Y0_OFF);
  float* HFIN  = (float*)(ws + HFIN_OFF);
  u16* WBH = (u16*)(ws + WBH_OFF);
  u16* WBL = (u16*)(ws + WBL_OFF);

  // weight conversions (split hi/lo)
  cvt_conv_w_split<<<(64 * 288 + 255) / 256, 256, 0, stream>>>(cw2, WBH + W2_E, WBL + W2_E, 64, 32);
  cvt_conv_w_split<<<(128 * 576 + 255) / 256, 256, 0, stream>>>(cw3, WBH + W3_E, WBL + W3_E, 128, 64);
  cvt_conv_w_split<<<(256 * 1152 + 255) / 256, 256, 0, stream>>>(cw4, WBH + W4_E, WBL + W4_E, 256, 128);
  cvt_split<<<(64 * 256 + 255) / 256, 256, 0, stream>>>(aw, WBH + AW_E, WBL + AW_E, 64 * 256);
  cvt_split<<<(384 * 512 + 255) / 256, 256, 0, stream>>>(wi0, WBH + WI0_E, WBL + WI0_E, 384 * 512);
  cvt_split<<<(384 * 128 + 255) / 256, 256, 0, stream>>>(wi1, WBH + WI1_E, WBL + WI1_E, 384 * 128);

  // ---- encoder ----
  conv1_pool<<<15680, 256, 0, stream>>>(support, query, cw1, cb1, g1, be1, A1);
  // conv2: A1(40,56,56,32) -> X2(40,56,56,64) -> P2(40,28,28,64)
  sgemm<2, 0><<<dim3(1, 1960), 256, 0, stream>>>(
      A1, nullptr, 125440, 288, WBH + W2_E, WBL + W2_E, cb2, g2, be2, X2, 64,
      56, 56, 32, 5);
  maxpool2_f32<<<1960, 256, 0, stream>>>(X2, P2, NB, 56, 56, 64);
  // conv3: P2 -> X3(40,28,28,128) -> P3(40,14,14,128)
  sgemm<2, 0><<<dim3(2, 490), 256, 0, stream>>>(
      P2, nullptr, 31360, 576, WBH + W3_E, WBL + W3_E, cb3, g3, be3, X3, 128,
      28, 28, 64, 6);
  maxpool2_f32<<<980, 256, 0, stream>>>(X3, P3, NB, 28, 28, 128);
  // conv4: P3 -> X4(40,14,14,256) -> FEATT(40,7,7,256)
  sgemm<2, 0><<<dim3(4, 123), 256, 0, stream>>>(
      P3, nullptr, 7840, 1152, WBH + W4_E, WBL + W4_E, cb4, g4, be4, X4, 256,
      14, 14, 128, 7);
  maxpool2_f32<<<490, 256, 0, stream>>>(X4, FEATT, NB, 14, 14, 256);

  // ---- attention ----
  sgemm<0, 1><<<dim3(1, 31), 256, 0, stream>>>(
      FEATT, nullptr, NB * T49, 256, WBH + AW_E, WBL + AW_E, ab, nullptr,
      nullptr, PROJ, 64, 0, 0, 0, 0);
  attention_f32<<<B3 * 7, 512, 0, stream>>>(PROJ, FEATT, ATT);

  // ---- GRU stack ----
  sgemm<1, 1><<<dim3(6, 288), 256, 0, stream>>>(
      ATT, FEATT, B3 * T49, 512, WBH + WI0_E, WBL + WI0_E, bi0, nullptr,
      nullptr, GI, 384, 0, 0, 0, 0);
  gru_mfma<<<47, 512, 0, stream>>>(GI, wh0, bh0, Y0, 1);
  sgemm<0, 1><<<dim3(6, 288), 256, 0, stream>>>(
      Y0, nullptr, B3 * T49, 128, WBH + WI1_E, WBL + WI1_E, bi1, nullptr,
      nullptr, GI, 384, 0, 0, 0, 0);
  gru_mfma<<<47, 512, 0, stream>>>(GI, wh1, bh1, HFIN, 0);

  // ---- head ----
  head_kernel<<<1, 512, 0, stream>>>(HFIN, tw, tb, out);
}

// Round 11
// 404.986 us; speedup vs baseline: 9.3116x; 1.0906x over previous
//
#include <hip/hip_runtime.h>
#include <hip/hip_bf16.h>
#include <math.h>

typedef unsigned short u16;
typedef unsigned int u32;
typedef __attribute__((ext_vector_type(8))) short bf16x8v;
typedef __attribute__((ext_vector_type(4))) float f32x4;

// ---------------- problem constants ----------------
constexpr int NS = 25, NQ = 15, NB = 40;
constexpr int B3 = 375;     // 15*25
constexpr int T49 = 49;
constexpr float BN_INV = 0.9999950000374997f;

// ---------------- workspace layout (BYTES), f32 activations ----------------
constexpr size_t A1_OFF    = 0;            // (40,56,56,32) f32 = 16,056,320
constexpr size_t X2_OFF    = 16056320;     // (40,56,56,64) f32 = 32,112,640
constexpr size_t P2_OFF    = 48168960;     // (40,28,28,64) f32 = 8,028,160
constexpr size_t X3_OFF    = 0;            // (40,28,28,128) f32 = 16,056,320
constexpr size_t P3_OFF    = 56197120;     // (40,14,14,128) f32 = 4,014,080
constexpr size_t X4_OFF    = 16056320;     // (40,14,14,256) f32 = 8,028,160
constexpr size_t FEATT_OFF = 60211200;     // (40,49,256) f32 = 2,007,040
constexpr size_t PROJ_OFF  = 24084480;     // (1960,64) f32 = 501,760
constexpr size_t ATT_OFF   = 24586240;     // (375,49,256) f32 = 18,816,000
constexpr size_t GI_OFF    = 62218240;     // (18375,384) f32 = 28,224,000
constexpr size_t Y0_OFF    = 0;            // (18375,128) f32 = 9,408,000
constexpr size_t HFIN_OFF  = 90442240;     // (375,128) f32 = 192,000
constexpr size_t WBH_OFF   = 91027456;     // bf16-hi arena 649,216 u16
constexpr size_t WBL_OFF   = 92325888;     // bf16-lo arena
// u16-element offsets within each arena:
constexpr size_t W2_E = 0;        // 64*288
constexpr size_t W3_E = 18432;    // 128*576
constexpr size_t W4_E = 92160;    // 256*1152
constexpr size_t AW_E = 387072;   // 64*256
constexpr size_t WI0_E = 403456;  // 384*512
constexpr size_t WI1_E = 600064;  // 384*128

static __device__ __forceinline__ u16 f2b(float f) {
  __hip_bfloat16 h = __float2bfloat16(f);
  return *reinterpret_cast<u16*>(&h);
}
static __device__ __forceinline__ float b2f(u16 u) {
  return __uint_as_float((u32)u << 16);
}
// split v into hi+lo bf16 pair, packed into u32 words
static __device__ __forceinline__ void split8(const float* v, u32* hp, u32* lp) {
  u16 h[8], l[8];
#pragma unroll
  for (int j = 0; j < 8; ++j) {
    const u16 hb = f2b(v[j]);
    h[j] = hb;
    l[j] = f2b(v[j] - b2f(hb));
  }
#pragma unroll
  for (int j = 0; j < 4; ++j) {
    hp[j] = (u32)h[2 * j] | ((u32)h[2 * j + 1] << 16);
    lp[j] = (u32)l[2 * j] | ((u32)l[2 * j + 1] << 16);
  }
}
// fast sigmoid / tanh (exp2+rcp intrinsics; err ~1e-6, validated at absmax 0.0)
constexpr float LOG2E = 1.4426950408889634f;
static __device__ __forceinline__ float fsigmoid(float x) {
  return __builtin_amdgcn_rcpf(1.f + __builtin_amdgcn_exp2f(-x * LOG2E));
}
static __device__ __forceinline__ float ftanh(float x) {
  return 1.f - 2.f * __builtin_amdgcn_rcpf(__builtin_amdgcn_exp2f(x * (2.f * LOG2E)) + 1.f);
}

// ---------------- weight split converters ----------------
__global__ void cvt_split(const float* __restrict__ x, u16* __restrict__ oh,
                          u16* __restrict__ ol, int n) {
  int i = blockIdx.x * 256 + threadIdx.x;
  if (i >= n) return;
  const float v = x[i];
  const u16 h = f2b(v);
  oh[i] = h;
  ol[i] = f2b(v - b2f(h));
}
// OIHW f32 -> [oc][(ky*3+kx)*IC + ic] hi/lo bf16
__global__ void cvt_conv_w_split(const float* __restrict__ w, u16* __restrict__ oh,
                                 u16* __restrict__ ol, int OC, int IC) {
  const int n = OC * IC * 9;
  int i = blockIdx.x * 256 + threadIdx.x;
  if (i >= n) return;
  const int oc = i / (IC * 9), rem = i % (IC * 9);
  const int e = rem / IC, ic = rem % IC;
  const int ky = e / 3, kx = e % 3;
  const float v = w[((size_t)(oc * IC + ic) * 3 + ky) * 3 + kx];
  const u16 h = f2b(v);
  oh[i] = h;
  ol[i] = f2b(v - b2f(h));
}

// ---------------- fused conv1(s2)+BN+ReLU+pool2, f32 out NHWC ----------------
__global__ __launch_bounds__(256) void conv1_pool(
    const float* __restrict__ support, const float* __restrict__ query,
    const float* __restrict__ w1, const float* __restrict__ cb1,
    const float* __restrict__ g1, const float* __restrict__ be1,
    float* __restrict__ out) {
  __shared__ float wl[288], scl[32], shl[32], cbl[32];
  const int tid = threadIdx.x;
  for (int l = tid; l < 288; l += 256) wl[l] = w1[l];  // FIX(r5): strided, 288>256
  if (tid < 32) { scl[tid] = g1[tid] * BN_INV; shl[tid] = be1[tid]; cbl[tid] = cb1[tid]; }
  __syncthreads();
  const int oc = tid & 31;
  const int p = blockIdx.x * 8 + (tid >> 5);   // 0 .. 125439 = (b,oy,ox)
  const int ox = p % 56, oy = (p / 56) % 56, b = p / 3136;
  const float* in_b = (b < NS) ? (support + (size_t)b * 50176)
                               : (query + (size_t)(b - NS) * 50176);
  const int iy0 = 4 * oy - 1, ix0 = 4 * ox - 1;
  float pat[5][5];
#pragma unroll
  for (int dy = 0; dy < 5; ++dy) {
    const int iy = iy0 + dy;
#pragma unroll
    for (int dx = 0; dx < 5; ++dx) {
      const int ix = ix0 + dx;
      pat[dy][dx] = (iy >= 0 && iy < 224 && ix >= 0 && ix < 224)
                        ? in_b[(size_t)iy * 224 + ix] : 0.f;
    }
  }
  const float* wp = &wl[oc * 9];
  float mx = 0.f;  // post-ReLU values >= 0
#pragma unroll
  for (int py = 0; py < 2; ++py)
#pragma unroll
    for (int px = 0; px < 2; ++px) {
      float acc = 0.f;
#pragma unroll
      for (int ky = 0; ky < 3; ++ky)
#pragma unroll
        for (int kx = 0; kx < 3; ++kx)
          acc += pat[2 * py + ky][2 * px + kx] * wp[ky * 3 + kx];
      float v = (acc + cbl[oc]) * scl[oc] + shl[oc];
      mx = fmaxf(mx, v);
    }
  out[(size_t)p * 32 + oc] = mx;
}

// ---------------- f32 NHWC maxpool 2x2 ----------------
__global__ void maxpool2_f32(const float* __restrict__ X, float* __restrict__ Y,
                             int Bn, int H, int W, int C) {
  const int OH = H >> 1, OW = W >> 1;
  const int cpr = C >> 2;
  const int chunks = Bn * OH * OW * cpr;
  for (int i = blockIdx.x * blockDim.x + threadIdx.x; i < chunks;
       i += gridDim.x * blockDim.x) {
    const int c4 = i % cpr, m = i / cpr;
    const int ox = m % OW, oy = (m / OW) % OH, b = m / (OW * OH);
    const size_t base = (((size_t)b * H + 2 * oy) * W + 2 * ox) * C + (c4 << 2);
    const float4 r0 = *(const float4*)&X[base];
    const float4 r1 = *(const float4*)&X[base + C];
    const float4 r2 = *(const float4*)&X[base + (size_t)W * C];
    const float4 r3 = *(const float4*)&X[base + (size_t)W * C + C];
    float4 o;
    o.x = fmaxf(fmaxf(r0.x, r1.x), fmaxf(r2.x, r3.x));
    o.y = fmaxf(fmaxf(r0.y, r1.y), fmaxf(r2.y, r3.y));
    o.z = fmaxf(fmaxf(r0.z, r1.z), fmaxf(r2.z, r3.z));
    o.w = fmaxf(fmaxf(r0.w, r1.w), fmaxf(r2.w, r3.w));
    *(float4*)&Y[(size_t)m * C + (c4 << 2)] = o;
  }
}

// ---------------- split-bf16 MFMA GEMM: C = epi(A @ W^T) --------------------
// 3-pass Dekker: acc += Ah*Wh + Ah*Wl + Al*Wh  (error ~1.6e-5 relative)
// AMODE 0: A f32 (M x K) contiguous.
// AMODE 1: K=512 concat gather: k<256 -> A(=ATT f32), else A2(=FEATT f32) qrep.
// AMODE 2: implicit im2col from A = NHWC f32 (Bn,H,W,IC); K = 9*IC; pad=1.
// EPI 0: f32 out = relu((acc+p0[n])*p1[n]*BN_INV + p2[n]).  EPI 1: f32 out = acc+p0[n].
template <int AMODE, int EPI>
__global__ __launch_bounds__(256) void sgemm(
    const float* __restrict__ A, const float* __restrict__ A2, int M, int K,
    const u16* __restrict__ Bh, const u16* __restrict__ Bl,
    const float* __restrict__ p0, const float* __restrict__ p1,
    const float* __restrict__ p2, float* __restrict__ Cout, int ldc,
    int H, int W, int IC, int icb) {
  __shared__ u16 Ash[64][72], Asl[64][72];
  __shared__ u16 Bsh[64][72], Bsl[64][72];
  const int tid = threadIdx.x;
  const int lane = tid & 63, wv = tid >> 6;
  const int wy = wv >> 1, wx = wv & 1;
  const int n0 = blockIdx.x * 64, m0 = blockIdx.y * 64;
  f32x4 acc[2][2] = {{{0, 0, 0, 0}, {0, 0, 0, 0}}, {{0, 0, 0, 0}, {0, 0, 0, 0}}};
  for (int k0 = 0; k0 < K; k0 += 64) {
    // ---- stage A (split f32 -> hi/lo bf16) ----
#pragma unroll
    for (int s = 0; s < 2; ++s) {
      const int c = s * 256 + tid;
      const int row = c >> 3, kc = (c & 7) << 3;
      const int gm = m0 + row, gk = k0 + kc;
      float4 x0 = {0, 0, 0, 0}, x1 = {0, 0, 0, 0};
      if (AMODE == 0) {
        if (gm < M && gk < K) {
          const float* p = A + (size_t)gm * K + gk;
          x0 = *(const float4*)p; x1 = *(const float4*)(p + 4);
        }
      } else if (AMODE == 1) {
        if (gm < M) {
          const float* p;
          if (gk < 256) {
            p = A + (size_t)gm * 256 + gk;
          } else {
            const int b = gm / T49, t = gm % T49, q = b / NS;
            p = A2 + (((size_t)(NS + q) * T49 + t) << 8) + (gk - 256);
          }
          x0 = *(const float4*)p; x1 = *(const float4*)(p + 4);
        }
      } else {  // implicit im2col
        if (gm < M && gk < K) {
          const int ox = gm % W, t_ = gm / W;
          const int oy = t_ % H, b = t_ / H;
          const int e = gk >> icb, ic = gk & (IC - 1);
          const int ky = e / 3, kx = e - 3 * (e / 3);
          const int iy = oy + ky - 1, ix = ox + kx - 1;
          if (iy >= 0 && iy < H && ix >= 0 && ix < W) {
            const float* p = A + (((size_t)b * H + iy) * W + ix) * IC + ic;
            x0 = *(const float4*)p; x1 = *(const float4*)(p + 4);
          }
        }
      }
      float v[8] = {x0.x, x0.y, x0.z, x0.w, x1.x, x1.y, x1.z, x1.w};
      u32 hp[4], lp[4];
      split8(v, hp, lp);
      *(uint4*)&Ash[row][kc] = *(uint4*)hp;
      *(uint4*)&Asl[row][kc] = *(uint4*)lp;
    }
    // ---- stage B (pre-split weights) ----
#pragma unroll
    for (int s = 0; s < 2; ++s) {
      const int c = s * 256 + tid;
      const int row = c >> 3, kc = (c & 7) << 3;
      const int gk = k0 + kc;
      uint4 vh = {0u, 0u, 0u, 0u}, vl = {0u, 0u, 0u, 0u};
      if (gk < K) {
        vh = *(const uint4*)&Bh[(size_t)(n0 + row) * K + gk];
        vl = *(const uint4*)&Bl[(size_t)(n0 + row) * K + gk];
      }
      *(uint4*)&Bsh[row][kc] = vh;
      *(uint4*)&Bsl[row][kc] = vl;
    }
    __syncthreads();
#pragma unroll
    for (int kk = 0; kk < 64; kk += 32) {
      const int ko = kk + ((lane >> 4) << 3);
      const int ra0 = wy * 32 + (lane & 15), ra1 = ra0 + 16;
      const int rb0 = wx * 32 + (lane & 15), rb1 = rb0 + 16;
      bf16x8v a0h = *(const bf16x8v*)&Ash[ra0][ko];
      bf16x8v a1h = *(const bf16x8v*)&Ash[ra1][ko];
      bf16x8v b0h = *(const bf16x8v*)&Bsh[rb0][ko];
      bf16x8v b1h = *(const bf16x8v*)&Bsh[rb1][ko];
      bf16x8v a0l = *(const bf16x8v*)&Asl[ra0][ko];
      bf16x8v a1l = *(const bf16x8v*)&Asl[ra1][ko];
      bf16x8v b0l = *(const bf16x8v*)&Bsl[rb0][ko];
      bf16x8v b1l = *(const bf16x8v*)&Bsl[rb1][ko];
      acc[0][0] = __builtin_amdgcn_mfma_f32_16x16x32_bf16(a0h, b0h, acc[0][0], 0, 0, 0);
      acc[0][1] = __builtin_amdgcn_mfma_f32_16x16x32_bf16(a0h, b1h, acc[0][1], 0, 0, 0);
      acc[1][0] = __builtin_amdgcn_mfma_f32_16x16x32_bf16(a1h, b0h, acc[1][0], 0, 0, 0);
      acc[1][1] = __builtin_amdgcn_mfma_f32_16x16x32_bf16(a1h, b1h, acc[1][1], 0, 0, 0);
      acc[0][0] = __builtin_amdgcn_mfma_f32_16x16x32_bf16(a0h, b0l, acc[0][0], 0, 0, 0);
      acc[0][1] = __builtin_amdgcn_mfma_f32_16x16x32_bf16(a0h, b1l, acc[0][1], 0, 0, 0);
      acc[1][0] = __builtin_amdgcn_mfma_f32_16x16x32_bf16(a1h, b0l, acc[1][0], 0, 0, 0);
      acc[1][1] = __builtin_amdgcn_mfma_f32_16x16x32_bf16(a1h, b1l, acc[1][1], 0, 0, 0);
      acc[0][0] = __builtin_amdgcn_mfma_f32_16x16x32_bf16(a0l, b0h, acc[0][0], 0, 0, 0);
      acc[0][1] = __builtin_amdgcn_mfma_f32_16x16x32_bf16(a0l, b1h, acc[0][1], 0, 0, 0);
      acc[1][0] = __builtin_amdgcn_mfma_f32_16x16x32_bf16(a1l, b0h, acc[1][0], 0, 0, 0);
      acc[1][1] = __builtin_amdgcn_mfma_f32_16x16x32_bf16(a1l, b1h, acc[1][1], 0, 0, 0);
    }
    __syncthreads();
  }
  // ---- epilogue (f32 out) ----
#pragma unroll
  for (int r = 0; r < 2; ++r) {
#pragma unroll
    for (int c = 0; c < 2; ++c) {
      const int gn = n0 + wx * 32 + c * 16 + (lane & 15);
      float sc0 = 0.f, sh0 = 0.f;
      if (EPI == 0) { sc0 = p1[gn] * BN_INV; sh0 = p2[gn]; }
#pragma unroll
      for (int i = 0; i < 4; ++i) {
        const int gm = m0 + wy * 32 + r * 16 + ((lane >> 4) << 2) + i;
        if (gm >= M) continue;
        const float a = acc[r][c][i];
        if (EPI == 0) {
          Cout[(size_t)gm * ldc + gn] = fmaxf((a + p0[gn]) * sc0 + sh0, 0.f);
        } else {
          Cout[(size_t)gm * ldc + gn] = a + p0[gn];
        }
      }
    }
  }
}

// ---------------- fused attention, block = (q,s,t-group of 7) ---------------
// r10: 256-thread blocks (8 blocks/CU = 32 waves with 8 independent barrier
// domains, was 4x512 in lockstep), parallel 8-lane softmax (was 7-thread
// serial), WqT padded [64][9] (stride-9 staging writes, conflict-free).
__global__ __launch_bounds__(256) void attention_f32(
    const float* __restrict__ proj, const float* __restrict__ featT,
    float* __restrict__ attended) {
  __shared__ float WqT[64][9];    // [h][tloc], 7 used, pad 9 -> conflict-free
  __shared__ float WhT[64][51];   // [h][u], odd pad -> conflict-free
  __shared__ float sc[7][64];
  const int bid = blockIdx.x;
  const int qs = bid / 7, tg = bid - 7 * qs;
  const int q = qs / NS, s = qs - NS * q;
  const int tid = threadIdx.x;
  const float* pq = proj + ((size_t)(NS + q) * T49 + tg * 7) * 64;
  const float* ph = proj + (size_t)s * T49 * 64;
  for (int l = tid; l < 7 * 64; l += 256) WqT[l & 63][l >> 6] = pq[l];
  for (int l = tid; l < T49 * 64; l += 256) WhT[l & 63][l >> 6] = ph[l];
  __syncthreads();
  // scores: 343 (t,u) pairs over 256 threads, 4-acc ILP h-loop
  constexpr float C2LOG2E = 2.8853900817779268f;
  for (int e = tid; e < 343; e += 256) {
    const int tl = e / 49, u = e - 49 * tl;
    float a0 = 0.f, a1 = 0.f, a2 = 0.f, a3 = 0.f;
#pragma unroll
    for (int h = 0; h < 64; h += 4) {
      const float p0 = WqT[h + 0][tl] * WhT[h + 0][u];
      const float p1 = WqT[h + 1][tl] * WhT[h + 1][u];
      const float p2 = WqT[h + 2][tl] * WhT[h + 2][u];
      const float p3 = WqT[h + 3][tl] * WhT[h + 3][u];
      a0 += 1.f - 2.f * __builtin_amdgcn_rcpf(__builtin_amdgcn_exp2f(p0 * C2LOG2E) + 1.f);
      a1 += 1.f - 2.f * __builtin_amdgcn_rcpf(__builtin_amdgcn_exp2f(p1 * C2LOG2E) + 1.f);
      a2 += 1.f - 2.f * __builtin_amdgcn_rcpf(__builtin_amdgcn_exp2f(p2 * C2LOG2E) + 1.f);
      a3 += 1.f - 2.f * __builtin_amdgcn_rcpf(__builtin_amdgcn_exp2f(p3 * C2LOG2E) + 1.f);
    }
    sc[tl][u] = (a0 + a1) + (a2 + a3);
  }
  __syncthreads();
  // parallel softmax: 8 lanes per row, all 56 lanes in wave 0
  if (tid < 56) {
    const int t = tid >> 3, g = tid & 7;
    float m = -3.4e38f;
    for (int u = g; u < T49; u += 8) m = fmaxf(m, sc[t][u]);
    m = fmaxf(m, __shfl_xor(m, 4));
    m = fmaxf(m, __shfl_xor(m, 2));
    m = fmaxf(m, __shfl_xor(m, 1));
    float ssum = 0.f;
    for (int u = g; u < T49; u += 8) {
      const float e = __builtin_amdgcn_exp2f((sc[t][u] - m) * LOG2E);
      sc[t][u] = e; ssum += e;
    }
    ssum += __shfl_xor(ssum, 4);
    ssum += __shfl_xor(ssum, 2);
    ssum += __shfl_xor(ssum, 1);
    const float inv = 1.f / ssum;
    for (int u = g; u < T49; u += 8) sc[t][u] *= inv;
  }
  __syncthreads();
  // PV: f = tid (256), 7 t-accumulators per thread; sc reads broadcast
  const float* fs = featT + (size_t)s * T49 * 256;
  float* outp = attended + ((size_t)qs * T49 + tg * 7) * 256;
  float acc[7] = {0.f, 0.f, 0.f, 0.f, 0.f, 0.f, 0.f};
  for (int u = 0; u < T49; ++u) {
    const float v = fs[u * 256 + tid];
#pragma unroll
    for (int i = 0; i < 7; ++i) acc[i] += sc[i][u] * v;
  }
#pragma unroll
  for (int i = 0; i < 7; ++i) outp[(size_t)i * 256 + tid] = acc[i];
}

// ---------------- batched split-bf16 MFMA GRU ----------------
// r8: SPB=8 (47 blocks), gi prefetched one step ahead, fast exp2 gates.
// Wh register-resident hi/lo bf16 (3-pass Dekker MFMA).
constexpr int SPB = 8;
__global__ __launch_bounds__(512) void gru_mfma(
    const float* __restrict__ gi,   // (375,49,384), includes bi
    const float* __restrict__ wh,   // (384,128) f32
    const float* __restrict__ bh,   // (384)
    float* __restrict__ y,          // (375,49,128) if store_all else (375,128)
    int store_all) {
  __shared__ u16 hah[16][136], hal[16][136];
  __shared__ float ghs[SPB][384];
  __shared__ float hfl[SPB][128];
  const int tid = threadIdx.x;
  const int lane = tid & 63, wv = tid >> 6;   // 8 waves
  const int r0 = blockIdx.x * SPB;
  bf16x8v Bhr[3][4], Blr[3][4];
#pragma unroll
  for (int f = 0; f < 3; ++f) {
    const int n = (wv * 3 + f) * 16 + (lane & 15);
#pragma unroll
    for (int kk = 0; kk < 4; ++kk) {
      const int k = kk * 32 + ((lane >> 4) << 3);
      const float* p = wh + (size_t)n * 128 + k;
      float v[8];
      *(float4*)&v[0] = *(const float4*)p;
      *(float4*)&v[4] = *(const float4*)(p + 4);
      u32 hp[4], lp[4];
      split8(v, hp, lp);
      Bhr[f][kk] = *(bf16x8v*)hp;
      Blr[f][kk] = *(bf16x8v*)lp;
    }
  }
  const int row0 = tid >> 7, j0 = tid & 127;
  const int row1 = (512 + tid) >> 7, j1 = tid & 127;
  int sq0 = r0 + row0; if (sq0 >= B3) sq0 = B3 - 1;
  int sq1 = r0 + row1; if (sq1 >= B3) sq1 = B3 - 1;
  const float bhr0 = bh[j0], bhz0 = bh[128 + j0], bhn0 = bh[256 + j0];
  const float bhr1 = bh[j1], bhz1 = bh[128 + j1], bhn1 = bh[256 + j1];
  const float* gib0 = gi + (size_t)sq0 * T49 * 384;
  const float* gib1 = gi + (size_t)sq1 * T49 * 384;
  for (int i = tid; i < 16 * 136; i += 512) { hah[i / 136][i % 136] = 0; hal[i / 136][i % 136] = 0; }
  for (int i = tid; i < SPB * 128; i += 512) hfl[i >> 7][i & 127] = 0.f;
  __syncthreads();
  const int ar = lane & 15, ko = (lane >> 4) << 3;
  float xr0c = gib0[j0], xz0c = gib0[128 + j0], xn0c = gib0[256 + j0];
  float xr1c = gib1[j1], xz1c = gib1[128 + j1], xn1c = gib1[256 + j1];
  for (int t = 0; t < T49; ++t) {
    const int tn = (t + 1 < T49) ? t + 1 : t;
    const float* g0n = gib0 + (size_t)tn * 384;
    const float* g1n = gib1 + (size_t)tn * 384;
    const float xr0n = g0n[j0], xz0n = g0n[128 + j0], xn0n = g0n[256 + j0];
    const float xr1n = g1n[j1], xz1n = g1n[128 + j1], xn1n = g1n[256 + j1];
    bf16x8v Ah[4], Al[4];
#pragma unroll
    for (int kk = 0; kk < 4; ++kk) {
      Ah[kk] = *(const bf16x8v*)&hah[ar][kk * 32 + ko];
      Al[kk] = *(const bf16x8v*)&hal[ar][kk * 32 + ko];
    }
#pragma unroll
    for (int f = 0; f < 3; ++f) {
      f32x4 acc = {0, 0, 0, 0};
#pragma unroll
      for (int kk = 0; kk < 4; ++kk)
        acc = __builtin_amdgcn_mfma_f32_16x16x32_bf16(Ah[kk], Bhr[f][kk], acc, 0, 0, 0);
#pragma unroll
      for (int kk = 0; kk < 4; ++kk)
        acc = __builtin_amdgcn_mfma_f32_16x16x32_bf16(Ah[kk], Blr[f][kk], acc, 0, 0, 0);
#pragma unroll
      for (int kk = 0; kk < 4; ++kk)
        acc = __builtin_amdgcn_mfma_f32_16x16x32_bf16(Al[kk], Bhr[f][kk], acc, 0, 0, 0);
      const int nc = (wv * 3 + f) * 16 + (lane & 15);
      const int rb = (lane >> 4) << 2;
      if (rb < SPB) {
#pragma unroll
        for (int i = 0; i < 4; ++i) ghs[rb + i][nc] = acc[i];
      }
    }
    __syncthreads();
    {
      const float r_ = fsigmoid(xr0c + ghs[row0][j0] + bhr0);
      const float z_ = fsigmoid(xz0c + ghs[row0][128 + j0] + bhz0);
      const float n_ = ftanh(xn0c + r_ * (ghs[row0][256 + j0] + bhn0));
      const float hn = (1.f - z_) * n_ + z_ * hfl[row0][j0];
      hfl[row0][j0] = hn;
      const u16 hb = f2b(hn);
      hah[row0][j0] = hb;
      hal[row0][j0] = f2b(hn - b2f(hb));
      if (r0 + row0 < B3) {
        if (store_all) y[((size_t)(r0 + row0) * T49 + t) * 128 + j0] = hn;
        else if (t == T49 - 1) y[(size_t)(r0 + row0) * 128 + j0] = hn;
      }
    }
    {
      const float r_ = fsigmoid(xr1c + ghs[row1][j1] + bhr1);
      const float z_ = fsigmoid(xz1c + ghs[row1][128 + j1] + bhz1);
      const float n_ = ftanh(xn1c + r_ * (ghs[row1][256 + j1] + bhn1));
      const float hn = (1.f - z_) * n_ + z_ * hfl[row1][j1];
      hfl[row1][j1] = hn;
      const u16 hb = f2b(hn);
      hah[row1][j1] = hb;
      hal[row1][j1] = f2b(hn - b2f(hb));
      if (r0 + row1 < B3) {
        if (store_all) y[((size_t)(r0 + row1) * T49 + t) * 128 + j1] = hn;
        else if (t == T49 - 1) y[(size_t)(r0 + row1) * 128 + j1] = hn;
      }
    }
    __syncthreads();
    xr0c = xr0n; xz0c = xz0n; xn0c = xn0n;
    xr1c = xr1n; xz1c = xz1n; xn1c = xn1n;
  }
}

// ---------------- head ----------------
__global__ __launch_bounds__(512) void head_kernel(
    const float* __restrict__ hf, const float* __restrict__ tw,
    const float* __restrict__ tb, float* __restrict__ out) {
  __shared__ float lg[B3];
  const int tid = threadIdx.x;
  if (tid < B3) {
    const float* h = hf + (size_t)tid * 128;
    float acc = tb[0];
    for (int k = 0; k < 128; ++k) acc += h[k] * tw[k];
    lg[tid] = acc;
  }
  __syncthreads();
  if (tid < NQ) {
    float cls[5];
#pragma unroll
    for (int n = 0; n < 5; ++n) {
      float s = 0.f;
#pragma unroll
      for (int k = 0; k < 5; ++k) s += lg[tid * 25 + n * 5 + k];
      cls[n] = s;
    }
    float m = cls[0];
#pragma unroll
    for (int n = 1; n < 5; ++n) m = fmaxf(m, cls[n]);
    float se = 0.f;
#pragma unroll
    for (int n = 0; n < 5; ++n) se += expf(cls[n] - m);
    const float lse = m + logf(se);
#pragma unroll
    for (int n = 0; n < 5; ++n) out[tid * 5 + n] = cls[n] - lse;
  }
}

extern "C" void kernel_launch(void* const* d_in, const int* in_sizes, int n_in,
                              void* d_out, int out_size, void* d_ws,
                              size_t ws_size, hipStream_t stream) {
  (void)in_sizes; (void)n_in; (void)out_size; (void)ws_size;
  const float* support = (const float*)d_in[0];
  const float* query   = (const float*)d_in[1];
  const float* cw1 = (const float*)d_in[2];  const float* cb1 = (const float*)d_in[3];
  const float* cw2 = (const float*)d_in[4];  const float* cb2 = (const float*)d_in[5];
  const float* cw3 = (const float*)d_in[6];  const float* cb3 = (const float*)d_in[7];
  const float* cw4 = (const float*)d_in[8];  const float* cb4 = (const float*)d_in[9];
  const float* g1  = (const float*)d_in[10]; const float* be1 = (const float*)d_in[11];
  const float* g2  = (const float*)d_in[12]; const float* be2 = (const float*)d_in[13];
  const float* g3  = (const float*)d_in[14]; const float* be3 = (const float*)d_in[15];
  const float* g4  = (const float*)d_in[16]; const float* be4 = (const float*)d_in[17];
  const float* aw  = (const float*)d_in[18]; const float* ab  = (const float*)d_in[19];
  const float* wi0 = (const float*)d_in[20]; const float* wh0 = (const float*)d_in[21];
  const float* bi0 = (const float*)d_in[22]; const float* bh0 = (const float*)d_in[23];
  const float* wi1 = (const float*)d_in[24]; const float* wh1 = (const float*)d_in[25];
  const float* bi1 = (const float*)d_in[26]; const float* bh1 = (const float*)d_in[27];
  const float* tw  = (const float*)d_in[28]; const float* tb  = (const float*)d_in[29];

  char* ws = (char*)d_ws;
  float* out = (float*)d_out;
  float* A1    = (float*)(ws + A1_OFF);
  float* X2    = (float*)(ws + X2_OFF);
  float* P2    = (float*)(ws + P2_OFF);
  float* X3    = (float*)(ws + X3_OFF);
  float* P3    = (float*)(ws + P3_OFF);
  float* X4    = (float*)(ws + X4_OFF);
  float* FEATT = (float*)(ws + FEATT_OFF);
  float* PROJ  = (float*)(ws + PROJ_OFF);
  float* ATT   = (float*)(ws + ATT_OFF);
  float* GI    = (float*)(ws + GI_OFF);
  float* Y0    = (float*)(ws + Y0_OFF);
  float* HFIN  = (float*)(ws + HFIN_OFF);
  u16* WBH = (u16*)(ws + WBH_OFF);
  u16* WBL = (u16*)(ws + WBL_OFF);

  // weight conversions (split hi/lo)
  cvt_conv_w_split<<<(64 * 288 + 255) / 256, 256, 0, stream>>>(cw2, WBH + W2_E, WBL + W2_E, 64, 32);
  cvt_conv_w_split<<<(128 * 576 + 255) / 256, 256, 0, stream>>>(cw3, WBH + W3_E, WBL + W3_E, 128, 64);
  cvt_conv_w_split<<<(256 * 1152 + 255) / 256, 256, 0, stream>>>(cw4, WBH + W4_E, WBL + W4_E, 256, 128);
  cvt_split<<<(64 * 256 + 255) / 256, 256, 0, stream>>>(aw, WBH + AW_E, WBL + AW_E, 64 * 256);
  cvt_split<<<(384 * 512 + 255) / 256, 256, 0, stream>>>(wi0, WBH + WI0_E, WBL + WI0_E, 384 * 512);
  cvt_split<<<(384 * 128 + 255) / 256, 256, 0, stream>>>(wi1, WBH + WI1_E, WBL + WI1_E, 384 * 128);

  // ---- encoder ----
  conv1_pool<<<15680, 256, 0, stream>>>(support, query, cw1, cb1, g1, be1, A1);
  // conv2: A1(40,56,56,32) -> X2(40,56,56,64) -> P2(40,28,28,64)
  sgemm<2, 0><<<dim3(1, 1960), 256, 0, stream>>>(
      A1, nullptr, 125440, 288, WBH + W2_E, WBL + W2_E, cb2, g2, be2, X2, 64,
      56, 56, 32, 5);
  maxpool2_f32<<<1960, 256, 0, stream>>>(X2, P2, NB, 56, 56, 64);
  // conv3: P2 -> X3(40,28,28,128) -> P3(40,14,14,128)
  sgemm<2, 0><<<dim3(2, 490), 256, 0, stream>>>(
      P2, nullptr, 31360, 576, WBH + W3_E, WBL + W3_E, cb3, g3, be3, X3, 128,
      28, 28, 64, 6);
  maxpool2_f32<<<980, 256, 0, stream>>>(X3, P3, NB, 28, 28, 128);
  // conv4: P3 -> X4(40,14,14,256) -> FEATT(40,7,7,256)
  sgemm<2, 0><<<dim3(4, 123), 256, 0, stream>>>(
      P3, nullptr, 7840, 1152, WBH + W4_E, WBL + W4_E, cb4, g4, be4, X4, 256,
      14, 14, 128, 7);
  maxpool2_f32<<<490, 256, 0, stream>>>(X4, FEATT, NB, 14, 14, 256);

  // ---- attention ----
  sgemm<0, 1><<<dim3(1, 31), 256, 0, stream>>>(
      FEATT, nullptr, NB * T49, 256, WBH + AW_E, WBL + AW_E, ab, nullptr,
      nullptr, PROJ, 64, 0, 0, 0, 0);
  attention_f32<<<B3 * 7, 256, 0, stream>>>(PROJ, FEATT, ATT);

  // ---- GRU stack ----
  sgemm<1, 1><<<dim3(6, 288), 256, 0, stream>>>(
      ATT, FEATT, B3 * T49, 512, WBH + WI0_E, WBL + WI0_E, bi0, nullptr,
      nullptr, GI, 384, 0, 0, 0, 0);
  gru_mfma<<<47, 512, 0, stream>>>(GI, wh0, bh0, Y0, 1);
  sgemm<0, 1><<<dim3(6, 288), 256, 0, stream>>>(
      Y0, nullptr, B3 * T49, 128, WBH + WI1_E, WBL + WI1_E, bi1, nullptr,
      nullptr, GI, 384, 0, 0, 0, 0);
  gru_mfma<<<47, 512, 0, stream>>>(GI, wh1, bh1, HFIN, 0);

  // ---- head ----
  head_kernel<<<1, 512, 0, stream>>>(HFIN, tw, tb, out);
}